// Round 10
// baseline (469.747 us; speedup 1.0000x reference)
//
#include <hip/hip_runtime.h>
#include <math.h>
#include <stdint.h>

#ifndef M_PI
#define M_PI 3.14159265358979323846
#endif

#define HW 16384
#define BHW 131072

typedef __attribute__((ext_vector_type(8))) short s8bf;    // 8 bf16 = 4 VGPR
typedef __attribute__((ext_vector_type(4))) float f32x4;   // MFMA C/D

union FragU { uint32_t u[4]; s8bf s; };

// ---------- bf16 split helpers ----------
__device__ __forceinline__ uint32_t bf16h(float x) {
  uint32_t u = __float_as_uint(x);
  return (u + 0x7FFFu + ((u >> 16) & 1u)) >> 16;     // RNE, low 16 bits
}
__device__ __forceinline__ uint32_t packhl(float x) {  // u32 = (hi<<16)|lo
  uint32_t h = bf16h(x);
  float r = x - __uint_as_float(h << 16);
  return (h << 16) | bf16h(r);
}
__device__ __forceinline__ void unpack8(const uint32_t* w, s8bf& hi, s8bf& lo) {
  FragU H, L;
#pragma unroll
  for (int j = 0; j < 4; ++j) {
    H.u[j] = __builtin_amdgcn_perm(w[2 * j + 1], w[2 * j], 0x07060302u);
    L.u[j] = __builtin_amdgcn_perm(w[2 * j + 1], w[2 * j], 0x05040100u);
  }
  hi = H.s; lo = L.s;
}

// ---------- tables ----------
__global__ void k0_tables(float* __restrict__ cc, float* __restrict__ ee) {
  int gid = blockIdx.x * 256 + threadIdx.x;   // 16384
  int n = gid >> 7, m = gid & 127;
  double v = cos((double)n * ((double)m + 0.5) * (M_PI / 128.0)) * sqrt(2.0 / 128.0);
  if (n == 0) v *= 0.70710678118654752440;
  cc[gid] = (float)v;
  double wn = (double)n * (M_PI / 128.0), wm = (double)m * (M_PI / 128.0);
  ee[gid] = (float)(wn * wn + wm * wm);
}

// ---------- DCT matrix fragment constants (A-operand order, hi/lo split) ----------
__device__ __forceinline__ float cval(int a, int b) {
  double v = cos((double)a * ((double)b + 0.5) * (M_PI / 128.0)) * sqrt(2.0 / 128.0);
  if (a == 0) v *= 0.70710678118654752440;
  return (float)v;
}
__global__ void k0_frags(uint32_t* __restrict__ FAh, uint32_t* __restrict__ FAl,
                         uint32_t* __restrict__ FTh, uint32_t* __restrict__ FTl) {
  int tid = blockIdx.x * 256 + threadIdx.x;   // 2048
  int lane = tid & 63, fid = tid >> 6;
  int mt = fid >> 2, ks = fid & 3;
  int n = 16 * mt + (lane & 15);
  int k0 = 32 * ks + 8 * (lane >> 4);
#pragma unroll
  for (int j = 0; j < 4; ++j) {
    float a0 = cval(n, k0 + 2 * j), a1 = cval(n, k0 + 2 * j + 1);
    uint32_t p0 = packhl(a0), p1 = packhl(a1);
    FAh[tid * 4 + j] = (p0 >> 16) | (p1 & 0xFFFF0000u);
    FAl[tid * 4 + j] = (p0 & 0xFFFFu) | (p1 << 16);
    float b0 = cval(k0 + 2 * j, n), b1 = cval(k0 + 2 * j + 1, n);
    uint32_t q0 = packhl(b0), q1 = packhl(b1);
    FTh[tid * 4 + j] = (q0 >> 16) | (q1 & 0xFFFF0000u);
    FTl[tid * 4 + j] = (q0 & 0xFFFFu) | (q1 << 16);
  }
}

// ---------- generic weight A-frag builder: W[D][K] row-major -> hi/lo frags ----------
__global__ void k_wfrag(const float* __restrict__ src, uint32_t* __restrict__ Fh,
                        uint32_t* __restrict__ Fl, int D, int K) {
  int tid = blockIdx.x * 256 + threadIdx.x;
  int nksl = K >> 5;
  int total = (D >> 4) * nksl * 64;
  if (tid >= total) return;
  int lane = tid & 63, fid = tid >> 6;
  int nt = fid / nksl, ksl = fid - nt * nksl;
  int d = 16 * nt + (lane & 15);
  int k0 = 32 * ksl + 8 * (lane >> 4);
#pragma unroll
  for (int j = 0; j < 4; ++j) {
    uint32_t p0 = packhl(src[d * K + k0 + 2 * j]);
    uint32_t p1 = packhl(src[d * K + k0 + 2 * j + 1]);
    Fh[tid * 4 + j] = (p0 >> 16) | (p1 & 0xFFFF0000u);
    Fl[tid * 4 + j] = (p0 & 0xFFFFu) | (p1 << 16);
  }
}

// ---------- generic weight transpose: src[D][C] -> dst[C][D] ----------
__global__ void k_wt(const float* __restrict__ src, float* __restrict__ dst, int D, int C) {
  int gid = blockIdx.x * 256 + threadIdx.x;
  if (gid >= D * C) return;
  int d = gid / C, c = gid % C;
  dst[c * D + d] = src[gid];
}

// ---------- fe transpose: [HW][96] -> [96][HW] ----------
__global__ __launch_bounds__(256) void k_tfe(const float* __restrict__ fe,
                                             float* __restrict__ fet) {
  __shared__ float tile[64 * 97];
  int hw0 = blockIdx.x * 64;
  int tid = threadIdx.x;
#pragma unroll
  for (int t = 0; t < 24; ++t) {
    int l = tid + t * 256;
    int r = l / 96, c0 = l % 96;
    tile[r * 97 + c0] = fe[((size_t)hw0 + r) * 96 + c0];
  }
  __syncthreads();
#pragma unroll
  for (int t = 0; t < 24; ++t) {
    int l = tid + t * 256;
    int c0 = l >> 6, r = l & 63;
    fet[(size_t)c0 * HW + hw0 + r] = tile[r * 97 + c0];
  }
}

// ---------- KC: depthwise 3x3 conv, float4 per thread, plane-major out ----------
__global__ __launch_bounds__(256) void kconv(
    const float* __restrict__ x, const float* __restrict__ dw_w,
    const float* __restrict__ dw_b, float* __restrict__ xc) {
  int gid = blockIdx.x * 256 + threadIdx.x;   // B*96*4096 = 3145728
  int p = gid >> 12;                          // plane b*96+c
  int q = gid & 4095;
  int h = q >> 5, w4 = (q & 31) << 2;
  int c = p % 96;
  const float* pw = dw_w + c * 9;
  const float* row = x + (size_t)p * HW + h * 128 + w4;
  bool tp = h > 0, bt = h < 127, lf = w4 > 0, rt = w4 < 124;
  float4 t_, m_, b_;
  float tl, tr, ml, mr, bl, br;
  m_ = *(const float4*)row;
  ml = lf ? row[-1] : 0.f;
  mr = rt ? row[4] : 0.f;
  if (tp) {
    t_ = *(const float4*)(row - 128);
    tl = lf ? row[-129] : 0.f;
    tr = rt ? row[-124] : 0.f;
  } else { t_ = make_float4(0.f, 0.f, 0.f, 0.f); tl = tr = 0.f; }
  if (bt) {
    b_ = *(const float4*)(row + 128);
    bl = lf ? row[127] : 0.f;
    br = rt ? row[132] : 0.f;
  } else { b_ = make_float4(0.f, 0.f, 0.f, 0.f); bl = br = 0.f; }
  float w0 = pw[0], w1 = pw[1], w2 = pw[2], w3 = pw[3], w4w = pw[4],
        w5 = pw[5], w6 = pw[6], w7 = pw[7], w8 = pw[8];
  float bias = dw_b[c];
  float4 o;
  o.x = tl * w0 + t_.x * w1 + t_.y * w2 + ml * w3 + m_.x * w4w + m_.y * w5 + bl * w6 + b_.x * w7 + b_.y * w8 + bias;
  o.y = t_.x * w0 + t_.y * w1 + t_.z * w2 + m_.x * w3 + m_.y * w4w + m_.z * w5 + b_.x * w6 + b_.y * w7 + b_.z * w8 + bias;
  o.z = t_.y * w0 + t_.z * w1 + t_.w * w2 + m_.y * w3 + m_.z * w4w + m_.w * w5 + b_.y * w6 + b_.z * w7 + b_.w * w8 + bias;
  o.w = t_.z * w0 + t_.w * w1 + tr * w2 + m_.z * w3 + m_.w * w4w + mr * w5 + b_.z * w6 + b_.w * w7 + br * w8 + bias;
  *(float4*)(xc + (size_t)p * HW + h * 128 + w4) = o;
}

// ---------- KL-MFMA: [B*HW,96] @ lin_w^T -> x1 planes + z planes ----------
__global__ __launch_bounds__(256) void klin_mfma(
    const float* __restrict__ xc, const uint32_t* __restrict__ WLh,
    const uint32_t* __restrict__ WLl, const float* __restrict__ lin_b,
    float* __restrict__ x1p, float* __restrict__ z) {
  __shared__ uint32_t Ds[64 * 102];   // [m][k], 26 KB
  const int tid = threadIdx.x;
  const int lane = tid & 63;
  const int w = tid >> 6;
  const int l15 = lane & 15, lg = lane >> 4;
  const int gp0 = blockIdx.x * 64;
  const int b = gp0 >> 14, hw0 = gp0 & 16383;

#pragma unroll
  for (int i = 0; i < 24; ++i) {      // stage xc -> Ds[m*102+k]
    int k = w + 4 * i;
    float v = xc[((size_t)(b * 96 + k)) * HW + hw0 + lane];
    Ds[lane * 102 + k] = packhl(v);
  }
  __syncthreads();

  f32x4 acc[3][4];
#pragma unroll
  for (int nt = 0; nt < 3; ++nt) {
    float bv[4];
#pragma unroll
    for (int r = 0; r < 4; ++r) bv[r] = lin_b[16 * (3 * w + nt) + 4 * lg + r];
#pragma unroll
    for (int mt = 0; mt < 4; ++mt)
#pragma unroll
      for (int r = 0; r < 4; ++r) acc[nt][mt][r] = bv[r];
  }

#pragma unroll
  for (int ksl = 0; ksl < 3; ++ksl) {
    s8bf Dhi[4], Dlo[4];
#pragma unroll
    for (int mt = 0; mt < 4; ++mt) {
      const uint32_t* p = Ds + (16 * mt + l15) * 102 + 32 * ksl + 8 * lg;
      uint32_t wv[8];
      *(uint2*)&wv[0] = *(const uint2*)(p);
      *(uint2*)&wv[2] = *(const uint2*)(p + 2);
      *(uint2*)&wv[4] = *(const uint2*)(p + 4);
      *(uint2*)&wv[6] = *(const uint2*)(p + 6);
      unpack8(wv, Dhi[mt], Dlo[mt]);
    }
#pragma unroll
    for (int nt = 0; nt < 3; ++nt) {
      int base = (((3 * w + nt) * 3 + ksl) * 64 + lane) * 4;
      FragU H, L;
      *(uint4*)H.u = *(const uint4*)(WLh + base);
      *(uint4*)L.u = *(const uint4*)(WLl + base);
#pragma unroll
      for (int mt = 0; mt < 4; ++mt) {
        acc[nt][mt] = __builtin_amdgcn_mfma_f32_16x16x32_bf16(H.s, Dhi[mt], acc[nt][mt], 0, 0, 0);
        acc[nt][mt] = __builtin_amdgcn_mfma_f32_16x16x32_bf16(H.s, Dlo[mt], acc[nt][mt], 0, 0, 0);
        acc[nt][mt] = __builtin_amdgcn_mfma_f32_16x16x32_bf16(L.s, Dhi[mt], acc[nt][mt], 0, 0, 0);
      }
    }
  }
#pragma unroll
  for (int nt = 0; nt < 3; ++nt) {
    int d0 = 16 * (3 * w + nt) + 4 * lg;
#pragma unroll
    for (int mt = 0; mt < 4; ++mt) {
#pragma unroll
      for (int r = 0; r < 4; ++r) {
        int d = d0 + r;
        if (d < 96)
          x1p[((size_t)(b * 96 + d)) * HW + hw0 + 16 * mt + l15] = acc[nt][mt][r];
        else
          z[((size_t)(d - 96)) * BHW + gp0 + 16 * mt + l15] = acc[nt][mt][r];
      }
    }
  }
}

// ---------- K3: outline_feat transpose to plane-major + mean over B ----------
__global__ __launch_bounds__(256) void k3_transpose_mean(
    const float* __restrict__ of, float* __restrict__ ofp, float* __restrict__ cmU) {
  __shared__ float tile[64 * 97];
  int hw0 = blockIdx.x * 64;
  int tid = threadIdx.x;
  float sum[24];
#pragma unroll
  for (int t = 0; t < 24; ++t) sum[t] = 0.f;
  for (int b = 0; b < 8; ++b) {
    __syncthreads();
#pragma unroll
    for (int t = 0; t < 24; ++t) {
      int l = tid + t * 256;
      int r = l / 96, c0 = l % 96;
      tile[r * 97 + c0] = of[((size_t)b * 16384 + hw0 + r) * 96 + c0];
    }
    __syncthreads();
#pragma unroll
    for (int t = 0; t < 24; ++t) {
      int l = tid + t * 256;
      int c0 = l >> 6, r = l & 63;
      float v = tile[r * 97 + c0];
      sum[t] += v;
      ofp[(size_t)(b * 96 + c0) * HW + hw0 + r] = v;
    }
  }
#pragma unroll
  for (int t = 0; t < 24; ++t) {
    int l = tid + t * 256;
    int c0 = l >> 6, r = l & 63;
    cmU[(size_t)c0 * HW + hw0 + r] = sum[t] * 0.125f;
  }
}

// ---------- K3b: k = relu((fet+otm)@k_w^T + k_b); P1 = exp(-e*k) ----------
__global__ __launch_bounds__(256) void k3b_kgemm(
    const float* __restrict__ fet, const float* __restrict__ otm,
    const float* __restrict__ kT, const float* __restrict__ kb,
    const float* __restrict__ ee, float* __restrict__ P1) {
  int tid = threadIdx.x;
  int lane = tid & 63;
  int n0 = __builtin_amdgcn_readfirstlane((tid >> 6) * 24);
  int row = blockIdx.x * 64 + lane;           // 256 blocks
  float acc[24];
#pragma unroll
  for (int j = 0; j < 24; ++j) acc[j] = kb[n0 + j];
#pragma unroll 4
  for (int c = 0; c < 96; ++c) {
    float a = fet[(size_t)c * HW + row] + otm[(size_t)c * HW + row];
    const float* wr = kT + c * 96 + n0;
#pragma unroll
    for (int j = 0; j < 24; ++j) acc[j] = fmaf(a, wr[j], acc[j]);
  }
  float er = ee[row];
#pragma unroll
  for (int j = 0; j < 24; ++j)
    P1[(size_t)(n0 + j) * HW + row] = expf(-er * fmaxf(acc[j], 0.f));
}

// ---------- MFMA transform primitives ----------
template <bool DATA_A>
__device__ __forceinline__ void heat_step(
    const uint32_t* __restrict__ Fh, const uint32_t* __restrict__ Fl,
    const uint32_t* __restrict__ Ds, f32x4 (&acc)[4][4], int wm, int wn, int lane) {
  const int l15 = lane & 15, lg = lane >> 4;
  const int wd = DATA_A ? wm : wn;
  const int wf = DATA_A ? wn : wm;
#pragma unroll
  for (int ksl = 0; ksl < 4; ++ksl) {
    s8bf Dhi[4], Dlo[4], Fhi[4], Flo[4];
#pragma unroll
    for (int t = 0; t < 4; ++t) {
      const uint32_t* p = Ds + (64 * wd + 16 * t + l15) * 130 + 32 * ksl + 8 * lg;
      uint32_t wv[8];
      *(uint2*)&wv[0] = *(const uint2*)(p);
      *(uint2*)&wv[2] = *(const uint2*)(p + 2);
      *(uint2*)&wv[4] = *(const uint2*)(p + 4);
      *(uint2*)&wv[6] = *(const uint2*)(p + 6);
      unpack8(wv, Dhi[t], Dlo[t]);
    }
#pragma unroll
    for (int t = 0; t < 4; ++t) {
      int base = (((4 * wf + t) * 4 + ksl) * 64 + lane) * 4;
      FragU H, L;
      *(uint4*)H.u = *(const uint4*)(Fh + base);
      *(uint4*)L.u = *(const uint4*)(Fl + base);
      Fhi[t] = H.s; Flo[t] = L.s;
    }
    const s8bf* Ah = DATA_A ? Dhi : Fhi;
    const s8bf* Al = DATA_A ? Dlo : Flo;
    const s8bf* Bh = DATA_A ? Fhi : Dhi;
    const s8bf* Bl = DATA_A ? Flo : Dlo;
#pragma unroll
    for (int mi = 0; mi < 4; ++mi)
#pragma unroll
      for (int ni = 0; ni < 4; ++ni)
        acc[mi][ni] = __builtin_amdgcn_mfma_f32_16x16x32_bf16(Ah[mi], Bh[ni], acc[mi][ni], 0, 0, 0);
#pragma unroll
    for (int mi = 0; mi < 4; ++mi)
#pragma unroll
      for (int ni = 0; ni < 4; ++ni)
        acc[mi][ni] = __builtin_amdgcn_mfma_f32_16x16x32_bf16(Ah[mi], Bl[ni], acc[mi][ni], 0, 0, 0);
#pragma unroll
    for (int mi = 0; mi < 4; ++mi)
#pragma unroll
      for (int ni = 0; ni < 4; ++ni)
        acc[mi][ni] = __builtin_amdgcn_mfma_f32_16x16x32_bf16(Al[mi], Bh[ni], acc[mi][ni], 0, 0, 0);
  }
}

// ---------- heat_half: Out = F * In * F^T (2 matmuls), optional P multiply ----------
template <bool USE_P>
__global__ __launch_bounds__(256, 2) void heat_half(
    const float* __restrict__ In, float* __restrict__ Out,
    const float* __restrict__ P, const uint32_t* __restrict__ Fh,
    const uint32_t* __restrict__ Fl, int Cmod) {
  __shared__ uint32_t Ds[128 * 130];
  const int tid = threadIdx.x;
  const int lane = tid & 63;
  const int w = tid >> 6;
  const int wm = w >> 1, wn = w & 1;
  const int l15 = lane & 15, lg = lane >> 4;
  const float* Ip = In + (size_t)blockIdx.x * HW;
  float* Op = Out + (size_t)blockIdx.x * HW;
  const float* Pp = nullptr;
  if constexpr (USE_P) Pp = P + (size_t)(blockIdx.x % Cmod) * HW;

  {
    int col = tid & 127, r0 = tid >> 7;
#pragma unroll
    for (int i = 0; i < 64; ++i) {
      int row = r0 + 2 * i;
      Ds[col * 130 + row] = packhl(Ip[row * 128 + col]);
    }
  }
  __syncthreads();

  f32x4 acc[4][4];
  const f32x4 zero4 = {0.f, 0.f, 0.f, 0.f};
#pragma unroll
  for (int mi = 0; mi < 4; ++mi)
#pragma unroll
    for (int ni = 0; ni < 4; ++ni) acc[mi][ni] = zero4;
  heat_step<false>(Fh, Fl, Ds, acc, wm, wn, lane);     // T = F * In
  __syncthreads();
#pragma unroll
  for (int mi = 0; mi < 4; ++mi)
#pragma unroll
    for (int ni = 0; ni < 4; ++ni)
#pragma unroll
      for (int r = 0; r < 4; ++r)
        Ds[(64 * wm + 16 * mi + 4 * lg + r) * 130 + 64 * wn + 16 * ni + l15] =
            packhl(acc[mi][ni][r]);
  __syncthreads();

#pragma unroll
  for (int mi = 0; mi < 4; ++mi)
#pragma unroll
    for (int ni = 0; ni < 4; ++ni) acc[mi][ni] = zero4;
  heat_step<true>(Fh, Fl, Ds, acc, wm, wn, lane);      // Out = T * F^T
#pragma unroll
  for (int mi = 0; mi < 4; ++mi)
#pragma unroll
    for (int ni = 0; ni < 4; ++ni) {
      int row = 64 * wm + 16 * mi + 4 * lg;
      int col = 64 * wn + 16 * ni + l15;
#pragma unroll
      for (int r = 0; r < 4; ++r) {
        float v = acc[mi][ni][r];
        if constexpr (USE_P) v *= Pp[(row + r) * 128 + col];
        Op[(row + r) * 128 + col] = v;
      }
    }
}

// ---------- K5: plane-mean over batch: dst[c][s] = mean_b src[b*96+c][s] ----------
__global__ void k5_mean(const float* __restrict__ src, float* __restrict__ dst) {
  int idx = blockIdx.x * 256 + threadIdx.x;
  int c = idx >> 14, s = idx & 16383;
  float sum = 0.f;
#pragma unroll
  for (int b = 0; b < 8; ++b) sum += src[(size_t)(b * 96 + c) * HW + s];
  dst[idx] = sum * 0.125f;
}

// ---------- K67: skf = cm@lin2^T+b2 (LDS); k2 = relu(skf@k2^T+b2k); P2 = exp(-e*k2) ----------
__global__ __launch_bounds__(256) void k67(
    const float* __restrict__ cm, const float* __restrict__ w2T,
    const float* __restrict__ b2, const float* __restrict__ k2T,
    const float* __restrict__ b2k, const float* __restrict__ ee,
    float* __restrict__ P2) {
  __shared__ float skf_s[64][193];            // 49.4 KB
  int tid = threadIdx.x;
  int lane = tid & 63;
  int n0 = __builtin_amdgcn_readfirstlane((tid >> 6) * 48);
  int row = blockIdx.x * 64 + lane;           // 256 blocks
  float acc[48];
#pragma unroll
  for (int j = 0; j < 48; ++j) acc[j] = b2[n0 + j];
#pragma unroll 4
  for (int k = 0; k < 192; ++k) {
    float a = cm[(size_t)k * HW + row];
    const float* wr = w2T + k * 192 + n0;
#pragma unroll
    for (int j = 0; j < 48; ++j) acc[j] = fmaf(a, wr[j], acc[j]);
  }
#pragma unroll
  for (int j = 0; j < 48; ++j) skf_s[lane][n0 + j] = acc[j];
  __syncthreads();
  float acc2[48];
#pragma unroll
  for (int j = 0; j < 48; ++j) acc2[j] = b2k[n0 + j];
#pragma unroll 4
  for (int k = 0; k < 192; ++k) {
    float a = skf_s[lane][k];
    const float* wr = k2T + k * 192 + n0;
#pragma unroll
    for (int j = 0; j < 48; ++j) acc2[j] = fmaf(a, wr[j], acc2[j]);
  }
  float er = ee[row];
#pragma unroll
  for (int j = 0; j < 48; ++j)
    P2[(size_t)(n0 + j) * HW + row] = expf(-er * fmaxf(acc2[j], 0.f));
}

// ---------- KMIX: Tf = (concat[S1*P2lo, Ohat'(pre-mul P2hi)]) @ lin3_w^T ----------
// 128 positions/block, K processed in two 96-chunks (LDS reused). In-place safe.
__global__ __launch_bounds__(256) void kmix(
    const float* __restrict__ S1, const float* __restrict__ OhP,
    const float* __restrict__ P2,
    const uint32_t* __restrict__ W3h, const uint32_t* __restrict__ W3l,
    float* __restrict__ Tf) {
  __shared__ uint32_t Ds[128 * 98];           // 50 KB -> 3 blocks/CU
  const int tid = threadIdx.x;
  const int lane = tid & 63;
  const int w = tid >> 6;
  const int wn = w >> 1, wm = w & 1;
  const int l15 = lane & 15, lg = lane >> 4;
  const int gp0 = blockIdx.x * 128;           // 1024 blocks
  const int b = gp0 >> 14, hw0 = gp0 & 16383;

  f32x4 acc[3][4];
#pragma unroll
  for (int i = 0; i < 3; ++i)
#pragma unroll
    for (int j = 0; j < 4; ++j)
#pragma unroll
      for (int r = 0; r < 4; ++r) acc[i][j][r] = 0.f;

#pragma unroll
  for (int c = 0; c < 2; ++c) {
    if (c) __syncthreads();                   // protect LDS reuse
#pragma unroll
    for (int i = 0; i < 24; ++i) {
      int k = w + 4 * i;
      if (c == 0) {
        const float* sp = S1 + ((size_t)(b * 96 + k)) * HW + hw0;
        const float* pp = P2 + (size_t)k * HW + hw0;
        Ds[lane * 98 + k] = packhl(sp[lane] * pp[lane]);
        Ds[(lane + 64) * 98 + k] = packhl(sp[lane + 64] * pp[lane + 64]);
      } else {
        const float* sp = OhP + ((size_t)(b * 96 + k)) * HW + hw0;
        Ds[lane * 98 + k] = packhl(sp[lane]);
        Ds[(lane + 64) * 98 + k] = packhl(sp[lane + 64]);
      }
    }
    __syncthreads();
#pragma unroll
    for (int ksl = 0; ksl < 3; ++ksl) {
      s8bf Dhi[4], Dlo[4];
#pragma unroll
      for (int j = 0; j < 4; ++j) {
        const uint32_t* p = Ds + (16 * (4 * wm + j) + l15) * 98 + 32 * ksl + 8 * lg;
        uint32_t wv[8];
        *(uint2*)&wv[0] = *(const uint2*)(p);
        *(uint2*)&wv[2] = *(const uint2*)(p + 2);
        *(uint2*)&wv[4] = *(const uint2*)(p + 4);
        *(uint2*)&wv[6] = *(const uint2*)(p + 6);
        unpack8(wv, Dhi[j], Dlo[j]);
      }
#pragma unroll
      for (int i = 0; i < 3; ++i) {
        int base = (((3 * wn + i) * 6 + 3 * c + ksl) * 64 + lane) * 4;
        FragU H, L;
        *(uint4*)H.u = *(const uint4*)(W3h + base);
        *(uint4*)L.u = *(const uint4*)(W3l + base);
#pragma unroll
        for (int j = 0; j < 4; ++j) {
          acc[i][j] = __builtin_amdgcn_mfma_f32_16x16x32_bf16(H.s, Dhi[j], acc[i][j], 0, 0, 0);
          acc[i][j] = __builtin_amdgcn_mfma_f32_16x16x32_bf16(H.s, Dlo[j], acc[i][j], 0, 0, 0);
          acc[i][j] = __builtin_amdgcn_mfma_f32_16x16x32_bf16(L.s, Dhi[j], acc[i][j], 0, 0, 0);
        }
      }
    }
  }
#pragma unroll
  for (int i = 0; i < 3; ++i) {
    int d0 = 16 * (3 * wn + i) + 4 * lg;
#pragma unroll
    for (int j = 0; j < 4; ++j) {
      int hw = hw0 + 16 * (4 * wm + j) + l15;
#pragma unroll
      for (int r = 0; r < 4; ++r)
        Tf[((size_t)(b * 96 + d0 + r)) * HW + hw] = acc[i][j][r];
    }
  }
}

// ---------- K9R: (y3 + b3) -> LN -> *silu(z) -> out GEMM (128 pos/block) ----------
__global__ __launch_bounds__(256) void k9r(
    const float* __restrict__ y3, const float* __restrict__ z,
    const float* __restrict__ lin3b,
    const float* __restrict__ lng, const float* __restrict__ lnb,
    const uint32_t* __restrict__ WOh, const uint32_t* __restrict__ WOl,
    const float* __restrict__ outb, float* __restrict__ out) {
  __shared__ uint32_t Ds2[128 * 98];          // 50 KB
  __shared__ float2 red[4][128];              // 4 KB  (total 54.2 KB -> 3 blocks/CU)
  const int tid = threadIdx.x;
  const int lane = tid & 63;
  const int w = tid >> 6;
  const int wn = w >> 1, wm = w & 1;
  const int l15 = lane & 15, lg = lane >> 4;
  const int gp0 = blockIdx.x * 128;           // 1024 blocks
  const int b = gp0 >> 14, hw0 = gp0 & 16383;

  float vA[24], vB[24];
  float sA = 0.f, qA = 0.f, sB = 0.f, qB = 0.f;
#pragma unroll
  for (int i = 0; i < 24; ++i) {
    int k = w + 4 * i;
    const float* yp = y3 + ((size_t)(b * 96 + k)) * HW + hw0;
    float bk = lin3b[k];
    float tA = yp[lane] + bk;      vA[i] = tA; sA += tA; qA = fmaf(tA, tA, qA);
    float tB = yp[lane + 64] + bk; vB[i] = tB; sB += tB; qB = fmaf(tB, tB, qB);
  }
  red[w][lane] = make_float2(sA, qA);
  red[w][lane + 64] = make_float2(sB, qB);
  __syncthreads();
  float2 a0 = red[0][lane], a1 = red[1][lane], a2 = red[2][lane], a3 = red[3][lane];
  float2 b0 = red[0][lane + 64], b1 = red[1][lane + 64], b2_ = red[2][lane + 64], b3 = red[3][lane + 64];
  float muA = (a0.x + a1.x + a2.x + a3.x) * (1.f / 96.f);
  float vrA = (a0.y + a1.y + a2.y + a3.y) * (1.f / 96.f) - muA * muA;
  float invA = rsqrtf(fmaxf(vrA, 0.f) + 1e-5f);
  float muB = (b0.x + b1.x + b2_.x + b3.x) * (1.f / 96.f);
  float vrB = (b0.y + b1.y + b2_.y + b3.y) * (1.f / 96.f) - muB * muB;
  float invB = rsqrtf(fmaxf(vrB, 0.f) + 1e-5f);
#pragma unroll
  for (int i = 0; i < 24; ++i) {
    int k = w + 4 * i;
    const float* zp = z + (size_t)k * BHW + gp0;
    float g = lng[k], bb = lnb[k];
    float zA = zp[lane];
    float uA = (vA[i] - muA) * invA * g + bb;
    Ds2[lane * 98 + k] = packhl(uA * (zA / (1.f + expf(-zA))));
    float zB = zp[lane + 64];
    float uB = (vB[i] - muB) * invB * g + bb;
    Ds2[(lane + 64) * 98 + k] = packhl(uB * (zB / (1.f + expf(-zB))));
  }
  __syncthreads();

  f32x4 acc2[3][4];
#pragma unroll
  for (int i = 0; i < 3; ++i) {
    float bv[4];
#pragma unroll
    for (int r = 0; r < 4; ++r) bv[r] = outb[16 * (3 * wn + i) + 4 * lg + r];
#pragma unroll
    for (int j = 0; j < 4; ++j)
#pragma unroll
      for (int r = 0; r < 4; ++r) acc2[i][j][r] = bv[r];
  }
#pragma unroll
  for (int ksl = 0; ksl < 3; ++ksl) {
    s8bf Dhi[4], Dlo[4];
#pragma unroll
    for (int j = 0; j < 4; ++j) {
      const uint32_t* p = Ds2 + (16 * (4 * wm + j) + l15) * 98 + 32 * ksl + 8 * lg;
      uint32_t wv[8];
      *(uint2*)&wv[0] = *(const uint2*)(p);
      *(uint2*)&wv[2] = *(const uint2*)(p + 2);
      *(uint2*)&wv[4] = *(const uint2*)(p + 4);
      *(uint2*)&wv[6] = *(const uint2*)(p + 6);
      unpack8(wv, Dhi[j], Dlo[j]);
    }
#pragma unroll
    for (int i = 0; i < 3; ++i) {
      int base = (((3 * wn + i) * 3 + ksl) * 64 + lane) * 4;
      FragU H, L;
      *(uint4*)H.u = *(const uint4*)(WOh + base);
      *(uint4*)L.u = *(const uint4*)(WOl + base);
#pragma unroll
      for (int j = 0; j < 4; ++j) {
        acc2[i][j] = __builtin_amdgcn_mfma_f32_16x16x32_bf16(H.s, Dhi[j], acc2[i][j], 0, 0, 0);
        acc2[i][j] = __builtin_amdgcn_mfma_f32_16x16x32_bf16(H.s, Dlo[j], acc2[i][j], 0, 0, 0);
        acc2[i][j] = __builtin_amdgcn_mfma_f32_16x16x32_bf16(L.s, Dhi[j], acc2[i][j], 0, 0, 0);
      }
    }
  }
#pragma unroll
  for (int i = 0; i < 3; ++i) {
    int d0 = 16 * (3 * wn + i) + 4 * lg;
#pragma unroll
    for (int j = 0; j < 4; ++j) {
      int hw = hw0 + 16 * (4 * wm + j) + l15;
#pragma unroll
      for (int r = 0; r < 4; ++r)
        out[((size_t)(b * 96 + d0 + r)) * HW + hw] = acc2[i][j][r];
    }
  }
}

extern "C" void kernel_launch(void* const* d_in, const int* in_sizes, int n_in,
                              void* d_out, int out_size, void* d_ws, size_t ws_size,
                              hipStream_t stream) {
  const float* x      = (const float*)d_in[0];
  const float* fe     = (const float*)d_in[1];
  const float* of     = (const float*)d_in[2];
  const float* dw_w   = (const float*)d_in[3];
  const float* dw_b   = (const float*)d_in[4];
  const float* lin_w  = (const float*)d_in[5];
  const float* lin_b  = (const float*)d_in[6];
  const float* k_w    = (const float*)d_in[7];
  const float* k_b    = (const float*)d_in[8];
  const float* lin2_w = (const float*)d_in[9];
  const float* lin2_b = (const float*)d_in[10];
  const float* k2_w   = (const float*)d_in[11];
  const float* k2_b   = (const float*)d_in[12];
  const float* lin3_w = (const float*)d_in[13];
  const float* lin3_b = (const float*)d_in[14];
  const float* ln_g   = (const float*)d_in[15];
  const float* ln_b   = (const float*)d_in[16];
  const float* out_w  = (const float*)d_in[17];
  const float* out_b  = (const float*)d_in[18];
  float* out = (float*)d_out;

  float* ws    = (float*)d_ws;
  float* x1p   = ws;                      // [B][96][HW]: x1 -> S1 -> Tf -> y3 (in-place chain)
  float* z     = x1p   + 12582912;        // [96][B*HW] plane-major
  float* ofp   = z     + 12582912;        // [B][96][HW]: xc -> outline planes -> Ohat'
  float* cm    = ofp   + 12582912;        // [192][HW]: lower = idct(mean S1), upper = mean outline
  float* skf   = cm    + 3145728;         // [192][HW] (first 96 planes reused as cmSf scratch)
  float* P1    = skf   + 3145728;         // [96][HW]
  float* P2    = P1    + 1572864;         // [192][HW]
  float* cc    = P2    + 3145728;         // [128][128] (unused)
  float* ee    = cc    + 16384;           // [128][128]
  float* linT  = ee    + 16384;           // (unused)
  float* kT    = linT  + 18432;           // [96][96]
  float* lin2T = kT    + 9216;            // [192][192]
  float* k2T   = lin2T + 36864;           // [192][192]
  float* lin3T = k2T   + 36864;           // (unused)
  float* outT  = lin3T + 18432;           // (unused)
  float* fet   = outT  + 9216;            // [96][HW]
  uint32_t* FAh = (uint32_t*)(fet + 1572864);  // 8192 u32 each
  uint32_t* FAl = FAh + 8192;
  uint32_t* FTh = FAl + 8192;
  uint32_t* FTl = FTh + 8192;
  uint32_t* WLh = FTl + 8192;             // lin frags:  12x3x64x4 = 9216 u32
  uint32_t* WLl = WLh + 9216;
  uint32_t* W3h = WLl + 9216;             // lin3 frags: 6x6x64x4 = 9216
  uint32_t* W3l = W3h + 9216;
  uint32_t* WOh = W3l + 9216;             // out frags:  6x3x64x4 = 4608
  uint32_t* WOl = WOh + 4608;
  float* xc    = ofp;                     // aliases ofp: dead after klin, before k3
  float* cmSf  = skf;                     // [96][HW] temp: mean_b(S1)
  (void)in_sizes; (void)n_in; (void)out_size; (void)ws_size;

  k0_tables<<<64, 256, 0, stream>>>(cc, ee);
  k0_frags<<<8, 256, 0, stream>>>(FAh, FAl, FTh, FTl);
  k_wfrag<<<9, 256, 0, stream>>>(lin_w, WLh, WLl, 192, 96);
  k_wfrag<<<9, 256, 0, stream>>>(lin3_w, W3h, W3l, 96, 192);
  k_wfrag<<<5, 256, 0, stream>>>(out_w, WOh, WOl, 96, 96);
  k_wt<<<36, 256, 0, stream>>>(k_w, kT, 96, 96);
  k_wt<<<144, 256, 0, stream>>>(lin2_w, lin2T, 192, 192);
  k_wt<<<144, 256, 0, stream>>>(k2_w, k2T, 192, 192);
  k_tfe<<<256, 256, 0, stream>>>(fe, fet);

  kconv<<<12288, 256, 0, stream>>>(x, dw_w, dw_b, xc);
  klin_mfma<<<2048, 256, 0, stream>>>(xc, WLh, WLl, lin_b, x1p, z);
  k3_transpose_mean<<<256, 256, 0, stream>>>(of, ofp, cm + (size_t)96 * HW);
  k3b_kgemm<<<256, 256, 0, stream>>>(fet, cm + (size_t)96 * HW, kT, k_b, ee, P1);
  // S1 = P1 .* dct2(x1)   (in-place in x1p)
  heat_half<true><<<768, 256, 0, stream>>>(x1p, x1p, P1, FAh, FAl, 96);
  // mean_b(y1) = idct2(mean_b(S1))
  k5_mean<<<6144, 256, 0, stream>>>(x1p, cmSf);
  heat_half<false><<<96, 256, 0, stream>>>(cmSf, cm, nullptr, FTh, FTl, 96);
  // P2 (k6+k7 fused)
  k67<<<256, 256, 0, stream>>>(cm, lin2T, lin2_b, k2T, k2_b, ee, P2);
  // Ohat' = dct2(outline) .* P2hi  (in-place in ofp, P2 fold into epilogue)
  heat_half<true><<<768, 256, 0, stream>>>(ofp, ofp, P2 + (size_t)96 * HW, FAh, FAl, 96);
  // Tf = (concat[S1*P2lo, Ohat']) @ lin3^T  (in-place into x1p)
  kmix<<<1024, 256, 0, stream>>>(x1p, ofp, P2, W3h, W3l, x1p);
  // y3 = idct2(Tf)  (in-place in x1p)
  heat_half<false><<<768, 256, 0, stream>>>(x1p, x1p, nullptr, FTh, FTl, 96);
  k9r<<<1024, 256, 0, stream>>>(x1p, z, lin3_b, ln_g, ln_b, WOh, WOl, out_b, out);
}

// Round 11
// 461.600 us; speedup vs baseline: 1.0176x; 1.0176x over previous
//
#include <hip/hip_runtime.h>
#include <math.h>
#include <stdint.h>

#ifndef M_PI
#define M_PI 3.14159265358979323846
#endif

#define HW 16384
#define BHW 131072

typedef __attribute__((ext_vector_type(8))) short s8bf;    // 8 bf16 = 4 VGPR
typedef __attribute__((ext_vector_type(4))) float f32x4;   // MFMA C/D

union FragU { uint32_t u[4]; s8bf s; };

// ---------- bf16 split helpers ----------
__device__ __forceinline__ uint32_t bf16h(float x) {
  uint32_t u = __float_as_uint(x);
  return (u + 0x7FFFu + ((u >> 16) & 1u)) >> 16;     // RNE, low 16 bits
}
__device__ __forceinline__ uint32_t packhl(float x) {  // u32 = (hi<<16)|lo
  uint32_t h = bf16h(x);
  float r = x - __uint_as_float(h << 16);
  return (h << 16) | bf16h(r);
}
__device__ __forceinline__ void unpack8(const uint32_t* w, s8bf& hi, s8bf& lo) {
  FragU H, L;
#pragma unroll
  for (int j = 0; j < 4; ++j) {
    H.u[j] = __builtin_amdgcn_perm(w[2 * j + 1], w[2 * j], 0x07060302u);
    L.u[j] = __builtin_amdgcn_perm(w[2 * j + 1], w[2 * j], 0x05040100u);
  }
  hi = H.s; lo = L.s;
}

// ---------- tables ----------
__global__ void k0_tables(float* __restrict__ cc, float* __restrict__ ee) {
  int gid = blockIdx.x * 256 + threadIdx.x;   // 16384
  int n = gid >> 7, m = gid & 127;
  double v = cos((double)n * ((double)m + 0.5) * (M_PI / 128.0)) * sqrt(2.0 / 128.0);
  if (n == 0) v *= 0.70710678118654752440;
  cc[gid] = (float)v;
  double wn = (double)n * (M_PI / 128.0), wm = (double)m * (M_PI / 128.0);
  ee[gid] = (float)(wn * wn + wm * wm);
}

// ---------- DCT matrix fragment constants (A-operand order, hi/lo split) ----------
__device__ __forceinline__ float cval(int a, int b) {
  double v = cos((double)a * ((double)b + 0.5) * (M_PI / 128.0)) * sqrt(2.0 / 128.0);
  if (a == 0) v *= 0.70710678118654752440;
  return (float)v;
}
__global__ void k0_frags(uint32_t* __restrict__ FAh, uint32_t* __restrict__ FAl,
                         uint32_t* __restrict__ FTh, uint32_t* __restrict__ FTl) {
  int tid = blockIdx.x * 256 + threadIdx.x;   // 2048
  int lane = tid & 63, fid = tid >> 6;
  int mt = fid >> 2, ks = fid & 3;
  int n = 16 * mt + (lane & 15);
  int k0 = 32 * ks + 8 * (lane >> 4);
#pragma unroll
  for (int j = 0; j < 4; ++j) {
    float a0 = cval(n, k0 + 2 * j), a1 = cval(n, k0 + 2 * j + 1);
    uint32_t p0 = packhl(a0), p1 = packhl(a1);
    FAh[tid * 4 + j] = (p0 >> 16) | (p1 & 0xFFFF0000u);
    FAl[tid * 4 + j] = (p0 & 0xFFFFu) | (p1 << 16);
    float b0 = cval(k0 + 2 * j, n), b1 = cval(k0 + 2 * j + 1, n);
    uint32_t q0 = packhl(b0), q1 = packhl(b1);
    FTh[tid * 4 + j] = (q0 >> 16) | (q1 & 0xFFFF0000u);
    FTl[tid * 4 + j] = (q0 & 0xFFFFu) | (q1 << 16);
  }
}

// ---------- generic weight A-frag builder: W[D][K] row-major -> hi/lo frags ----------
__global__ void k_wfrag(const float* __restrict__ src, uint32_t* __restrict__ Fh,
                        uint32_t* __restrict__ Fl, int D, int K) {
  int tid = blockIdx.x * 256 + threadIdx.x;
  int nksl = K >> 5;
  int total = (D >> 4) * nksl * 64;
  if (tid >= total) return;
  int lane = tid & 63, fid = tid >> 6;
  int nt = fid / nksl, ksl = fid - nt * nksl;
  int d = 16 * nt + (lane & 15);
  int k0 = 32 * ksl + 8 * (lane >> 4);
#pragma unroll
  for (int j = 0; j < 4; ++j) {
    uint32_t p0 = packhl(src[d * K + k0 + 2 * j]);
    uint32_t p1 = packhl(src[d * K + k0 + 2 * j + 1]);
    Fh[tid * 4 + j] = (p0 >> 16) | (p1 & 0xFFFF0000u);
    Fl[tid * 4 + j] = (p0 & 0xFFFFu) | (p1 << 16);
  }
}

// ---------- generic weight transpose: src[D][C] -> dst[C][D] ----------
__global__ void k_wt(const float* __restrict__ src, float* __restrict__ dst, int D, int C) {
  int gid = blockIdx.x * 256 + threadIdx.x;
  if (gid >= D * C) return;
  int d = gid / C, c = gid % C;
  dst[c * D + d] = src[gid];
}

// ---------- fe transpose: [HW][96] -> [96][HW] ----------
__global__ __launch_bounds__(256) void k_tfe(const float* __restrict__ fe,
                                             float* __restrict__ fet) {
  __shared__ float tile[64 * 97];
  int hw0 = blockIdx.x * 64;
  int tid = threadIdx.x;
#pragma unroll
  for (int t = 0; t < 24; ++t) {
    int l = tid + t * 256;
    int r = l / 96, c0 = l % 96;
    tile[r * 97 + c0] = fe[((size_t)hw0 + r) * 96 + c0];
  }
  __syncthreads();
#pragma unroll
  for (int t = 0; t < 24; ++t) {
    int l = tid + t * 256;
    int c0 = l >> 6, r = l & 63;
    fet[(size_t)c0 * HW + hw0 + r] = tile[r * 97 + c0];
  }
}

// ---------- KC: depthwise 3x3 conv, float4 per thread, plane-major out ----------
__global__ __launch_bounds__(256) void kconv(
    const float* __restrict__ x, const float* __restrict__ dw_w,
    const float* __restrict__ dw_b, float* __restrict__ xc) {
  int gid = blockIdx.x * 256 + threadIdx.x;   // B*96*4096 = 3145728
  int p = gid >> 12;                          // plane b*96+c
  int q = gid & 4095;
  int h = q >> 5, w4 = (q & 31) << 2;
  int c = p % 96;
  const float* pw = dw_w + c * 9;
  const float* row = x + (size_t)p * HW + h * 128 + w4;
  bool tp = h > 0, bt = h < 127, lf = w4 > 0, rt = w4 < 124;
  float4 t_, m_, b_;
  float tl, tr, ml, mr, bl, br;
  m_ = *(const float4*)row;
  ml = lf ? row[-1] : 0.f;
  mr = rt ? row[4] : 0.f;
  if (tp) {
    t_ = *(const float4*)(row - 128);
    tl = lf ? row[-129] : 0.f;
    tr = rt ? row[-124] : 0.f;
  } else { t_ = make_float4(0.f, 0.f, 0.f, 0.f); tl = tr = 0.f; }
  if (bt) {
    b_ = *(const float4*)(row + 128);
    bl = lf ? row[127] : 0.f;
    br = rt ? row[132] : 0.f;
  } else { b_ = make_float4(0.f, 0.f, 0.f, 0.f); bl = br = 0.f; }
  float w0 = pw[0], w1 = pw[1], w2 = pw[2], w3 = pw[3], w4w = pw[4],
        w5 = pw[5], w6 = pw[6], w7 = pw[7], w8 = pw[8];
  float bias = dw_b[c];
  float4 o;
  o.x = tl * w0 + t_.x * w1 + t_.y * w2 + ml * w3 + m_.x * w4w + m_.y * w5 + bl * w6 + b_.x * w7 + b_.y * w8 + bias;
  o.y = t_.x * w0 + t_.y * w1 + t_.z * w2 + m_.x * w3 + m_.y * w4w + m_.z * w5 + b_.x * w6 + b_.y * w7 + b_.z * w8 + bias;
  o.z = t_.y * w0 + t_.z * w1 + t_.w * w2 + m_.y * w3 + m_.z * w4w + m_.w * w5 + b_.y * w6 + b_.z * w7 + b_.w * w8 + bias;
  o.w = t_.z * w0 + t_.w * w1 + tr * w2 + m_.z * w3 + m_.w * w4w + mr * w5 + b_.z * w6 + b_.w * w7 + br * w8 + bias;
  *(float4*)(xc + (size_t)p * HW + h * 128 + w4) = o;
}

// ---------- KL-MFMA: [B*HW,96] @ lin_w^T -> x1 planes + z planes ----------
__global__ __launch_bounds__(256) void klin_mfma(
    const float* __restrict__ xc, const uint32_t* __restrict__ WLh,
    const uint32_t* __restrict__ WLl, const float* __restrict__ lin_b,
    float* __restrict__ x1p, float* __restrict__ z) {
  __shared__ uint32_t Ds[64 * 102];   // [m][k], 26 KB
  const int tid = threadIdx.x;
  const int lane = tid & 63;
  const int w = tid >> 6;
  const int l15 = lane & 15, lg = lane >> 4;
  const int gp0 = blockIdx.x * 64;
  const int b = gp0 >> 14, hw0 = gp0 & 16383;

#pragma unroll
  for (int i = 0; i < 24; ++i) {      // stage xc -> Ds[m*102+k]
    int k = w + 4 * i;
    float v = xc[((size_t)(b * 96 + k)) * HW + hw0 + lane];
    Ds[lane * 102 + k] = packhl(v);
  }
  __syncthreads();

  f32x4 acc[3][4];
#pragma unroll
  for (int nt = 0; nt < 3; ++nt) {
    float bv[4];
#pragma unroll
    for (int r = 0; r < 4; ++r) bv[r] = lin_b[16 * (3 * w + nt) + 4 * lg + r];
#pragma unroll
    for (int mt = 0; mt < 4; ++mt)
#pragma unroll
      for (int r = 0; r < 4; ++r) acc[nt][mt][r] = bv[r];
  }

#pragma unroll
  for (int ksl = 0; ksl < 3; ++ksl) {
    s8bf Dhi[4], Dlo[4];
#pragma unroll
    for (int mt = 0; mt < 4; ++mt) {
      const uint32_t* p = Ds + (16 * mt + l15) * 102 + 32 * ksl + 8 * lg;
      uint32_t wv[8];
      *(uint2*)&wv[0] = *(const uint2*)(p);
      *(uint2*)&wv[2] = *(const uint2*)(p + 2);
      *(uint2*)&wv[4] = *(const uint2*)(p + 4);
      *(uint2*)&wv[6] = *(const uint2*)(p + 6);
      unpack8(wv, Dhi[mt], Dlo[mt]);
    }
#pragma unroll
    for (int nt = 0; nt < 3; ++nt) {
      int base = (((3 * w + nt) * 3 + ksl) * 64 + lane) * 4;
      FragU H, L;
      *(uint4*)H.u = *(const uint4*)(WLh + base);
      *(uint4*)L.u = *(const uint4*)(WLl + base);
#pragma unroll
      for (int mt = 0; mt < 4; ++mt) {
        acc[nt][mt] = __builtin_amdgcn_mfma_f32_16x16x32_bf16(H.s, Dhi[mt], acc[nt][mt], 0, 0, 0);
        acc[nt][mt] = __builtin_amdgcn_mfma_f32_16x16x32_bf16(H.s, Dlo[mt], acc[nt][mt], 0, 0, 0);
        acc[nt][mt] = __builtin_amdgcn_mfma_f32_16x16x32_bf16(L.s, Dhi[mt], acc[nt][mt], 0, 0, 0);
      }
    }
  }
#pragma unroll
  for (int nt = 0; nt < 3; ++nt) {
    int d0 = 16 * (3 * w + nt) + 4 * lg;
#pragma unroll
    for (int mt = 0; mt < 4; ++mt) {
#pragma unroll
      for (int r = 0; r < 4; ++r) {
        int d = d0 + r;
        if (d < 96)
          x1p[((size_t)(b * 96 + d)) * HW + hw0 + 16 * mt + l15] = acc[nt][mt][r];
        else
          z[((size_t)(d - 96)) * BHW + gp0 + 16 * mt + l15] = acc[nt][mt][r];
      }
    }
  }
}

// ---------- K3: outline_feat transpose to plane-major + mean over B ----------
__global__ __launch_bounds__(256) void k3_transpose_mean(
    const float* __restrict__ of, float* __restrict__ ofp, float* __restrict__ cmU) {
  __shared__ float tile[64 * 97];
  int hw0 = blockIdx.x * 64;
  int tid = threadIdx.x;
  float sum[24];
#pragma unroll
  for (int t = 0; t < 24; ++t) sum[t] = 0.f;
  for (int b = 0; b < 8; ++b) {
    __syncthreads();
#pragma unroll
    for (int t = 0; t < 24; ++t) {
      int l = tid + t * 256;
      int r = l / 96, c0 = l % 96;
      tile[r * 97 + c0] = of[((size_t)b * 16384 + hw0 + r) * 96 + c0];
    }
    __syncthreads();
#pragma unroll
    for (int t = 0; t < 24; ++t) {
      int l = tid + t * 256;
      int c0 = l >> 6, r = l & 63;
      float v = tile[r * 97 + c0];
      sum[t] += v;
      ofp[(size_t)(b * 96 + c0) * HW + hw0 + r] = v;
    }
  }
#pragma unroll
  for (int t = 0; t < 24; ++t) {
    int l = tid + t * 256;
    int c0 = l >> 6, r = l & 63;
    cmU[(size_t)c0 * HW + hw0 + r] = sum[t] * 0.125f;
  }
}

// ---------- K3b: k = relu((fet+otm)@k_w^T + k_b); P1 = exp(-e*k) ----------
__global__ __launch_bounds__(256) void k3b_kgemm(
    const float* __restrict__ fet, const float* __restrict__ otm,
    const float* __restrict__ kT, const float* __restrict__ kb,
    const float* __restrict__ ee, float* __restrict__ P1) {
  int tid = threadIdx.x;
  int lane = tid & 63;
  int n0 = __builtin_amdgcn_readfirstlane((tid >> 6) * 24);
  int row = blockIdx.x * 64 + lane;           // 256 blocks
  float acc[24];
#pragma unroll
  for (int j = 0; j < 24; ++j) acc[j] = kb[n0 + j];
#pragma unroll 4
  for (int c = 0; c < 96; ++c) {
    float a = fet[(size_t)c * HW + row] + otm[(size_t)c * HW + row];
    const float* wr = kT + c * 96 + n0;
#pragma unroll
    for (int j = 0; j < 24; ++j) acc[j] = fmaf(a, wr[j], acc[j]);
  }
  float er = ee[row];
#pragma unroll
  for (int j = 0; j < 24; ++j)
    P1[(size_t)(n0 + j) * HW + row] = expf(-er * fmaxf(acc[j], 0.f));
}

// ---------- MFMA transform primitives ----------
template <bool DATA_A>
__device__ __forceinline__ void heat_step(
    const uint32_t* __restrict__ Fh, const uint32_t* __restrict__ Fl,
    const uint32_t* __restrict__ Ds, f32x4 (&acc)[4][4], int wm, int wn, int lane) {
  const int l15 = lane & 15, lg = lane >> 4;
  const int wd = DATA_A ? wm : wn;
  const int wf = DATA_A ? wn : wm;
#pragma unroll
  for (int ksl = 0; ksl < 4; ++ksl) {
    s8bf Dhi[4], Dlo[4], Fhi[4], Flo[4];
#pragma unroll
    for (int t = 0; t < 4; ++t) {
      const uint32_t* p = Ds + (64 * wd + 16 * t + l15) * 130 + 32 * ksl + 8 * lg;
      uint32_t wv[8];
      *(uint2*)&wv[0] = *(const uint2*)(p);
      *(uint2*)&wv[2] = *(const uint2*)(p + 2);
      *(uint2*)&wv[4] = *(const uint2*)(p + 4);
      *(uint2*)&wv[6] = *(const uint2*)(p + 6);
      unpack8(wv, Dhi[t], Dlo[t]);
    }
#pragma unroll
    for (int t = 0; t < 4; ++t) {
      int base = (((4 * wf + t) * 4 + ksl) * 64 + lane) * 4;
      FragU H, L;
      *(uint4*)H.u = *(const uint4*)(Fh + base);
      *(uint4*)L.u = *(const uint4*)(Fl + base);
      Fhi[t] = H.s; Flo[t] = L.s;
    }
    const s8bf* Ah = DATA_A ? Dhi : Fhi;
    const s8bf* Al = DATA_A ? Dlo : Flo;
    const s8bf* Bh = DATA_A ? Fhi : Dhi;
    const s8bf* Bl = DATA_A ? Flo : Dlo;
#pragma unroll
    for (int mi = 0; mi < 4; ++mi)
#pragma unroll
      for (int ni = 0; ni < 4; ++ni)
        acc[mi][ni] = __builtin_amdgcn_mfma_f32_16x16x32_bf16(Ah[mi], Bh[ni], acc[mi][ni], 0, 0, 0);
#pragma unroll
    for (int mi = 0; mi < 4; ++mi)
#pragma unroll
      for (int ni = 0; ni < 4; ++ni)
        acc[mi][ni] = __builtin_amdgcn_mfma_f32_16x16x32_bf16(Ah[mi], Bl[ni], acc[mi][ni], 0, 0, 0);
#pragma unroll
    for (int mi = 0; mi < 4; ++mi)
#pragma unroll
      for (int ni = 0; ni < 4; ++ni)
        acc[mi][ni] = __builtin_amdgcn_mfma_f32_16x16x32_bf16(Al[mi], Bh[ni], acc[mi][ni], 0, 0, 0);
  }
}

// ---------- heat_half: Out = F * In * F^T (2 matmuls), optional P multiply ----------
template <bool USE_P>
__global__ __launch_bounds__(256, 2) void heat_half(
    const float* __restrict__ In, float* __restrict__ Out,
    const float* __restrict__ P, const uint32_t* __restrict__ Fh,
    const uint32_t* __restrict__ Fl, int Cmod) {
  __shared__ uint32_t Ds[128 * 130];
  const int tid = threadIdx.x;
  const int lane = tid & 63;
  const int w = tid >> 6;
  const int wm = w >> 1, wn = w & 1;
  const int l15 = lane & 15, lg = lane >> 4;
  const float* Ip = In + (size_t)blockIdx.x * HW;
  float* Op = Out + (size_t)blockIdx.x * HW;
  const float* Pp = nullptr;
  if constexpr (USE_P) Pp = P + (size_t)(blockIdx.x % Cmod) * HW;

  {
    int col = tid & 127, r0 = tid >> 7;
#pragma unroll
    for (int i = 0; i < 64; ++i) {
      int row = r0 + 2 * i;
      Ds[col * 130 + row] = packhl(Ip[row * 128 + col]);
    }
  }
  __syncthreads();

  f32x4 acc[4][4];
  const f32x4 zero4 = {0.f, 0.f, 0.f, 0.f};
#pragma unroll
  for (int mi = 0; mi < 4; ++mi)
#pragma unroll
    for (int ni = 0; ni < 4; ++ni) acc[mi][ni] = zero4;
  heat_step<false>(Fh, Fl, Ds, acc, wm, wn, lane);     // T = F * In
  __syncthreads();
#pragma unroll
  for (int mi = 0; mi < 4; ++mi)
#pragma unroll
    for (int ni = 0; ni < 4; ++ni)
#pragma unroll
      for (int r = 0; r < 4; ++r)
        Ds[(64 * wm + 16 * mi + 4 * lg + r) * 130 + 64 * wn + 16 * ni + l15] =
            packhl(acc[mi][ni][r]);
  __syncthreads();

#pragma unroll
  for (int mi = 0; mi < 4; ++mi)
#pragma unroll
    for (int ni = 0; ni < 4; ++ni) acc[mi][ni] = zero4;
  heat_step<true>(Fh, Fl, Ds, acc, wm, wn, lane);      // Out = T * F^T
#pragma unroll
  for (int mi = 0; mi < 4; ++mi)
#pragma unroll
    for (int ni = 0; ni < 4; ++ni) {
      int row = 64 * wm + 16 * mi + 4 * lg;
      int col = 64 * wn + 16 * ni + l15;
#pragma unroll
      for (int r = 0; r < 4; ++r) {
        float v = acc[mi][ni][r];
        if constexpr (USE_P) v *= Pp[(row + r) * 128 + col];
        Op[(row + r) * 128 + col] = v;
      }
    }
}

// ---------- K5: plane-mean over batch: dst[c][s] = mean_b src[b*96+c][s] ----------
__global__ void k5_mean(const float* __restrict__ src, float* __restrict__ dst) {
  int idx = blockIdx.x * 256 + threadIdx.x;
  int c = idx >> 14, s = idx & 16383;
  float sum = 0.f;
#pragma unroll
  for (int b = 0; b < 8; ++b) sum += src[(size_t)(b * 96 + c) * HW + s];
  dst[idx] = sum * 0.125f;
}

// ---------- K67: skf = cm@lin2^T+b2 (LDS); k2 = relu(skf@k2^T+b2k); P2 = exp(-e*k2) ----------
__global__ __launch_bounds__(256) void k67(
    const float* __restrict__ cm, const float* __restrict__ w2T,
    const float* __restrict__ b2, const float* __restrict__ k2T,
    const float* __restrict__ b2k, const float* __restrict__ ee,
    float* __restrict__ P2) {
  __shared__ float skf_s[64][193];            // 49.4 KB
  int tid = threadIdx.x;
  int lane = tid & 63;
  int n0 = __builtin_amdgcn_readfirstlane((tid >> 6) * 48);
  int row = blockIdx.x * 64 + lane;           // 256 blocks
  float acc[48];
#pragma unroll
  for (int j = 0; j < 48; ++j) acc[j] = b2[n0 + j];
#pragma unroll 4
  for (int k = 0; k < 192; ++k) {
    float a = cm[(size_t)k * HW + row];
    const float* wr = w2T + k * 192 + n0;
#pragma unroll
    for (int j = 0; j < 48; ++j) acc[j] = fmaf(a, wr[j], acc[j]);
  }
#pragma unroll
  for (int j = 0; j < 48; ++j) skf_s[lane][n0 + j] = acc[j];
  __syncthreads();
  float acc2[48];
#pragma unroll
  for (int j = 0; j < 48; ++j) acc2[j] = b2k[n0 + j];
#pragma unroll 4
  for (int k = 0; k < 192; ++k) {
    float a = skf_s[lane][k];
    const float* wr = k2T + k * 192 + n0;
#pragma unroll
    for (int j = 0; j < 48; ++j) acc2[j] = fmaf(a, wr[j], acc2[j]);
  }
  float er = ee[row];
#pragma unroll
  for (int j = 0; j < 48; ++j)
    P2[(size_t)(n0 + j) * HW + row] = expf(-er * fmaxf(acc2[j], 0.f));
}

// ---------- KMIX: Tf = (concat[S1*P2lo, Ohat'(pre-mul P2hi)]) @ lin3_w^T ----------
// 128 positions/block, K processed in two 96-chunks (LDS reused). In-place safe.
__global__ __launch_bounds__(256) void kmix(
    const float* __restrict__ S1, const float* __restrict__ OhP,
    const float* __restrict__ P2,
    const uint32_t* __restrict__ W3h, const uint32_t* __restrict__ W3l,
    float* __restrict__ Tf) {
  __shared__ uint32_t Ds[128 * 98];           // 50 KB -> 3 blocks/CU
  const int tid = threadIdx.x;
  const int lane = tid & 63;
  const int w = tid >> 6;
  const int wn = w >> 1, wm = w & 1;
  const int l15 = lane & 15, lg = lane >> 4;
  const int gp0 = blockIdx.x * 128;           // 1024 blocks
  const int b = gp0 >> 14, hw0 = gp0 & 16383;

  f32x4 acc[3][4];
#pragma unroll
  for (int i = 0; i < 3; ++i)
#pragma unroll
    for (int j = 0; j < 4; ++j)
#pragma unroll
      for (int r = 0; r < 4; ++r) acc[i][j][r] = 0.f;

#pragma unroll
  for (int c = 0; c < 2; ++c) {
    if (c) __syncthreads();                   // protect LDS reuse
#pragma unroll
    for (int i = 0; i < 24; ++i) {
      int k = w + 4 * i;
      if (c == 0) {
        const float* sp = S1 + ((size_t)(b * 96 + k)) * HW + hw0;
        const float* pp = P2 + (size_t)k * HW + hw0;
        Ds[lane * 98 + k] = packhl(sp[lane] * pp[lane]);
        Ds[(lane + 64) * 98 + k] = packhl(sp[lane + 64] * pp[lane + 64]);
      } else {
        const float* sp = OhP + ((size_t)(b * 96 + k)) * HW + hw0;
        Ds[lane * 98 + k] = packhl(sp[lane]);
        Ds[(lane + 64) * 98 + k] = packhl(sp[lane + 64]);
      }
    }
    __syncthreads();
#pragma unroll
    for (int ksl = 0; ksl < 3; ++ksl) {
      s8bf Dhi[4], Dlo[4];
#pragma unroll
      for (int j = 0; j < 4; ++j) {
        const uint32_t* p = Ds + (16 * (4 * wm + j) + l15) * 98 + 32 * ksl + 8 * lg;
        uint32_t wv[8];
        *(uint2*)&wv[0] = *(const uint2*)(p);
        *(uint2*)&wv[2] = *(const uint2*)(p + 2);
        *(uint2*)&wv[4] = *(const uint2*)(p + 4);
        *(uint2*)&wv[6] = *(const uint2*)(p + 6);
        unpack8(wv, Dhi[j], Dlo[j]);
      }
#pragma unroll
      for (int i = 0; i < 3; ++i) {
        int base = (((3 * wn + i) * 6 + 3 * c + ksl) * 64 + lane) * 4;
        FragU H, L;
        *(uint4*)H.u = *(const uint4*)(W3h + base);
        *(uint4*)L.u = *(const uint4*)(W3l + base);
#pragma unroll
        for (int j = 0; j < 4; ++j) {
          acc[i][j] = __builtin_amdgcn_mfma_f32_16x16x32_bf16(H.s, Dhi[j], acc[i][j], 0, 0, 0);
          acc[i][j] = __builtin_amdgcn_mfma_f32_16x16x32_bf16(H.s, Dlo[j], acc[i][j], 0, 0, 0);
          acc[i][j] = __builtin_amdgcn_mfma_f32_16x16x32_bf16(L.s, Dhi[j], acc[i][j], 0, 0, 0);
        }
      }
    }
  }
#pragma unroll
  for (int i = 0; i < 3; ++i) {
    int d0 = 16 * (3 * wn + i) + 4 * lg;
#pragma unroll
    for (int j = 0; j < 4; ++j) {
      int hw = hw0 + 16 * (4 * wm + j) + l15;
#pragma unroll
      for (int r = 0; r < 4; ++r)
        Tf[((size_t)(b * 96 + d0 + r)) * HW + hw] = acc[i][j][r];
    }
  }
}

// ---------- K9R: (y3 + b3) -> LN -> *silu(z) -> out GEMM (128 pos/block) ----------
__global__ __launch_bounds__(256) void k9r(
    const float* __restrict__ y3, const float* __restrict__ z,
    const float* __restrict__ lin3b,
    const float* __restrict__ lng, const float* __restrict__ lnb,
    const uint32_t* __restrict__ WOh, const uint32_t* __restrict__ WOl,
    const float* __restrict__ outb, float* __restrict__ out) {
  __shared__ uint32_t Ds2[128 * 98];          // 50 KB
  __shared__ float2 red[4][128];              // 4 KB  (total 54.2 KB -> 3 blocks/CU)
  const int tid = threadIdx.x;
  const int lane = tid & 63;
  const int w = tid >> 6;
  const int wn = w >> 1, wm = w & 1;
  const int l15 = lane & 15, lg = lane >> 4;
  const int gp0 = blockIdx.x * 128;           // 1024 blocks
  const int b = gp0 >> 14, hw0 = gp0 & 16383;

  float vA[24], vB[24];
  float sA = 0.f, qA = 0.f, sB = 0.f, qB = 0.f;
#pragma unroll
  for (int i = 0; i < 24; ++i) {
    int k = w + 4 * i;
    const float* yp = y3 + ((size_t)(b * 96 + k)) * HW + hw0;
    float bk = lin3b[k];
    float tA = yp[lane] + bk;      vA[i] = tA; sA += tA; qA = fmaf(tA, tA, qA);
    float tB = yp[lane + 64] + bk; vB[i] = tB; sB += tB; qB = fmaf(tB, tB, qB);
  }
  red[w][lane] = make_float2(sA, qA);
  red[w][lane + 64] = make_float2(sB, qB);
  __syncthreads();
  float2 a0 = red[0][lane], a1 = red[1][lane], a2 = red[2][lane], a3 = red[3][lane];
  float2 b0 = red[0][lane + 64], b1 = red[1][lane + 64], b2_ = red[2][lane + 64], b3 = red[3][lane + 64];
  float muA = (a0.x + a1.x + a2.x + a3.x) * (1.f / 96.f);
  float vrA = (a0.y + a1.y + a2.y + a3.y) * (1.f / 96.f) - muA * muA;
  float invA = rsqrtf(fmaxf(vrA, 0.f) + 1e-5f);
  float muB = (b0.x + b1.x + b2_.x + b3.x) * (1.f / 96.f);
  float vrB = (b0.y + b1.y + b2_.y + b3.y) * (1.f / 96.f) - muB * muB;
  float invB = rsqrtf(fmaxf(vrB, 0.f) + 1e-5f);
#pragma unroll
  for (int i = 0; i < 24; ++i) {
    int k = w + 4 * i;
    const float* zp = z + (size_t)k * BHW + gp0;
    float g = lng[k], bb = lnb[k];
    float zA = zp[lane];
    float uA = (vA[i] - muA) * invA * g + bb;
    Ds2[lane * 98 + k] = packhl(uA * (zA / (1.f + expf(-zA))));
    float zB = zp[lane + 64];
    float uB = (vB[i] - muB) * invB * g + bb;
    Ds2[(lane + 64) * 98 + k] = packhl(uB * (zB / (1.f + expf(-zB))));
  }
  __syncthreads();

  f32x4 acc2[3][4];
#pragma unroll
  for (int i = 0; i < 3; ++i) {
    float bv[4];
#pragma unroll
    for (int r = 0; r < 4; ++r) bv[r] = outb[16 * (3 * wn + i) + 4 * lg + r];
#pragma unroll
    for (int j = 0; j < 4; ++j)
#pragma unroll
      for (int r = 0; r < 4; ++r) acc2[i][j][r] = bv[r];
  }
#pragma unroll
  for (int ksl = 0; ksl < 3; ++ksl) {
    s8bf Dhi[4], Dlo[4];
#pragma unroll
    for (int j = 0; j < 4; ++j) {
      const uint32_t* p = Ds2 + (16 * (4 * wm + j) + l15) * 98 + 32 * ksl + 8 * lg;
      uint32_t wv[8];
      *(uint2*)&wv[0] = *(const uint2*)(p);
      *(uint2*)&wv[2] = *(const uint2*)(p + 2);
      *(uint2*)&wv[4] = *(const uint2*)(p + 4);
      *(uint2*)&wv[6] = *(const uint2*)(p + 6);
      unpack8(wv, Dhi[j], Dlo[j]);
    }
#pragma unroll
    for (int i = 0; i < 3; ++i) {
      int base = (((3 * wn + i) * 3 + ksl) * 64 + lane) * 4;
      FragU H, L;
      *(uint4*)H.u = *(const uint4*)(WOh + base);
      *(uint4*)L.u = *(const uint4*)(WOl + base);
#pragma unroll
      for (int j = 0; j < 4; ++j) {
        acc2[i][j] = __builtin_amdgcn_mfma_f32_16x16x32_bf16(H.s, Dhi[j], acc2[i][j], 0, 0, 0);
        acc2[i][j] = __builtin_amdgcn_mfma_f32_16x16x32_bf16(H.s, Dlo[j], acc2[i][j], 0, 0, 0);
        acc2[i][j] = __builtin_amdgcn_mfma_f32_16x16x32_bf16(L.s, Dhi[j], acc2[i][j], 0, 0, 0);
      }
    }
  }
#pragma unroll
  for (int i = 0; i < 3; ++i) {
    int d0 = 16 * (3 * wn + i) + 4 * lg;
#pragma unroll
    for (int j = 0; j < 4; ++j) {
      int hw = hw0 + 16 * (4 * wm + j) + l15;
#pragma unroll
      for (int r = 0; r < 4; ++r)
        out[((size_t)(b * 96 + d0 + r)) * HW + hw] = acc2[i][j][r];
    }
  }
}

extern "C" void kernel_launch(void* const* d_in, const int* in_sizes, int n_in,
                              void* d_out, int out_size, void* d_ws, size_t ws_size,
                              hipStream_t stream) {
  const float* x      = (const float*)d_in[0];
  const float* fe     = (const float*)d_in[1];
  const float* of     = (const float*)d_in[2];
  const float* dw_w   = (const float*)d_in[3];
  const float* dw_b   = (const float*)d_in[4];
  const float* lin_w  = (const float*)d_in[5];
  const float* lin_b  = (const float*)d_in[6];
  const float* k_w    = (const float*)d_in[7];
  const float* k_b    = (const float*)d_in[8];
  const float* lin2_w = (const float*)d_in[9];
  const float* lin2_b = (const float*)d_in[10];
  const float* k2_w   = (const float*)d_in[11];
  const float* k2_b   = (const float*)d_in[12];
  const float* lin3_w = (const float*)d_in[13];
  const float* lin3_b = (const float*)d_in[14];
  const float* ln_g   = (const float*)d_in[15];
  const float* ln_b   = (const float*)d_in[16];
  const float* out_w  = (const float*)d_in[17];
  const float* out_b  = (const float*)d_in[18];
  float* out = (float*)d_out;

  float* ws    = (float*)d_ws;
  float* x1p   = ws;                      // [B][96][HW]: x1 -> S1 -> Tf -> y3 (in-place chain)
  float* z     = x1p   + 12582912;        // [96][B*HW] plane-major
  float* ofp   = z     + 12582912;        // [B][96][HW]: xc -> outline planes -> Ohat'
  float* cm    = ofp   + 12582912;        // [192][HW]: lower = idct(mean S1), upper = mean outline
  float* skf   = cm    + 3145728;         // [192][HW] (first 96 planes reused as cmSf scratch)
  float* P1    = skf   + 3145728;         // [96][HW]
  float* P2    = P1    + 1572864;         // [192][HW]
  float* cc    = P2    + 3145728;         // [128][128] (unused)
  float* ee    = cc    + 16384;           // [128][128]
  float* linT  = ee    + 16384;           // (unused)
  float* kT    = linT  + 18432;           // [96][96]
  float* lin2T = kT    + 9216;            // [192][192]
  float* k2T   = lin2T + 36864;           // [192][192]
  float* lin3T = k2T   + 36864;           // (unused)
  float* outT  = lin3T + 18432;           // (unused)
  float* fet   = outT  + 9216;            // [96][HW]
  uint32_t* FAh = (uint32_t*)(fet + 1572864);  // 8192 u32 each
  uint32_t* FAl = FAh + 8192;
  uint32_t* FTh = FAl + 8192;
  uint32_t* FTl = FTh + 8192;
  uint32_t* WLh = FTl + 8192;             // lin frags:  12x3x64x4 = 9216 u32
  uint32_t* WLl = WLh + 9216;
  uint32_t* W3h = WLl + 9216;             // lin3 frags: 6x6x64x4 = 9216
  uint32_t* W3l = W3h + 9216;
  uint32_t* WOh = W3l + 9216;             // out frags:  6x3x64x4 = 4608
  uint32_t* WOl = WOh + 4608;
  float* xc    = ofp;                     // aliases ofp: dead after klin, before k3
  float* cmSf  = skf;                     // [96][HW] temp: mean_b(S1)
  (void)in_sizes; (void)n_in; (void)out_size; (void)ws_size;

  k0_tables<<<64, 256, 0, stream>>>(cc, ee);
  k0_frags<<<8, 256, 0, stream>>>(FAh, FAl, FTh, FTl);
  k_wfrag<<<9, 256, 0, stream>>>(lin_w, WLh, WLl, 192, 96);
  k_wfrag<<<9, 256, 0, stream>>>(lin3_w, W3h, W3l, 96, 192);
  k_wfrag<<<5, 256, 0, stream>>>(out_w, WOh, WOl, 96, 96);
  k_wt<<<36, 256, 0, stream>>>(k_w, kT, 96, 96);
  k_wt<<<144, 256, 0, stream>>>(lin2_w, lin2T, 192, 192);
  k_wt<<<144, 256, 0, stream>>>(k2_w, k2T, 192, 192);
  k_tfe<<<256, 256, 0, stream>>>(fe, fet);

  kconv<<<12288, 256, 0, stream>>>(x, dw_w, dw_b, xc);
  klin_mfma<<<2048, 256, 0, stream>>>(xc, WLh, WLl, lin_b, x1p, z);
  k3_transpose_mean<<<256, 256, 0, stream>>>(of, ofp, cm + (size_t)96 * HW);
  k3b_kgemm<<<256, 256, 0, stream>>>(fet, cm + (size_t)96 * HW, kT, k_b, ee, P1);
  // S1 = P1 .* dct2(x1)   (in-place in x1p)
  heat_half<true><<<768, 256, 0, stream>>>(x1p, x1p, P1, FAh, FAl, 96);
  // mean_b(y1) = idct2(mean_b(S1))
  k5_mean<<<6144, 256, 0, stream>>>(x1p, cmSf);
  heat_half<false><<<96, 256, 0, stream>>>(cmSf, cm, nullptr, FTh, FTl, 96);
  // P2 (k6+k7 fused)
  k67<<<256, 256, 0, stream>>>(cm, lin2T, lin2_b, k2T, k2_b, ee, P2);
  // Ohat' = dct2(outline) .* P2hi  (in-place in ofp, P2 fold into epilogue)
  heat_half<true><<<768, 256, 0, stream>>>(ofp, ofp, P2 + (size_t)96 * HW, FAh, FAl, 96);
  // Tf = (concat[S1*P2lo, Ohat']) @ lin3^T  (in-place into x1p)
  kmix<<<1024, 256, 0, stream>>>(x1p, ofp, P2, W3h, W3l, x1p);
  // y3 = idct2(Tf)  (in-place in x1p)
  heat_half<false><<<768, 256, 0, stream>>>(x1p, x1p, nullptr, FTh, FTl, 96);
  k9r<<<1024, 256, 0, stream>>>(x1p, z, lin3_b, ln_g, ln_b, WOh, WOl, out_b, out);
}

// Round 12
// 377.657 us; speedup vs baseline: 1.2438x; 1.2223x over previous
//
#include <hip/hip_runtime.h>
#include <math.h>
#include <stdint.h>

#ifndef M_PI
#define M_PI 3.14159265358979323846
#endif

#define HW 16384
#define BHW 131072

typedef __attribute__((ext_vector_type(8))) short s8bf;    // 8 bf16 = 4 VGPR
typedef __attribute__((ext_vector_type(4))) float f32x4;   // MFMA C/D

union FragU { uint32_t u[4]; s8bf s; };

// ---------- bf16 split helpers ----------
__device__ __forceinline__ uint32_t bf16h(float x) {
  uint32_t u = __float_as_uint(x);
  return (u + 0x7FFFu + ((u >> 16) & 1u)) >> 16;     // RNE, low 16 bits
}
__device__ __forceinline__ uint32_t packhl(float x) {  // u32 = (hi<<16)|lo
  uint32_t h = bf16h(x);
  float r = x - __uint_as_float(h << 16);
  return (h << 16) | bf16h(r);
}
__device__ __forceinline__ void unpack8(const uint32_t* w, s8bf& hi, s8bf& lo) {
  FragU H, L;
#pragma unroll
  for (int j = 0; j < 4; ++j) {
    H.u[j] = __builtin_amdgcn_perm(w[2 * j + 1], w[2 * j], 0x07060302u);
    L.u[j] = __builtin_amdgcn_perm(w[2 * j + 1], w[2 * j], 0x05040100u);
  }
  hi = H.s; lo = L.s;
}

// ---------- tables ----------
__global__ void k0_tables(float* __restrict__ cc, float* __restrict__ ee) {
  int gid = blockIdx.x * 256 + threadIdx.x;   // 16384
  int n = gid >> 7, m = gid & 127;
  double v = cos((double)n * ((double)m + 0.5) * (M_PI / 128.0)) * sqrt(2.0 / 128.0);
  if (n == 0) v *= 0.70710678118654752440;
  cc[gid] = (float)v;
  double wn = (double)n * (M_PI / 128.0), wm = (double)m * (M_PI / 128.0);
  ee[gid] = (float)(wn * wn + wm * wm);
}

// ---------- DCT matrix fragment constants (A-operand order, hi/lo split) ----------
__device__ __forceinline__ float cval(int a, int b) {
  double v = cos((double)a * ((double)b + 0.5) * (M_PI / 128.0)) * sqrt(2.0 / 128.0);
  if (a == 0) v *= 0.70710678118654752440;
  return (float)v;
}
__global__ void k0_frags(uint32_t* __restrict__ FAh, uint32_t* __restrict__ FAl,
                         uint32_t* __restrict__ FTh, uint32_t* __restrict__ FTl) {
  int tid = blockIdx.x * 256 + threadIdx.x;   // 2048
  int lane = tid & 63, fid = tid >> 6;
  int mt = fid >> 2, ks = fid & 3;
  int n = 16 * mt + (lane & 15);
  int k0 = 32 * ks + 8 * (lane >> 4);
#pragma unroll
  for (int j = 0; j < 4; ++j) {
    float a0 = cval(n, k0 + 2 * j), a1 = cval(n, k0 + 2 * j + 1);
    uint32_t p0 = packhl(a0), p1 = packhl(a1);
    FAh[tid * 4 + j] = (p0 >> 16) | (p1 & 0xFFFF0000u);
    FAl[tid * 4 + j] = (p0 & 0xFFFFu) | (p1 << 16);
    float b0 = cval(k0 + 2 * j, n), b1 = cval(k0 + 2 * j + 1, n);
    uint32_t q0 = packhl(b0), q1 = packhl(b1);
    FTh[tid * 4 + j] = (q0 >> 16) | (q1 & 0xFFFF0000u);
    FTl[tid * 4 + j] = (q0 & 0xFFFFu) | (q1 << 16);
  }
}

// ---------- generic weight A-frag builder: W[D][K] row-major -> hi/lo frags ----------
__global__ void k_wfrag(const float* __restrict__ src, uint32_t* __restrict__ Fh,
                        uint32_t* __restrict__ Fl, int D, int K) {
  int tid = blockIdx.x * 256 + threadIdx.x;
  int nksl = K >> 5;
  int total = (D >> 4) * nksl * 64;
  if (tid >= total) return;
  int lane = tid & 63, fid = tid >> 6;
  int nt = fid / nksl, ksl = fid - nt * nksl;
  int d = 16 * nt + (lane & 15);
  int k0 = 32 * ksl + 8 * (lane >> 4);
#pragma unroll
  for (int j = 0; j < 4; ++j) {
    uint32_t p0 = packhl(src[d * K + k0 + 2 * j]);
    uint32_t p1 = packhl(src[d * K + k0 + 2 * j + 1]);
    Fh[tid * 4 + j] = (p0 >> 16) | (p1 & 0xFFFF0000u);
    Fl[tid * 4 + j] = (p0 & 0xFFFFu) | (p1 << 16);
  }
}

// ---------- generic weight transpose: src[D][C] -> dst[C][D] ----------
__global__ void k_wt(const float* __restrict__ src, float* __restrict__ dst, int D, int C) {
  int gid = blockIdx.x * 256 + threadIdx.x;
  if (gid >= D * C) return;
  int d = gid / C, c = gid % C;
  dst[c * D + d] = src[gid];
}

// ---------- fe transpose: [HW][96] -> [96][HW] ----------
__global__ __launch_bounds__(256) void k_tfe(const float* __restrict__ fe,
                                             float* __restrict__ fet) {
  __shared__ float tile[64 * 97];
  int hw0 = blockIdx.x * 64;
  int tid = threadIdx.x;
#pragma unroll
  for (int t = 0; t < 24; ++t) {
    int l = tid + t * 256;
    int r = l / 96, c0 = l % 96;
    tile[r * 97 + c0] = fe[((size_t)hw0 + r) * 96 + c0];
  }
  __syncthreads();
#pragma unroll
  for (int t = 0; t < 24; ++t) {
    int l = tid + t * 256;
    int c0 = l >> 6, r = l & 63;
    fet[(size_t)c0 * HW + hw0 + r] = tile[r * 97 + c0];
  }
}

// ---------- KC: depthwise 3x3 conv, float4 per thread, plane-major out ----------
__global__ __launch_bounds__(256) void kconv(
    const float* __restrict__ x, const float* __restrict__ dw_w,
    const float* __restrict__ dw_b, float* __restrict__ xc) {
  int gid = blockIdx.x * 256 + threadIdx.x;   // B*96*4096 = 3145728
  int p = gid >> 12;                          // plane b*96+c
  int q = gid & 4095;
  int h = q >> 5, w4 = (q & 31) << 2;
  int c = p % 96;
  const float* pw = dw_w + c * 9;
  const float* row = x + (size_t)p * HW + h * 128 + w4;
  bool tp = h > 0, bt = h < 127, lf = w4 > 0, rt = w4 < 124;
  float4 t_, m_, b_;
  float tl, tr, ml, mr, bl, br;
  m_ = *(const float4*)row;
  ml = lf ? row[-1] : 0.f;
  mr = rt ? row[4] : 0.f;
  if (tp) {
    t_ = *(const float4*)(row - 128);
    tl = lf ? row[-129] : 0.f;
    tr = rt ? row[-124] : 0.f;
  } else { t_ = make_float4(0.f, 0.f, 0.f, 0.f); tl = tr = 0.f; }
  if (bt) {
    b_ = *(const float4*)(row + 128);
    bl = lf ? row[127] : 0.f;
    br = rt ? row[132] : 0.f;
  } else { b_ = make_float4(0.f, 0.f, 0.f, 0.f); bl = br = 0.f; }
  float w0 = pw[0], w1 = pw[1], w2 = pw[2], w3 = pw[3], w4w = pw[4],
        w5 = pw[5], w6 = pw[6], w7 = pw[7], w8 = pw[8];
  float bias = dw_b[c];
  float4 o;
  o.x = tl * w0 + t_.x * w1 + t_.y * w2 + ml * w3 + m_.x * w4w + m_.y * w5 + bl * w6 + b_.x * w7 + b_.y * w8 + bias;
  o.y = t_.x * w0 + t_.y * w1 + t_.z * w2 + m_.x * w3 + m_.y * w4w + m_.z * w5 + b_.x * w6 + b_.y * w7 + b_.z * w8 + bias;
  o.z = t_.y * w0 + t_.z * w1 + t_.w * w2 + m_.y * w3 + m_.z * w4w + m_.w * w5 + b_.y * w6 + b_.z * w7 + b_.w * w8 + bias;
  o.w = t_.z * w0 + t_.w * w1 + tr * w2 + m_.z * w3 + m_.w * w4w + mr * w5 + b_.z * w6 + b_.w * w7 + br * w8 + bias;
  *(float4*)(xc + (size_t)p * HW + h * 128 + w4) = o;
}

// ---------- KL-MFMA: [B*HW,96] @ lin_w^T -> x1 planes + z planes ----------
__global__ __launch_bounds__(256) void klin_mfma(
    const float* __restrict__ xc, const uint32_t* __restrict__ WLh,
    const uint32_t* __restrict__ WLl, const float* __restrict__ lin_b,
    float* __restrict__ x1p, float* __restrict__ z) {
  __shared__ uint32_t Ds[64 * 102];   // [m][k], 26 KB
  const int tid = threadIdx.x;
  const int lane = tid & 63;
  const int w = tid >> 6;
  const int l15 = lane & 15, lg = lane >> 4;
  const int gp0 = blockIdx.x * 64;
  const int b = gp0 >> 14, hw0 = gp0 & 16383;

#pragma unroll
  for (int i = 0; i < 24; ++i) {      // stage xc -> Ds[m*102+k]
    int k = w + 4 * i;
    float v = xc[((size_t)(b * 96 + k)) * HW + hw0 + lane];
    Ds[lane * 102 + k] = packhl(v);
  }
  __syncthreads();

  f32x4 acc[3][4];
#pragma unroll
  for (int nt = 0; nt < 3; ++nt) {
    float bv[4];
#pragma unroll
    for (int r = 0; r < 4; ++r) bv[r] = lin_b[16 * (3 * w + nt) + 4 * lg + r];
#pragma unroll
    for (int mt = 0; mt < 4; ++mt)
#pragma unroll
      for (int r = 0; r < 4; ++r) acc[nt][mt][r] = bv[r];
  }

#pragma unroll
  for (int ksl = 0; ksl < 3; ++ksl) {
    s8bf Dhi[4], Dlo[4];
#pragma unroll
    for (int mt = 0; mt < 4; ++mt) {
      const uint32_t* p = Ds + (16 * mt + l15) * 102 + 32 * ksl + 8 * lg;
      uint32_t wv[8];
      *(uint2*)&wv[0] = *(const uint2*)(p);
      *(uint2*)&wv[2] = *(const uint2*)(p + 2);
      *(uint2*)&wv[4] = *(const uint2*)(p + 4);
      *(uint2*)&wv[6] = *(const uint2*)(p + 6);
      unpack8(wv, Dhi[mt], Dlo[mt]);
    }
#pragma unroll
    for (int nt = 0; nt < 3; ++nt) {
      int base = (((3 * w + nt) * 3 + ksl) * 64 + lane) * 4;
      FragU H, L;
      *(uint4*)H.u = *(const uint4*)(WLh + base);
      *(uint4*)L.u = *(const uint4*)(WLl + base);
#pragma unroll
      for (int mt = 0; mt < 4; ++mt) {
        acc[nt][mt] = __builtin_amdgcn_mfma_f32_16x16x32_bf16(H.s, Dhi[mt], acc[nt][mt], 0, 0, 0);
        acc[nt][mt] = __builtin_amdgcn_mfma_f32_16x16x32_bf16(H.s, Dlo[mt], acc[nt][mt], 0, 0, 0);
        acc[nt][mt] = __builtin_amdgcn_mfma_f32_16x16x32_bf16(L.s, Dhi[mt], acc[nt][mt], 0, 0, 0);
      }
    }
  }
#pragma unroll
  for (int nt = 0; nt < 3; ++nt) {
    int d0 = 16 * (3 * w + nt) + 4 * lg;
#pragma unroll
    for (int mt = 0; mt < 4; ++mt) {
#pragma unroll
      for (int r = 0; r < 4; ++r) {
        int d = d0 + r;
        if (d < 96)
          x1p[((size_t)(b * 96 + d)) * HW + hw0 + 16 * mt + l15] = acc[nt][mt][r];
        else
          z[((size_t)(d - 96)) * BHW + gp0 + 16 * mt + l15] = acc[nt][mt][r];
      }
    }
  }
}

// ---------- K3: outline_feat transpose to plane-major + mean over B ----------
__global__ __launch_bounds__(256) void k3_transpose_mean(
    const float* __restrict__ of, float* __restrict__ ofp, float* __restrict__ cmU) {
  __shared__ float tile[64 * 97];
  int hw0 = blockIdx.x * 64;
  int tid = threadIdx.x;
  float sum[24];
#pragma unroll
  for (int t = 0; t < 24; ++t) sum[t] = 0.f;
  for (int b = 0; b < 8; ++b) {
    __syncthreads();
#pragma unroll
    for (int t = 0; t < 24; ++t) {
      int l = tid + t * 256;
      int r = l / 96, c0 = l % 96;
      tile[r * 97 + c0] = of[((size_t)b * 16384 + hw0 + r) * 96 + c0];
    }
    __syncthreads();
#pragma unroll
    for (int t = 0; t < 24; ++t) {
      int l = tid + t * 256;
      int c0 = l >> 6, r = l & 63;
      float v = tile[r * 97 + c0];
      sum[t] += v;
      ofp[(size_t)(b * 96 + c0) * HW + hw0 + r] = v;
    }
  }
#pragma unroll
  for (int t = 0; t < 24; ++t) {
    int l = tid + t * 256;
    int c0 = l >> 6, r = l & 63;
    cmU[(size_t)c0 * HW + hw0 + r] = sum[t] * 0.125f;
  }
}

// ---------- K3b: k = relu((fet+otm)@k_w^T + k_b); P1 = exp(-e*k) ----------
__global__ __launch_bounds__(256) void k3b_kgemm(
    const float* __restrict__ fet, const float* __restrict__ otm,
    const float* __restrict__ kT, const float* __restrict__ kb,
    const float* __restrict__ ee, float* __restrict__ P1) {
  int tid = threadIdx.x;
  int lane = tid & 63;
  int n0 = __builtin_amdgcn_readfirstlane((tid >> 6) * 24);
  int row = blockIdx.x * 64 + lane;           // 256 blocks
  float acc[24];
#pragma unroll
  for (int j = 0; j < 24; ++j) acc[j] = kb[n0 + j];
#pragma unroll 4
  for (int c = 0; c < 96; ++c) {
    float a = fet[(size_t)c * HW + row] + otm[(size_t)c * HW + row];
    const float* wr = kT + c * 96 + n0;
#pragma unroll
    for (int j = 0; j < 24; ++j) acc[j] = fmaf(a, wr[j], acc[j]);
  }
  float er = ee[row];
#pragma unroll
  for (int j = 0; j < 24; ++j)
    P1[(size_t)(n0 + j) * HW + row] = expf(-er * fmaxf(acc[j], 0.f));
}

// ---------- MFMA transform primitives ----------
template <bool DATA_A>
__device__ __forceinline__ void heat_step(
    const uint32_t* __restrict__ Fh, const uint32_t* __restrict__ Fl,
    const uint32_t* __restrict__ Ds, f32x4 (&acc)[4][4], int wm, int wn, int lane) {
  const int l15 = lane & 15, lg = lane >> 4;
  const int wd = DATA_A ? wm : wn;
  const int wf = DATA_A ? wn : wm;
#pragma unroll
  for (int ksl = 0; ksl < 4; ++ksl) {
    s8bf Dhi[4], Dlo[4], Fhi[4], Flo[4];
#pragma unroll
    for (int t = 0; t < 4; ++t) {
      const uint32_t* p = Ds + (64 * wd + 16 * t + l15) * 130 + 32 * ksl + 8 * lg;
      uint32_t wv[8];
      *(uint2*)&wv[0] = *(const uint2*)(p);
      *(uint2*)&wv[2] = *(const uint2*)(p + 2);
      *(uint2*)&wv[4] = *(const uint2*)(p + 4);
      *(uint2*)&wv[6] = *(const uint2*)(p + 6);
      unpack8(wv, Dhi[t], Dlo[t]);
    }
#pragma unroll
    for (int t = 0; t < 4; ++t) {
      int base = (((4 * wf + t) * 4 + ksl) * 64 + lane) * 4;
      FragU H, L;
      *(uint4*)H.u = *(const uint4*)(Fh + base);
      *(uint4*)L.u = *(const uint4*)(Fl + base);
      Fhi[t] = H.s; Flo[t] = L.s;
    }
    const s8bf* Ah = DATA_A ? Dhi : Fhi;
    const s8bf* Al = DATA_A ? Dlo : Flo;
    const s8bf* Bh = DATA_A ? Fhi : Dhi;
    const s8bf* Bl = DATA_A ? Flo : Dlo;
#pragma unroll
    for (int mi = 0; mi < 4; ++mi)
#pragma unroll
      for (int ni = 0; ni < 4; ++ni)
        acc[mi][ni] = __builtin_amdgcn_mfma_f32_16x16x32_bf16(Ah[mi], Bh[ni], acc[mi][ni], 0, 0, 0);
#pragma unroll
    for (int mi = 0; mi < 4; ++mi)
#pragma unroll
      for (int ni = 0; ni < 4; ++ni)
        acc[mi][ni] = __builtin_amdgcn_mfma_f32_16x16x32_bf16(Ah[mi], Bl[ni], acc[mi][ni], 0, 0, 0);
#pragma unroll
    for (int mi = 0; mi < 4; ++mi)
#pragma unroll
      for (int ni = 0; ni < 4; ++ni)
        acc[mi][ni] = __builtin_amdgcn_mfma_f32_16x16x32_bf16(Al[mi], Bh[ni], acc[mi][ni], 0, 0, 0);
  }
}

// ---------- heat_half: Out = F * In * F^T (2 matmuls), optional P multiply ----------
template <bool USE_P>
__global__ __launch_bounds__(256, 2) void heat_half(
    const float* __restrict__ In, float* __restrict__ Out,
    const float* __restrict__ P, const uint32_t* __restrict__ Fh,
    const uint32_t* __restrict__ Fl, int Cmod) {
  __shared__ uint32_t Ds[128 * 130];
  const int tid = threadIdx.x;
  const int lane = tid & 63;
  const int w = tid >> 6;
  const int wm = w >> 1, wn = w & 1;
  const int l15 = lane & 15, lg = lane >> 4;
  const float* Ip = In + (size_t)blockIdx.x * HW;
  float* Op = Out + (size_t)blockIdx.x * HW;
  const float* Pp = nullptr;
  if constexpr (USE_P) Pp = P + (size_t)(blockIdx.x % Cmod) * HW;

  {
    int col = tid & 127, r0 = tid >> 7;
#pragma unroll
    for (int i = 0; i < 64; ++i) {
      int row = r0 + 2 * i;
      Ds[col * 130 + row] = packhl(Ip[row * 128 + col]);
    }
  }
  __syncthreads();

  f32x4 acc[4][4];
  const f32x4 zero4 = {0.f, 0.f, 0.f, 0.f};
#pragma unroll
  for (int mi = 0; mi < 4; ++mi)
#pragma unroll
    for (int ni = 0; ni < 4; ++ni) acc[mi][ni] = zero4;
  heat_step<false>(Fh, Fl, Ds, acc, wm, wn, lane);     // T = F * In
  __syncthreads();
#pragma unroll
  for (int mi = 0; mi < 4; ++mi)
#pragma unroll
    for (int ni = 0; ni < 4; ++ni)
#pragma unroll
      for (int r = 0; r < 4; ++r)
        Ds[(64 * wm + 16 * mi + 4 * lg + r) * 130 + 64 * wn + 16 * ni + l15] =
            packhl(acc[mi][ni][r]);
  __syncthreads();

#pragma unroll
  for (int mi = 0; mi < 4; ++mi)
#pragma unroll
    for (int ni = 0; ni < 4; ++ni) acc[mi][ni] = zero4;
  heat_step<true>(Fh, Fl, Ds, acc, wm, wn, lane);      // Out = T * F^T
#pragma unroll
  for (int mi = 0; mi < 4; ++mi)
#pragma unroll
    for (int ni = 0; ni < 4; ++ni) {
      int row = 64 * wm + 16 * mi + 4 * lg;
      int col = 64 * wn + 16 * ni + l15;
#pragma unroll
      for (int r = 0; r < 4; ++r) {
        float v = acc[mi][ni][r];
        if constexpr (USE_P) v *= Pp[(row + r) * 128 + col];
        Op[(row + r) * 128 + col] = v;
      }
    }
}

// ---------- K5: plane-mean over batch: dst[c][s] = mean_b src[b*96+c][s] ----------
__global__ void k5_mean(const float* __restrict__ src, float* __restrict__ dst) {
  int idx = blockIdx.x * 256 + threadIdx.x;
  int c = idx >> 14, s = idx & 16383;
  float sum = 0.f;
#pragma unroll
  for (int b = 0; b < 8; ++b) sum += src[(size_t)(b * 96 + c) * HW + s];
  dst[idx] = sum * 0.125f;
}

// ---------- K67-MFMA: skf = cm@lin2^T+b2; k2 = relu(skf@k2^T+b2k); P2 = exp(-e*k2) ----------
// 64 rows/block, 256 blocks; two MFMA phases sharing one LDS buffer.
__global__ __launch_bounds__(256) void k67_mfma(
    const float* __restrict__ cm,
    const uint32_t* __restrict__ W2h, const uint32_t* __restrict__ W2l,
    const float* __restrict__ b2,
    const uint32_t* __restrict__ K2h, const uint32_t* __restrict__ K2l,
    const float* __restrict__ b2k, const float* __restrict__ ee,
    float* __restrict__ P2) {
  __shared__ uint32_t Ds[64 * 194];           // 48.5 KB
  const int tid = threadIdx.x;
  const int lane = tid & 63;
  const int w = tid >> 6;
  const int l15 = lane & 15, lg = lane >> 4;
  const int row0 = blockIdx.x * 64;           // 256 blocks

#pragma unroll
  for (int i = 0; i < 48; ++i) {              // stage cm -> Ds[m*194+k]
    int k = w + 4 * i;
    Ds[lane * 194 + k] = packhl(cm[(size_t)k * HW + row0 + lane]);
  }
  __syncthreads();

  // phase A: skf = cm @ lin2^T + b2  (K=192, N=192; wave owns n-tiles 3w..3w+2)
  f32x4 acc[3][4];
#pragma unroll
  for (int nt = 0; nt < 3; ++nt) {
    float bv[4];
#pragma unroll
    for (int r = 0; r < 4; ++r) bv[r] = b2[16 * (3 * w + nt) + 4 * lg + r];
#pragma unroll
    for (int mt = 0; mt < 4; ++mt)
#pragma unroll
      for (int r = 0; r < 4; ++r) acc[nt][mt][r] = bv[r];
  }
#pragma unroll
  for (int ksl = 0; ksl < 6; ++ksl) {
    s8bf Dhi[4], Dlo[4];
#pragma unroll
    for (int mt = 0; mt < 4; ++mt) {
      const uint32_t* p = Ds + (16 * mt + l15) * 194 + 32 * ksl + 8 * lg;
      uint32_t wv[8];
      *(uint2*)&wv[0] = *(const uint2*)(p);
      *(uint2*)&wv[2] = *(const uint2*)(p + 2);
      *(uint2*)&wv[4] = *(const uint2*)(p + 4);
      *(uint2*)&wv[6] = *(const uint2*)(p + 6);
      unpack8(wv, Dhi[mt], Dlo[mt]);
    }
#pragma unroll
    for (int nt = 0; nt < 3; ++nt) {
      int base = (((3 * w + nt) * 6 + ksl) * 64 + lane) * 4;
      FragU H, L;
      *(uint4*)H.u = *(const uint4*)(W2h + base);
      *(uint4*)L.u = *(const uint4*)(W2l + base);
#pragma unroll
      for (int mt = 0; mt < 4; ++mt) {
        acc[nt][mt] = __builtin_amdgcn_mfma_f32_16x16x32_bf16(H.s, Dhi[mt], acc[nt][mt], 0, 0, 0);
        acc[nt][mt] = __builtin_amdgcn_mfma_f32_16x16x32_bf16(H.s, Dlo[mt], acc[nt][mt], 0, 0, 0);
        acc[nt][mt] = __builtin_amdgcn_mfma_f32_16x16x32_bf16(L.s, Dhi[mt], acc[nt][mt], 0, 0, 0);
      }
    }
  }
  __syncthreads();                            // all phase-A LDS reads complete
  // write skf back: Ds[m*194 + d]
#pragma unroll
  for (int nt = 0; nt < 3; ++nt) {
    int d0 = 16 * (3 * w + nt) + 4 * lg;
#pragma unroll
    for (int mt = 0; mt < 4; ++mt) {
      int col = 16 * mt + l15;
#pragma unroll
      for (int r = 0; r < 4; ++r)
        Ds[col * 194 + d0 + r] = packhl(acc[nt][mt][r]);
    }
  }
  __syncthreads();

  // phase B: k2 = skf @ k2_w^T + b2k; P2 = exp(-ee * relu(k2))
  f32x4 acc2[3][4];
#pragma unroll
  for (int nt = 0; nt < 3; ++nt) {
    float bv[4];
#pragma unroll
    for (int r = 0; r < 4; ++r) bv[r] = b2k[16 * (3 * w + nt) + 4 * lg + r];
#pragma unroll
    for (int mt = 0; mt < 4; ++mt)
#pragma unroll
      for (int r = 0; r < 4; ++r) acc2[nt][mt][r] = bv[r];
  }
#pragma unroll
  for (int ksl = 0; ksl < 6; ++ksl) {
    s8bf Dhi[4], Dlo[4];
#pragma unroll
    for (int mt = 0; mt < 4; ++mt) {
      const uint32_t* p = Ds + (16 * mt + l15) * 194 + 32 * ksl + 8 * lg;
      uint32_t wv[8];
      *(uint2*)&wv[0] = *(const uint2*)(p);
      *(uint2*)&wv[2] = *(const uint2*)(p + 2);
      *(uint2*)&wv[4] = *(const uint2*)(p + 4);
      *(uint2*)&wv[6] = *(const uint2*)(p + 6);
      unpack8(wv, Dhi[mt], Dlo[mt]);
    }
#pragma unroll
    for (int nt = 0; nt < 3; ++nt) {
      int base = (((3 * w + nt) * 6 + ksl) * 64 + lane) * 4;
      FragU H, L;
      *(uint4*)H.u = *(const uint4*)(K2h + base);
      *(uint4*)L.u = *(const uint4*)(K2l + base);
#pragma unroll
      for (int mt = 0; mt < 4; ++mt) {
        acc2[nt][mt] = __builtin_amdgcn_mfma_f32_16x16x32_bf16(H.s, Dhi[mt], acc2[nt][mt], 0, 0, 0);
        acc2[nt][mt] = __builtin_amdgcn_mfma_f32_16x16x32_bf16(H.s, Dlo[mt], acc2[nt][mt], 0, 0, 0);
        acc2[nt][mt] = __builtin_amdgcn_mfma_f32_16x16x32_bf16(L.s, Dhi[mt], acc2[nt][mt], 0, 0, 0);
      }
    }
  }
  float er[4];
#pragma unroll
  for (int mt = 0; mt < 4; ++mt) er[mt] = ee[row0 + 16 * mt + l15];
#pragma unroll
  for (int nt = 0; nt < 3; ++nt) {
    int d0 = 16 * (3 * w + nt) + 4 * lg;
#pragma unroll
    for (int mt = 0; mt < 4; ++mt) {
      int row = row0 + 16 * mt + l15;
#pragma unroll
      for (int r = 0; r < 4; ++r)
        P2[(size_t)(d0 + r) * HW + row] = expf(-er[mt] * fmaxf(acc2[nt][mt][r], 0.f));
    }
  }
}

// ---------- KMIX: Tf = (concat[S1*P2lo, Ohat'(pre-mul P2hi)]) @ lin3_w^T ----------
__global__ __launch_bounds__(256) void kmix(
    const float* __restrict__ S1, const float* __restrict__ OhP,
    const float* __restrict__ P2,
    const uint32_t* __restrict__ W3h, const uint32_t* __restrict__ W3l,
    float* __restrict__ Tf) {
  __shared__ uint32_t Ds[128 * 98];           // 50 KB -> 3 blocks/CU
  const int tid = threadIdx.x;
  const int lane = tid & 63;
  const int w = tid >> 6;
  const int wn = w >> 1, wm = w & 1;
  const int l15 = lane & 15, lg = lane >> 4;
  const int gp0 = blockIdx.x * 128;           // 1024 blocks
  const int b = gp0 >> 14, hw0 = gp0 & 16383;

  f32x4 acc[3][4];
#pragma unroll
  for (int i = 0; i < 3; ++i)
#pragma unroll
    for (int j = 0; j < 4; ++j)
#pragma unroll
      for (int r = 0; r < 4; ++r) acc[i][j][r] = 0.f;

#pragma unroll
  for (int c = 0; c < 2; ++c) {
    if (c) __syncthreads();                   // protect LDS reuse
#pragma unroll
    for (int i = 0; i < 24; ++i) {
      int k = w + 4 * i;
      if (c == 0) {
        const float* sp = S1 + ((size_t)(b * 96 + k)) * HW + hw0;
        const float* pp = P2 + (size_t)k * HW + hw0;
        Ds[lane * 98 + k] = packhl(sp[lane] * pp[lane]);
        Ds[(lane + 64) * 98 + k] = packhl(sp[lane + 64] * pp[lane + 64]);
      } else {
        const float* sp = OhP + ((size_t)(b * 96 + k)) * HW + hw0;
        Ds[lane * 98 + k] = packhl(sp[lane]);
        Ds[(lane + 64) * 98 + k] = packhl(sp[lane + 64]);
      }
    }
    __syncthreads();
#pragma unroll
    for (int ksl = 0; ksl < 3; ++ksl) {
      s8bf Dhi[4], Dlo[4];
#pragma unroll
      for (int j = 0; j < 4; ++j) {
        const uint32_t* p = Ds + (16 * (4 * wm + j) + l15) * 98 + 32 * ksl + 8 * lg;
        uint32_t wv[8];
        *(uint2*)&wv[0] = *(const uint2*)(p);
        *(uint2*)&wv[2] = *(const uint2*)(p + 2);
        *(uint2*)&wv[4] = *(const uint2*)(p + 4);
        *(uint2*)&wv[6] = *(const uint2*)(p + 6);
        unpack8(wv, Dhi[j], Dlo[j]);
      }
#pragma unroll
      for (int i = 0; i < 3; ++i) {
        int base = (((3 * wn + i) * 6 + 3 * c + ksl) * 64 + lane) * 4;
        FragU H, L;
        *(uint4*)H.u = *(const uint4*)(W3h + base);
        *(uint4*)L.u = *(const uint4*)(W3l + base);
#pragma unroll
        for (int j = 0; j < 4; ++j) {
          acc[i][j] = __builtin_amdgcn_mfma_f32_16x16x32_bf16(H.s, Dhi[j], acc[i][j], 0, 0, 0);
          acc[i][j] = __builtin_amdgcn_mfma_f32_16x16x32_bf16(H.s, Dlo[j], acc[i][j], 0, 0, 0);
          acc[i][j] = __builtin_amdgcn_mfma_f32_16x16x32_bf16(L.s, Dhi[j], acc[i][j], 0, 0, 0);
        }
      }
    }
  }
#pragma unroll
  for (int i = 0; i < 3; ++i) {
    int d0 = 16 * (3 * wn + i) + 4 * lg;
#pragma unroll
    for (int j = 0; j < 4; ++j) {
      int hw = hw0 + 16 * (4 * wm + j) + l15;
#pragma unroll
      for (int r = 0; r < 4; ++r)
        Tf[((size_t)(b * 96 + d0 + r)) * HW + hw] = acc[i][j][r];
    }
  }
}

// ---------- K9R: (y3 + b3) -> LN -> *silu(z) -> out GEMM (128 pos/block) ----------
__global__ __launch_bounds__(256) void k9r(
    const float* __restrict__ y3, const float* __restrict__ z,
    const float* __restrict__ lin3b,
    const float* __restrict__ lng, const float* __restrict__ lnb,
    const uint32_t* __restrict__ WOh, const uint32_t* __restrict__ WOl,
    const float* __restrict__ outb, float* __restrict__ out) {
  __shared__ uint32_t Ds2[128 * 98];          // 50 KB
  __shared__ float2 red[4][128];              // 4 KB  (total 54.2 KB -> 3 blocks/CU)
  const int tid = threadIdx.x;
  const int lane = tid & 63;
  const int w = tid >> 6;
  const int wn = w >> 1, wm = w & 1;
  const int l15 = lane & 15, lg = lane >> 4;
  const int gp0 = blockIdx.x * 128;           // 1024 blocks
  const int b = gp0 >> 14, hw0 = gp0 & 16383;

  float vA[24], vB[24];
  float sA = 0.f, qA = 0.f, sB = 0.f, qB = 0.f;
#pragma unroll
  for (int i = 0; i < 24; ++i) {
    int k = w + 4 * i;
    const float* yp = y3 + ((size_t)(b * 96 + k)) * HW + hw0;
    float bk = lin3b[k];
    float tA = yp[lane] + bk;      vA[i] = tA; sA += tA; qA = fmaf(tA, tA, qA);
    float tB = yp[lane + 64] + bk; vB[i] = tB; sB += tB; qB = fmaf(tB, tB, qB);
  }
  red[w][lane] = make_float2(sA, qA);
  red[w][lane + 64] = make_float2(sB, qB);
  __syncthreads();
  float2 a0 = red[0][lane], a1 = red[1][lane], a2 = red[2][lane], a3 = red[3][lane];
  float2 b0 = red[0][lane + 64], b1 = red[1][lane + 64], b2_ = red[2][lane + 64], b3 = red[3][lane + 64];
  float muA = (a0.x + a1.x + a2.x + a3.x) * (1.f / 96.f);
  float vrA = (a0.y + a1.y + a2.y + a3.y) * (1.f / 96.f) - muA * muA;
  float invA = rsqrtf(fmaxf(vrA, 0.f) + 1e-5f);
  float muB = (b0.x + b1.x + b2_.x + b3.x) * (1.f / 96.f);
  float vrB = (b0.y + b1.y + b2_.y + b3.y) * (1.f / 96.f) - muB * muB;
  float invB = rsqrtf(fmaxf(vrB, 0.f) + 1e-5f);
#pragma unroll
  for (int i = 0; i < 24; ++i) {
    int k = w + 4 * i;
    const float* zp = z + (size_t)k * BHW + gp0;
    float g = lng[k], bb = lnb[k];
    float zA = zp[lane];
    float uA = (vA[i] - muA) * invA * g + bb;
    Ds2[lane * 98 + k] = packhl(uA * (zA / (1.f + expf(-zA))));
    float zB = zp[lane + 64];
    float uB = (vB[i] - muB) * invB * g + bb;
    Ds2[(lane + 64) * 98 + k] = packhl(uB * (zB / (1.f + expf(-zB))));
  }
  __syncthreads();

  f32x4 acc2[3][4];
#pragma unroll
  for (int i = 0; i < 3; ++i) {
    float bv[4];
#pragma unroll
    for (int r = 0; r < 4; ++r) bv[r] = outb[16 * (3 * wn + i) + 4 * lg + r];
#pragma unroll
    for (int j = 0; j < 4; ++j)
#pragma unroll
      for (int r = 0; r < 4; ++r) acc2[i][j][r] = bv[r];
  }
#pragma unroll
  for (int ksl = 0; ksl < 3; ++ksl) {
    s8bf Dhi[4], Dlo[4];
#pragma unroll
    for (int j = 0; j < 4; ++j) {
      const uint32_t* p = Ds2 + (16 * (4 * wm + j) + l15) * 98 + 32 * ksl + 8 * lg;
      uint32_t wv[8];
      *(uint2*)&wv[0] = *(const uint2*)(p);
      *(uint2*)&wv[2] = *(const uint2*)(p + 2);
      *(uint2*)&wv[4] = *(const uint2*)(p + 4);
      *(uint2*)&wv[6] = *(const uint2*)(p + 6);
      unpack8(wv, Dhi[j], Dlo[j]);
    }
#pragma unroll
    for (int i = 0; i < 3; ++i) {
      int base = (((3 * wn + i) * 3 + ksl) * 64 + lane) * 4;
      FragU H, L;
      *(uint4*)H.u = *(const uint4*)(WOh + base);
      *(uint4*)L.u = *(const uint4*)(WOl + base);
#pragma unroll
      for (int j = 0; j < 4; ++j) {
        acc2[i][j] = __builtin_amdgcn_mfma_f32_16x16x32_bf16(H.s, Dhi[j], acc2[i][j], 0, 0, 0);
        acc2[i][j] = __builtin_amdgcn_mfma_f32_16x16x32_bf16(H.s, Dlo[j], acc2[i][j], 0, 0, 0);
        acc2[i][j] = __builtin_amdgcn_mfma_f32_16x16x32_bf16(L.s, Dhi[j], acc2[i][j], 0, 0, 0);
      }
    }
  }
#pragma unroll
  for (int i = 0; i < 3; ++i) {
    int d0 = 16 * (3 * wn + i) + 4 * lg;
#pragma unroll
    for (int j = 0; j < 4; ++j) {
      int hw = hw0 + 16 * (4 * wm + j) + l15;
#pragma unroll
      for (int r = 0; r < 4; ++r)
        out[((size_t)(b * 96 + d0 + r)) * HW + hw] = acc2[i][j][r];
    }
  }
}

extern "C" void kernel_launch(void* const* d_in, const int* in_sizes, int n_in,
                              void* d_out, int out_size, void* d_ws, size_t ws_size,
                              hipStream_t stream) {
  const float* x      = (const float*)d_in[0];
  const float* fe     = (const float*)d_in[1];
  const float* of     = (const float*)d_in[2];
  const float* dw_w   = (const float*)d_in[3];
  const float* dw_b   = (const float*)d_in[4];
  const float* lin_w  = (const float*)d_in[5];
  const float* lin_b  = (const float*)d_in[6];
  const float* k_w    = (const float*)d_in[7];
  const float* k_b    = (const float*)d_in[8];
  const float* lin2_w = (const float*)d_in[9];
  const float* lin2_b = (const float*)d_in[10];
  const float* k2_w   = (const float*)d_in[11];
  const float* k2_b   = (const float*)d_in[12];
  const float* lin3_w = (const float*)d_in[13];
  const float* lin3_b = (const float*)d_in[14];
  const float* ln_g   = (const float*)d_in[15];
  const float* ln_b   = (const float*)d_in[16];
  const float* out_w  = (const float*)d_in[17];
  const float* out_b  = (const float*)d_in[18];
  float* out = (float*)d_out;

  float* ws    = (float*)d_ws;
  float* x1p   = ws;                      // [B][96][HW]: x1 -> S1 -> Tf -> y3 (in-place chain)
  float* z     = x1p   + 12582912;        // [96][B*HW] plane-major
  float* ofp   = z     + 12582912;        // [B][96][HW]: xc -> outline planes -> Ohat'
  float* cm    = ofp   + 12582912;        // [192][HW]: lower = idct(mean S1), upper = mean outline
  float* skf   = cm    + 3145728;         // [192][HW] (first 96 planes reused as cmSf scratch)
  float* P1    = skf   + 3145728;         // [96][HW]
  float* P2    = P1    + 1572864;         // [192][HW]
  float* cc    = P2    + 3145728;         // [128][128] (unused)
  float* ee    = cc    + 16384;           // [128][128]
  float* linT  = ee    + 16384;           // (unused)
  float* kT    = linT  + 18432;           // [96][96]
  float* lin2T = kT    + 9216;            // (unused now)
  float* k2T   = lin2T + 36864;           // (unused now)
  float* lin3T = k2T   + 36864;           // (unused)
  float* outT  = lin3T + 18432;           // (unused)
  float* fet   = outT  + 9216;            // [96][HW]
  uint32_t* FAh = (uint32_t*)(fet + 1572864);  // 8192 u32 each
  uint32_t* FAl = FAh + 8192;
  uint32_t* FTh = FAl + 8192;
  uint32_t* FTl = FTh + 8192;
  uint32_t* WLh = FTl + 8192;             // lin frags:  12x3x64x4 = 9216 u32
  uint32_t* WLl = WLh + 9216;
  uint32_t* W3h = WLl + 9216;             // lin3 frags: 6x6x64x4 = 9216
  uint32_t* W3l = W3h + 9216;
  uint32_t* WOh = W3l + 9216;             // out frags:  6x3x64x4 = 4608
  uint32_t* WOl = WOh + 4608;
  uint32_t* W2h = WOl + 4608;             // lin2 frags: 12x6x64x4 = 18432
  uint32_t* W2l = W2h + 18432;
  uint32_t* K2h = W2l + 18432;            // k2 frags:   18432
  uint32_t* K2l = K2h + 18432;
  float* xc    = ofp;                     // aliases ofp: dead after klin, before k3
  float* cmSf  = skf;                     // [96][HW] temp: mean_b(S1)
  (void)in_sizes; (void)n_in; (void)out_size; (void)ws_size;

  k0_tables<<<64, 256, 0, stream>>>(cc, ee);
  k0_frags<<<8, 256, 0, stream>>>(FAh, FAl, FTh, FTl);
  k_wfrag<<<9, 256, 0, stream>>>(lin_w, WLh, WLl, 192, 96);
  k_wfrag<<<9, 256, 0, stream>>>(lin3_w, W3h, W3l, 96, 192);
  k_wfrag<<<5, 256, 0, stream>>>(out_w, WOh, WOl, 96, 96);
  k_wfrag<<<18, 256, 0, stream>>>(lin2_w, W2h, W2l, 192, 192);
  k_wfrag<<<18, 256, 0, stream>>>(k2_w, K2h, K2l, 192, 192);
  k_wt<<<36, 256, 0, stream>>>(k_w, kT, 96, 96);
  k_tfe<<<256, 256, 0, stream>>>(fe, fet);

  kconv<<<12288, 256, 0, stream>>>(x, dw_w, dw_b, xc);
  klin_mfma<<<2048, 256, 0, stream>>>(xc, WLh, WLl, lin_b, x1p, z);
  k3_transpose_mean<<<256, 256, 0, stream>>>(of, ofp, cm + (size_t)96 * HW);
  k3b_kgemm<<<256, 256, 0, stream>>>(fet, cm + (size_t)96 * HW, kT, k_b, ee, P1);
  // S1 = P1 .* dct2(x1)   (in-place in x1p)
  heat_half<true><<<768, 256, 0, stream>>>(x1p, x1p, P1, FAh, FAl, 96);
  // mean_b(y1) = idct2(mean_b(S1))
  k5_mean<<<6144, 256, 0, stream>>>(x1p, cmSf);
  heat_half<false><<<96, 256, 0, stream>>>(cmSf, cm, nullptr, FTh, FTl, 96);
  // P2 (k6+k7 fused, MFMA)
  k67_mfma<<<256, 256, 0, stream>>>(cm, W2h, W2l, lin2_b, K2h, K2l, k2_b, ee, P2);
  // Ohat' = dct2(outline) .* P2hi  (in-place in ofp, P2 fold into epilogue)
  heat_half<true><<<768, 256, 0, stream>>>(ofp, ofp, P2 + (size_t)96 * HW, FAh, FAl, 96);
  // Tf = (concat[S1*P2lo, Ohat']) @ lin3^T  (in-place into x1p)
  kmix<<<1024, 256, 0, stream>>>(x1p, ofp, P2, W3h, W3l, x1p);
  // y3 = idct2(Tf)  (in-place in x1p)
  heat_half<false><<<768, 256, 0, stream>>>(x1p, x1p, nullptr, FTh, FTl, 96);
  k9r<<<1024, 256, 0, stream>>>(x1p, z, lin3_b, ln_g, ln_b, WOh, WOl, out_b, out);
}

// Round 13
// 358.489 us; speedup vs baseline: 1.3104x; 1.0535x over previous
//
#include <hip/hip_runtime.h>
#include <math.h>
#include <stdint.h>

#ifndef M_PI
#define M_PI 3.14159265358979323846
#endif

#define HW 16384
#define BHW 131072

typedef __attribute__((ext_vector_type(8))) short s8bf;    // 8 bf16 = 4 VGPR
typedef __attribute__((ext_vector_type(4))) float f32x4;   // MFMA C/D

union FragU { uint32_t u[4]; s8bf s; };

// ---------- bf16 split helpers ----------
__device__ __forceinline__ uint32_t bf16h(float x) {
  uint32_t u = __float_as_uint(x);
  return (u + 0x7FFFu + ((u >> 16) & 1u)) >> 16;     // RNE, low 16 bits
}
__device__ __forceinline__ uint32_t packhl(float x) {  // u32 = (hi<<16)|lo
  uint32_t h = bf16h(x);
  float r = x - __uint_as_float(h << 16);
  return (h << 16) | bf16h(r);
}
__device__ __forceinline__ void unpack8(const uint32_t* w, s8bf& hi, s8bf& lo) {
  FragU H, L;
#pragma unroll
  for (int j = 0; j < 4; ++j) {
    H.u[j] = __builtin_amdgcn_perm(w[2 * j + 1], w[2 * j], 0x07060302u);
    L.u[j] = __builtin_amdgcn_perm(w[2 * j + 1], w[2 * j], 0x05040100u);
  }
  hi = H.s; lo = L.s;
}

__device__ __forceinline__ float cval(int a, int b) {
  double v = cos((double)a * ((double)b + 0.5) * (M_PI / 128.0)) * sqrt(2.0 / 128.0);
  if (a == 0) v *= 0.70710678118654752440;
  return (float)v;
}

// ---------- weight A-frag device helper: W[D][K] row-major -> hi/lo frags ----------
__device__ __forceinline__ void wfrag_dev(const float* __restrict__ src,
                                          uint32_t* __restrict__ Fh,
                                          uint32_t* __restrict__ Fl,
                                          int D, int K, int tid) {
  int nksl = K >> 5;
  int total = (D >> 4) * nksl * 64;
  if (tid >= total) return;
  int lane = tid & 63, fid = tid >> 6;
  int nt = fid / nksl, ksl = fid - nt * nksl;
  int d = 16 * nt + (lane & 15);
  int k0 = 32 * ksl + 8 * (lane >> 4);
#pragma unroll
  for (int j = 0; j < 4; ++j) {
    uint32_t p0 = packhl(src[d * K + k0 + 2 * j]);
    uint32_t p1 = packhl(src[d * K + k0 + 2 * j + 1]);
    Fh[tid * 4 + j] = (p0 >> 16) | (p1 & 0xFFFF0000u);
    Fl[tid * 4 + j] = (p0 & 0xFFFFu) | (p1 << 16);
  }
}

// ---------- KPREP: all table/weight prep in one launch (423 blocks) ----------
__global__ __launch_bounds__(256) void kprep(
    float* __restrict__ ee,
    uint32_t* __restrict__ FAh, uint32_t* __restrict__ FAl,
    uint32_t* __restrict__ FTh, uint32_t* __restrict__ FTl,
    const float* __restrict__ lin_w, uint32_t* __restrict__ WLh, uint32_t* __restrict__ WLl,
    const float* __restrict__ lin3_w, uint32_t* __restrict__ W3h, uint32_t* __restrict__ W3l,
    const float* __restrict__ out_w, uint32_t* __restrict__ WOh, uint32_t* __restrict__ WOl,
    const float* __restrict__ lin2_w, uint32_t* __restrict__ W2h, uint32_t* __restrict__ W2l,
    const float* __restrict__ k2_w, uint32_t* __restrict__ K2h, uint32_t* __restrict__ K2l,
    const float* __restrict__ k_w, float* __restrict__ kT,
    const float* __restrict__ fe, float* __restrict__ fet) {
  __shared__ float tile[64 * 97];
  const int bb = blockIdx.x;
  const int tid = threadIdx.x;
  if (bb < 64) {                              // ee table
    int gid = bb * 256 + tid;
    int n = gid >> 7, m = gid & 127;
    double wn = (double)n * (M_PI / 128.0), wm = (double)m * (M_PI / 128.0);
    ee[gid] = (float)(wn * wn + wm * wm);
  } else if (bb < 72) {                       // DCT frags
    int t2 = (bb - 64) * 256 + tid;
    int lane = t2 & 63, fid = t2 >> 6;
    int mt = fid >> 2, ks = fid & 3;
    int n = 16 * mt + (lane & 15);
    int k0 = 32 * ks + 8 * (lane >> 4);
#pragma unroll
    for (int j = 0; j < 4; ++j) {
      uint32_t p0 = packhl(cval(n, k0 + 2 * j)), p1 = packhl(cval(n, k0 + 2 * j + 1));
      FAh[t2 * 4 + j] = (p0 >> 16) | (p1 & 0xFFFF0000u);
      FAl[t2 * 4 + j] = (p0 & 0xFFFFu) | (p1 << 16);
      uint32_t q0 = packhl(cval(k0 + 2 * j, n)), q1 = packhl(cval(k0 + 2 * j + 1, n));
      FTh[t2 * 4 + j] = (q0 >> 16) | (q1 & 0xFFFF0000u);
      FTl[t2 * 4 + j] = (q0 & 0xFFFFu) | (q1 << 16);
    }
  } else if (bb < 81) {
    wfrag_dev(lin_w, WLh, WLl, 192, 96, (bb - 72) * 256 + tid);
  } else if (bb < 90) {
    wfrag_dev(lin3_w, W3h, W3l, 96, 192, (bb - 81) * 256 + tid);
  } else if (bb < 95) {
    wfrag_dev(out_w, WOh, WOl, 96, 96, (bb - 90) * 256 + tid);
  } else if (bb < 113) {
    wfrag_dev(lin2_w, W2h, W2l, 192, 192, (bb - 95) * 256 + tid);
  } else if (bb < 131) {
    wfrag_dev(k2_w, K2h, K2l, 192, 192, (bb - 113) * 256 + tid);
  } else if (bb < 167) {                      // k_w transpose
    int gid = (bb - 131) * 256 + tid;
    if (gid < 96 * 96) {
      int d = gid / 96, c = gid % 96;
      kT[c * 96 + d] = k_w[gid];
    }
  } else {                                    // fe transpose (256 blocks)
    int hw0 = (bb - 167) * 64;
#pragma unroll
    for (int t = 0; t < 24; ++t) {
      int l = tid + t * 256;
      int r = l / 96, c0 = l % 96;
      tile[r * 97 + c0] = fe[((size_t)hw0 + r) * 96 + c0];
    }
    __syncthreads();
#pragma unroll
    for (int t = 0; t < 24; ++t) {
      int l = tid + t * 256;
      int c0 = l >> 6, r = l & 63;
      fet[(size_t)c0 * HW + hw0 + r] = tile[r * 97 + c0];
    }
  }
}

// ---------- KC: depthwise 3x3 conv, float4 per thread, plane-major out ----------
__global__ __launch_bounds__(256) void kconv(
    const float* __restrict__ x, const float* __restrict__ dw_w,
    const float* __restrict__ dw_b, float* __restrict__ xc) {
  int gid = blockIdx.x * 256 + threadIdx.x;   // B*96*4096 = 3145728
  int p = gid >> 12;                          // plane b*96+c
  int q = gid & 4095;
  int h = q >> 5, w4 = (q & 31) << 2;
  int c = p % 96;
  const float* pw = dw_w + c * 9;
  const float* row = x + (size_t)p * HW + h * 128 + w4;
  bool tp = h > 0, bt = h < 127, lf = w4 > 0, rt = w4 < 124;
  float4 t_, m_, b_;
  float tl, tr, ml, mr, bl, br;
  m_ = *(const float4*)row;
  ml = lf ? row[-1] : 0.f;
  mr = rt ? row[4] : 0.f;
  if (tp) {
    t_ = *(const float4*)(row - 128);
    tl = lf ? row[-129] : 0.f;
    tr = rt ? row[-124] : 0.f;
  } else { t_ = make_float4(0.f, 0.f, 0.f, 0.f); tl = tr = 0.f; }
  if (bt) {
    b_ = *(const float4*)(row + 128);
    bl = lf ? row[127] : 0.f;
    br = rt ? row[132] : 0.f;
  } else { b_ = make_float4(0.f, 0.f, 0.f, 0.f); bl = br = 0.f; }
  float w0 = pw[0], w1 = pw[1], w2 = pw[2], w3 = pw[3], w4w = pw[4],
        w5 = pw[5], w6 = pw[6], w7 = pw[7], w8 = pw[8];
  float bias = dw_b[c];
  float4 o;
  o.x = tl * w0 + t_.x * w1 + t_.y * w2 + ml * w3 + m_.x * w4w + m_.y * w5 + bl * w6 + b_.x * w7 + b_.y * w8 + bias;
  o.y = t_.x * w0 + t_.y * w1 + t_.z * w2 + m_.x * w3 + m_.y * w4w + m_.z * w5 + b_.x * w6 + b_.y * w7 + b_.z * w8 + bias;
  o.z = t_.y * w0 + t_.z * w1 + t_.w * w2 + m_.y * w3 + m_.z * w4w + m_.w * w5 + b_.y * w6 + b_.z * w7 + b_.w * w8 + bias;
  o.w = t_.z * w0 + t_.w * w1 + tr * w2 + m_.z * w3 + m_.w * w4w + mr * w5 + b_.z * w6 + b_.w * w7 + br * w8 + bias;
  *(float4*)(xc + (size_t)p * HW + h * 128 + w4) = o;
}

// ---------- KL-MFMA: [B*HW,96] @ lin_w^T -> x1 planes (PACKED u32) + z planes (f32) ----------
__global__ __launch_bounds__(256) void klin_mfma(
    const float* __restrict__ xc, const uint32_t* __restrict__ WLh,
    const uint32_t* __restrict__ WLl, const float* __restrict__ lin_b,
    uint32_t* __restrict__ x1u, float* __restrict__ z) {
  __shared__ uint32_t Ds[64 * 102];   // [m][k], 26 KB
  const int tid = threadIdx.x;
  const int lane = tid & 63;
  const int w = tid >> 6;
  const int l15 = lane & 15, lg = lane >> 4;
  const int gp0 = blockIdx.x * 64;
  const int b = gp0 >> 14, hw0 = gp0 & 16383;

#pragma unroll
  for (int i = 0; i < 24; ++i) {      // stage xc -> Ds[m*102+k]
    int k = w + 4 * i;
    float v = xc[((size_t)(b * 96 + k)) * HW + hw0 + lane];
    Ds[lane * 102 + k] = packhl(v);
  }
  __syncthreads();

  f32x4 acc[3][4];
#pragma unroll
  for (int nt = 0; nt < 3; ++nt) {
    float bv[4];
#pragma unroll
    for (int r = 0; r < 4; ++r) bv[r] = lin_b[16 * (3 * w + nt) + 4 * lg + r];
#pragma unroll
    for (int mt = 0; mt < 4; ++mt)
#pragma unroll
      for (int r = 0; r < 4; ++r) acc[nt][mt][r] = bv[r];
  }

#pragma unroll
  for (int ksl = 0; ksl < 3; ++ksl) {
    s8bf Dhi[4], Dlo[4];
#pragma unroll
    for (int mt = 0; mt < 4; ++mt) {
      const uint32_t* p = Ds + (16 * mt + l15) * 102 + 32 * ksl + 8 * lg;
      uint32_t wv[8];
      *(uint2*)&wv[0] = *(const uint2*)(p);
      *(uint2*)&wv[2] = *(const uint2*)(p + 2);
      *(uint2*)&wv[4] = *(const uint2*)(p + 4);
      *(uint2*)&wv[6] = *(const uint2*)(p + 6);
      unpack8(wv, Dhi[mt], Dlo[mt]);
    }
#pragma unroll
    for (int nt = 0; nt < 3; ++nt) {
      int base = (((3 * w + nt) * 3 + ksl) * 64 + lane) * 4;
      FragU H, L;
      *(uint4*)H.u = *(const uint4*)(WLh + base);
      *(uint4*)L.u = *(const uint4*)(WLl + base);
#pragma unroll
      for (int mt = 0; mt < 4; ++mt) {
        acc[nt][mt] = __builtin_amdgcn_mfma_f32_16x16x32_bf16(H.s, Dhi[mt], acc[nt][mt], 0, 0, 0);
        acc[nt][mt] = __builtin_amdgcn_mfma_f32_16x16x32_bf16(H.s, Dlo[mt], acc[nt][mt], 0, 0, 0);
        acc[nt][mt] = __builtin_amdgcn_mfma_f32_16x16x32_bf16(L.s, Dhi[mt], acc[nt][mt], 0, 0, 0);
      }
    }
  }
#pragma unroll
  for (int nt = 0; nt < 3; ++nt) {
    int d0 = 16 * (3 * w + nt) + 4 * lg;
#pragma unroll
    for (int mt = 0; mt < 4; ++mt) {
#pragma unroll
      for (int r = 0; r < 4; ++r) {
        int d = d0 + r;
        if (d < 96)
          x1u[((size_t)(b * 96 + d)) * HW + hw0 + 16 * mt + l15] = packhl(acc[nt][mt][r]);
        else
          z[((size_t)(d - 96)) * BHW + gp0 + 16 * mt + l15] = acc[nt][mt][r];
      }
    }
  }
}

// ---------- K3: outline_feat transpose to plane-major (PACKED) + mean over B (f32) ----------
__global__ __launch_bounds__(256) void k3_transpose_mean(
    const float* __restrict__ of, uint32_t* __restrict__ ofu, float* __restrict__ cmU) {
  __shared__ float tile[64 * 97];
  int hw0 = blockIdx.x * 64;
  int tid = threadIdx.x;
  float sum[24];
#pragma unroll
  for (int t = 0; t < 24; ++t) sum[t] = 0.f;
  for (int b = 0; b < 8; ++b) {
    __syncthreads();
#pragma unroll
    for (int t = 0; t < 24; ++t) {
      int l = tid + t * 256;
      int r = l / 96, c0 = l % 96;
      tile[r * 97 + c0] = of[((size_t)b * 16384 + hw0 + r) * 96 + c0];
    }
    __syncthreads();
#pragma unroll
    for (int t = 0; t < 24; ++t) {
      int l = tid + t * 256;
      int c0 = l >> 6, r = l & 63;
      float v = tile[r * 97 + c0];
      sum[t] += v;
      ofu[(size_t)(b * 96 + c0) * HW + hw0 + r] = packhl(v);
    }
  }
#pragma unroll
  for (int t = 0; t < 24; ++t) {
    int l = tid + t * 256;
    int c0 = l >> 6, r = l & 63;
    cmU[(size_t)c0 * HW + hw0 + r] = sum[t] * 0.125f;
  }
}

// ---------- K3b: k = relu((fet+otm)@k_w^T + k_b); P1 = exp(-e*k) ----------
__global__ __launch_bounds__(256) void k3b_kgemm(
    const float* __restrict__ fet, const float* __restrict__ otm,
    const float* __restrict__ kT, const float* __restrict__ kb,
    const float* __restrict__ ee, float* __restrict__ P1) {
  int tid = threadIdx.x;
  int lane = tid & 63;
  int n0 = __builtin_amdgcn_readfirstlane((tid >> 6) * 24);
  int row = blockIdx.x * 64 + lane;           // 256 blocks
  float acc[24];
#pragma unroll
  for (int j = 0; j < 24; ++j) acc[j] = kb[n0 + j];
#pragma unroll 4
  for (int c = 0; c < 96; ++c) {
    float a = fet[(size_t)c * HW + row] + otm[(size_t)c * HW + row];
    const float* wr = kT + c * 96 + n0;
#pragma unroll
    for (int j = 0; j < 24; ++j) acc[j] = fmaf(a, wr[j], acc[j]);
  }
  float er = ee[row];
#pragma unroll
  for (int j = 0; j < 24; ++j)
    P1[(size_t)(n0 + j) * HW + row] = expf(-er * fmaxf(acc[j], 0.f));
}

// ---------- MFMA transform primitives ----------
template <bool DATA_A>
__device__ __forceinline__ void heat_step(
    const uint32_t* __restrict__ Fh, const uint32_t* __restrict__ Fl,
    const uint32_t* __restrict__ Ds, f32x4 (&acc)[4][4], int wm, int wn, int lane) {
  const int l15 = lane & 15, lg = lane >> 4;
  const int wd = DATA_A ? wm : wn;
  const int wf = DATA_A ? wn : wm;
#pragma unroll
  for (int ksl = 0; ksl < 4; ++ksl) {
    s8bf Dhi[4], Dlo[4], Fhi[4], Flo[4];
#pragma unroll
    for (int t = 0; t < 4; ++t) {
      const uint32_t* p = Ds + (64 * wd + 16 * t + l15) * 130 + 32 * ksl + 8 * lg;
      uint32_t wv[8];
      *(uint2*)&wv[0] = *(const uint2*)(p);
      *(uint2*)&wv[2] = *(const uint2*)(p + 2);
      *(uint2*)&wv[4] = *(const uint2*)(p + 4);
      *(uint2*)&wv[6] = *(const uint2*)(p + 6);
      unpack8(wv, Dhi[t], Dlo[t]);
    }
#pragma unroll
    for (int t = 0; t < 4; ++t) {
      int base = (((4 * wf + t) * 4 + ksl) * 64 + lane) * 4;
      FragU H, L;
      *(uint4*)H.u = *(const uint4*)(Fh + base);
      *(uint4*)L.u = *(const uint4*)(Fl + base);
      Fhi[t] = H.s; Flo[t] = L.s;
    }
    const s8bf* Ah = DATA_A ? Dhi : Fhi;
    const s8bf* Al = DATA_A ? Dlo : Flo;
    const s8bf* Bh = DATA_A ? Fhi : Dhi;
    const s8bf* Bl = DATA_A ? Flo : Dlo;
#pragma unroll
    for (int mi = 0; mi < 4; ++mi)
#pragma unroll
      for (int ni = 0; ni < 4; ++ni)
        acc[mi][ni] = __builtin_amdgcn_mfma_f32_16x16x32_bf16(Ah[mi], Bh[ni], acc[mi][ni], 0, 0, 0);
#pragma unroll
    for (int mi = 0; mi < 4; ++mi)
#pragma unroll
      for (int ni = 0; ni < 4; ++ni)
        acc[mi][ni] = __builtin_amdgcn_mfma_f32_16x16x32_bf16(Ah[mi], Bl[ni], acc[mi][ni], 0, 0, 0);
#pragma unroll
    for (int mi = 0; mi < 4; ++mi)
#pragma unroll
      for (int ni = 0; ni < 4; ++ni)
        acc[mi][ni] = __builtin_amdgcn_mfma_f32_16x16x32_bf16(Al[mi], Bh[ni], acc[mi][ni], 0, 0, 0);
  }
}

// ---------- heat_half: Out = F * In * F^T; PIN: packed-u32 input; POUT: packed output ----------
template <bool PIN, bool POUT, bool USE_P>
__global__ __launch_bounds__(256, 2) void heat_half(
    const float* __restrict__ In, float* __restrict__ Out,
    const float* __restrict__ P, const uint32_t* __restrict__ Fh,
    const uint32_t* __restrict__ Fl, int Cmod) {
  __shared__ uint32_t Ds[128 * 130];
  const int tid = threadIdx.x;
  const int lane = tid & 63;
  const int w = tid >> 6;
  const int wm = w >> 1, wn = w & 1;
  const int l15 = lane & 15, lg = lane >> 4;
  const float* Ip = In + (size_t)blockIdx.x * HW;
  float* Op = Out + (size_t)blockIdx.x * HW;
  const float* Pp = nullptr;
  if constexpr (USE_P) Pp = P + (size_t)(blockIdx.x % Cmod) * HW;

  {
    int col = tid & 127, r0 = tid >> 7;
    if constexpr (PIN) {
      const uint32_t* Iu = (const uint32_t*)Ip;
#pragma unroll
      for (int i = 0; i < 64; ++i) {
        int row = r0 + 2 * i;
        Ds[col * 130 + row] = Iu[row * 128 + col];
      }
    } else {
#pragma unroll
      for (int i = 0; i < 64; ++i) {
        int row = r0 + 2 * i;
        Ds[col * 130 + row] = packhl(Ip[row * 128 + col]);
      }
    }
  }
  __syncthreads();

  f32x4 acc[4][4];
  const f32x4 zero4 = {0.f, 0.f, 0.f, 0.f};
#pragma unroll
  for (int mi = 0; mi < 4; ++mi)
#pragma unroll
    for (int ni = 0; ni < 4; ++ni) acc[mi][ni] = zero4;
  heat_step<false>(Fh, Fl, Ds, acc, wm, wn, lane);     // T = F * In
  __syncthreads();
#pragma unroll
  for (int mi = 0; mi < 4; ++mi)
#pragma unroll
    for (int ni = 0; ni < 4; ++ni)
#pragma unroll
      for (int r = 0; r < 4; ++r)
        Ds[(64 * wm + 16 * mi + 4 * lg + r) * 130 + 64 * wn + 16 * ni + l15] =
            packhl(acc[mi][ni][r]);
  __syncthreads();

#pragma unroll
  for (int mi = 0; mi < 4; ++mi)
#pragma unroll
    for (int ni = 0; ni < 4; ++ni) acc[mi][ni] = zero4;
  heat_step<true>(Fh, Fl, Ds, acc, wm, wn, lane);      // Out = T * F^T
#pragma unroll
  for (int mi = 0; mi < 4; ++mi)
#pragma unroll
    for (int ni = 0; ni < 4; ++ni) {
      int row = 64 * wm + 16 * mi + 4 * lg;
      int col = 64 * wn + 16 * ni + l15;
#pragma unroll
      for (int r = 0; r < 4; ++r) {
        float v = acc[mi][ni][r];
        if constexpr (USE_P) v *= Pp[(row + r) * 128 + col];
        if constexpr (POUT)
          ((uint32_t*)Op)[(row + r) * 128 + col] = packhl(v);
        else
          Op[(row + r) * 128 + col] = v;
      }
    }
}

// ---------- K5: plane-mean over batch: dst[c][s] = mean_b src[b*96+c][s] (f32 src) ----------
__global__ void k5_mean(const float* __restrict__ src, float* __restrict__ dst) {
  int idx = blockIdx.x * 256 + threadIdx.x;
  int c = idx >> 14, s = idx & 16383;
  float sum = 0.f;
#pragma unroll
  for (int b = 0; b < 8; ++b) sum += src[(size_t)(b * 96 + c) * HW + s];
  dst[idx] = sum * 0.125f;
}

// ---------- K67-MFMA: skf = cm@lin2^T+b2; k2 = relu(skf@k2^T+b2k); P2 = exp(-e*k2) ----------
__global__ __launch_bounds__(256) void k67_mfma(
    const float* __restrict__ cm,
    const uint32_t* __restrict__ W2h, const uint32_t* __restrict__ W2l,
    const float* __restrict__ b2,
    const uint32_t* __restrict__ K2h, const uint32_t* __restrict__ K2l,
    const float* __restrict__ b2k, const float* __restrict__ ee,
    float* __restrict__ P2) {
  __shared__ uint32_t Ds[64 * 194];           // 48.5 KB
  const int tid = threadIdx.x;
  const int lane = tid & 63;
  const int w = tid >> 6;
  const int l15 = lane & 15, lg = lane >> 4;
  const int row0 = blockIdx.x * 64;           // 256 blocks

#pragma unroll
  for (int i = 0; i < 48; ++i) {              // stage cm -> Ds[m*194+k]
    int k = w + 4 * i;
    Ds[lane * 194 + k] = packhl(cm[(size_t)k * HW + row0 + lane]);
  }
  __syncthreads();

  f32x4 acc[3][4];
#pragma unroll
  for (int nt = 0; nt < 3; ++nt) {
    float bv[4];
#pragma unroll
    for (int r = 0; r < 4; ++r) bv[r] = b2[16 * (3 * w + nt) + 4 * lg + r];
#pragma unroll
    for (int mt = 0; mt < 4; ++mt)
#pragma unroll
      for (int r = 0; r < 4; ++r) acc[nt][mt][r] = bv[r];
  }
#pragma unroll
  for (int ksl = 0; ksl < 6; ++ksl) {
    s8bf Dhi[4], Dlo[4];
#pragma unroll
    for (int mt = 0; mt < 4; ++mt) {
      const uint32_t* p = Ds + (16 * mt + l15) * 194 + 32 * ksl + 8 * lg;
      uint32_t wv[8];
      *(uint2*)&wv[0] = *(const uint2*)(p);
      *(uint2*)&wv[2] = *(const uint2*)(p + 2);
      *(uint2*)&wv[4] = *(const uint2*)(p + 4);
      *(uint2*)&wv[6] = *(const uint2*)(p + 6);
      unpack8(wv, Dhi[mt], Dlo[mt]);
    }
#pragma unroll
    for (int nt = 0; nt < 3; ++nt) {
      int base = (((3 * w + nt) * 6 + ksl) * 64 + lane) * 4;
      FragU H, L;
      *(uint4*)H.u = *(const uint4*)(W2h + base);
      *(uint4*)L.u = *(const uint4*)(W2l + base);
#pragma unroll
      for (int mt = 0; mt < 4; ++mt) {
        acc[nt][mt] = __builtin_amdgcn_mfma_f32_16x16x32_bf16(H.s, Dhi[mt], acc[nt][mt], 0, 0, 0);
        acc[nt][mt] = __builtin_amdgcn_mfma_f32_16x16x32_bf16(H.s, Dlo[mt], acc[nt][mt], 0, 0, 0);
        acc[nt][mt] = __builtin_amdgcn_mfma_f32_16x16x32_bf16(L.s, Dhi[mt], acc[nt][mt], 0, 0, 0);
      }
    }
  }
  __syncthreads();
#pragma unroll
  for (int nt = 0; nt < 3; ++nt) {
    int d0 = 16 * (3 * w + nt) + 4 * lg;
#pragma unroll
    for (int mt = 0; mt < 4; ++mt) {
      int col = 16 * mt + l15;
#pragma unroll
      for (int r = 0; r < 4; ++r)
        Ds[col * 194 + d0 + r] = packhl(acc[nt][mt][r]);
    }
  }
  __syncthreads();

  f32x4 acc2[3][4];
#pragma unroll
  for (int nt = 0; nt < 3; ++nt) {
    float bv[4];
#pragma unroll
    for (int r = 0; r < 4; ++r) bv[r] = b2k[16 * (3 * w + nt) + 4 * lg + r];
#pragma unroll
    for (int mt = 0; mt < 4; ++mt)
#pragma unroll
      for (int r = 0; r < 4; ++r) acc2[nt][mt][r] = bv[r];
  }
#pragma unroll
  for (int ksl = 0; ksl < 6; ++ksl) {
    s8bf Dhi[4], Dlo[4];
#pragma unroll
    for (int mt = 0; mt < 4; ++mt) {
      const uint32_t* p = Ds + (16 * mt + l15) * 194 + 32 * ksl + 8 * lg;
      uint32_t wv[8];
      *(uint2*)&wv[0] = *(const uint2*)(p);
      *(uint2*)&wv[2] = *(const uint2*)(p + 2);
      *(uint2*)&wv[4] = *(const uint2*)(p + 4);
      *(uint2*)&wv[6] = *(const uint2*)(p + 6);
      unpack8(wv, Dhi[mt], Dlo[mt]);
    }
#pragma unroll
    for (int nt = 0; nt < 3; ++nt) {
      int base = (((3 * w + nt) * 6 + ksl) * 64 + lane) * 4;
      FragU H, L;
      *(uint4*)H.u = *(const uint4*)(K2h + base);
      *(uint4*)L.u = *(const uint4*)(K2l + base);
#pragma unroll
      for (int mt = 0; mt < 4; ++mt) {
        acc2[nt][mt] = __builtin_amdgcn_mfma_f32_16x16x32_bf16(H.s, Dhi[mt], acc2[nt][mt], 0, 0, 0);
        acc2[nt][mt] = __builtin_amdgcn_mfma_f32_16x16x32_bf16(H.s, Dlo[mt], acc2[nt][mt], 0, 0, 0);
        acc2[nt][mt] = __builtin_amdgcn_mfma_f32_16x16x32_bf16(L.s, Dhi[mt], acc2[nt][mt], 0, 0, 0);
      }
    }
  }
  float er[4];
#pragma unroll
  for (int mt = 0; mt < 4; ++mt) er[mt] = ee[row0 + 16 * mt + l15];
#pragma unroll
  for (int nt = 0; nt < 3; ++nt) {
    int d0 = 16 * (3 * w + nt) + 4 * lg;
#pragma unroll
    for (int mt = 0; mt < 4; ++mt) {
      int row = row0 + 16 * mt + l15;
#pragma unroll
      for (int r = 0; r < 4; ++r)
        P2[(size_t)(d0 + r) * HW + row] = expf(-er[mt] * fmaxf(acc2[nt][mt][r], 0.f));
    }
  }
}

// ---------- KMIX: Tf(packed) = (concat[S1*P2lo, OhP(packed)]) @ lin3_w^T ----------
__global__ __launch_bounds__(256) void kmix(
    const float* __restrict__ S1, const uint32_t* __restrict__ OhU,
    const float* __restrict__ P2,
    const uint32_t* __restrict__ W3h, const uint32_t* __restrict__ W3l,
    uint32_t* __restrict__ TfU) {
  __shared__ uint32_t Ds[128 * 98];           // 50 KB -> 3 blocks/CU
  const int tid = threadIdx.x;
  const int lane = tid & 63;
  const int w = tid >> 6;
  const int wn = w >> 1, wm = w & 1;
  const int l15 = lane & 15, lg = lane >> 4;
  const int gp0 = blockIdx.x * 128;           // 1024 blocks
  const int b = gp0 >> 14, hw0 = gp0 & 16383;

  f32x4 acc[3][4];
#pragma unroll
  for (int i = 0; i < 3; ++i)
#pragma unroll
    for (int j = 0; j < 4; ++j)
#pragma unroll
      for (int r = 0; r < 4; ++r) acc[i][j][r] = 0.f;

#pragma unroll
  for (int c = 0; c < 2; ++c) {
    if (c) __syncthreads();                   // protect LDS reuse
#pragma unroll
    for (int i = 0; i < 24; ++i) {
      int k = w + 4 * i;
      if (c == 0) {
        const float* sp = S1 + ((size_t)(b * 96 + k)) * HW + hw0;
        const float* pp = P2 + (size_t)k * HW + hw0;
        Ds[lane * 98 + k] = packhl(sp[lane] * pp[lane]);
        Ds[(lane + 64) * 98 + k] = packhl(sp[lane + 64] * pp[lane + 64]);
      } else {
        const uint32_t* sp = OhU + ((size_t)(b * 96 + k)) * HW + hw0;
        Ds[lane * 98 + k] = sp[lane];
        Ds[(lane + 64) * 98 + k] = sp[lane + 64];
      }
    }
    __syncthreads();
#pragma unroll
    for (int ksl = 0; ksl < 3; ++ksl) {
      s8bf Dhi[4], Dlo[4];
#pragma unroll
      for (int j = 0; j < 4; ++j) {
        const uint32_t* p = Ds + (16 * (4 * wm + j) + l15) * 98 + 32 * ksl + 8 * lg;
        uint32_t wv[8];
        *(uint2*)&wv[0] = *(const uint2*)(p);
        *(uint2*)&wv[2] = *(const uint2*)(p + 2);
        *(uint2*)&wv[4] = *(const uint2*)(p + 4);
        *(uint2*)&wv[6] = *(const uint2*)(p + 6);
        unpack8(wv, Dhi[j], Dlo[j]);
      }
#pragma unroll
      for (int i = 0; i < 3; ++i) {
        int base = (((3 * wn + i) * 6 + 3 * c + ksl) * 64 + lane) * 4;
        FragU H, L;
        *(uint4*)H.u = *(const uint4*)(W3h + base);
        *(uint4*)L.u = *(const uint4*)(W3l + base);
#pragma unroll
        for (int j = 0; j < 4; ++j) {
          acc[i][j] = __builtin_amdgcn_mfma_f32_16x16x32_bf16(H.s, Dhi[j], acc[i][j], 0, 0, 0);
          acc[i][j] = __builtin_amdgcn_mfma_f32_16x16x32_bf16(H.s, Dlo[j], acc[i][j], 0, 0, 0);
          acc[i][j] = __builtin_amdgcn_mfma_f32_16x16x32_bf16(L.s, Dhi[j], acc[i][j], 0, 0, 0);
        }
      }
    }
  }
#pragma unroll
  for (int i = 0; i < 3; ++i) {
    int d0 = 16 * (3 * wn + i) + 4 * lg;
#pragma unroll
    for (int j = 0; j < 4; ++j) {
      int hw = hw0 + 16 * (4 * wm + j) + l15;
#pragma unroll
      for (int r = 0; r < 4; ++r)
        TfU[((size_t)(b * 96 + d0 + r)) * HW + hw] = packhl(acc[i][j][r]);
    }
  }
}

// ---------- K9R: (y3 + b3) -> LN -> *silu(z) -> out GEMM (128 pos/block) ----------
__global__ __launch_bounds__(256) void k9r(
    const float* __restrict__ y3, const float* __restrict__ z,
    const float* __restrict__ lin3b,
    const float* __restrict__ lng, const float* __restrict__ lnb,
    const uint32_t* __restrict__ WOh, const uint32_t* __restrict__ WOl,
    const float* __restrict__ outb, float* __restrict__ out) {
  __shared__ uint32_t Ds2[128 * 97];          // 49.7 KB
  __shared__ float2 red[4][128];              // 4 KB  (total 53.7 KB -> 3 blocks/CU)
  const int tid = threadIdx.x;
  const int lane = tid & 63;
  const int w = tid >> 6;
  const int wn = w >> 1, wm = w & 1;
  const int l15 = lane & 15, lg = lane >> 4;
  const int gp0 = blockIdx.x * 128;           // 1024 blocks
  const int b = gp0 >> 14, hw0 = gp0 & 16383;

  float zA[24], zB[24];
#pragma unroll
  for (int i = 0; i < 24; ++i) {              // prefetch z (hides under LN reduce)
    int k = w + 4 * i;
    const float* zp = z + (size_t)k * BHW + gp0;
    zA[i] = zp[lane];
    zB[i] = zp[lane + 64];
  }
  float vA[24], vB[24];
  float sA = 0.f, qA = 0.f, sB = 0.f, qB = 0.f;
#pragma unroll
  for (int i = 0; i < 24; ++i) {
    int k = w + 4 * i;
    const float* yp = y3 + ((size_t)(b * 96 + k)) * HW + hw0;
    float bk = lin3b[k];
    float tA = yp[lane] + bk;      vA[i] = tA; sA += tA; qA = fmaf(tA, tA, qA);
    float tB = yp[lane + 64] + bk; vB[i] = tB; sB += tB; qB = fmaf(tB, tB, qB);
  }
  red[w][lane] = make_float2(sA, qA);
  red[w][lane + 64] = make_float2(sB, qB);
  __syncthreads();
  float2 a0 = red[0][lane], a1 = red[1][lane], a2 = red[2][lane], a3 = red[3][lane];
  float2 b0 = red[0][lane + 64], b1 = red[1][lane + 64], b2_ = red[2][lane + 64], b3 = red[3][lane + 64];
  float muA = (a0.x + a1.x + a2.x + a3.x) * (1.f / 96.f);
  float vrA = (a0.y + a1.y + a2.y + a3.y) * (1.f / 96.f) - muA * muA;
  float invA = rsqrtf(fmaxf(vrA, 0.f) + 1e-5f);
  float muB = (b0.x + b1.x + b2_.x + b3.x) * (1.f / 96.f);
  float vrB = (b0.y + b1.y + b2_.y + b3.y) * (1.f / 96.f) - muB * muB;
  float invB = rsqrtf(fmaxf(vrB, 0.f) + 1e-5f);
#pragma unroll
  for (int i = 0; i < 24; ++i) {
    int k = w + 4 * i;
    float g = lng[k], bb = lnb[k];
    float uA = (vA[i] - muA) * invA * g + bb;
    Ds2[lane * 97 + k] = packhl(uA * (zA[i] / (1.f + __expf(-zA[i]))));
    float uB = (vB[i] - muB) * invB * g + bb;
    Ds2[(lane + 64) * 97 + k] = packhl(uB * (zB[i] / (1.f + __expf(-zB[i]))));
  }
  __syncthreads();

  f32x4 acc2[3][4];
#pragma unroll
  for (int i = 0; i < 3; ++i) {
    float bv[4];
#pragma unroll
    for (int r = 0; r < 4; ++r) bv[r] = outb[16 * (3 * wn + i) + 4 * lg + r];
#pragma unroll
    for (int j = 0; j < 4; ++j)
#pragma unroll
      for (int r = 0; r < 4; ++r) acc2[i][j][r] = bv[r];
  }
#pragma unroll
  for (int ksl = 0; ksl < 3; ++ksl) {
    s8bf Dhi[4], Dlo[4];
#pragma unroll
    for (int j = 0; j < 4; ++j) {
      const uint32_t* p = Ds2 + (16 * (4 * wm + j) + l15) * 97 + 32 * ksl + 8 * lg;
      uint32_t wv[8];
      *(uint2*)&wv[0] = *(const uint2*)(p);
      *(uint2*)&wv[2] = *(const uint2*)(p + 2);
      *(uint2*)&wv[4] = *(const uint2*)(p + 4);
      *(uint2*)&wv[6] = *(const uint2*)(p + 6);
      unpack8(wv, Dhi[j], Dlo[j]);
    }
#pragma unroll
    for (int i = 0; i < 3; ++i) {
      int base = (((3 * wn + i) * 3 + ksl) * 64 + lane) * 4;
      FragU H, L;
      *(uint4*)H.u = *(const uint4*)(WOh + base);
      *(uint4*)L.u = *(const uint4*)(WOl + base);
#pragma unroll
      for (int j = 0; j < 4; ++j) {
        acc2[i][j] = __builtin_amdgcn_mfma_f32_16x16x32_bf16(H.s, Dhi[j], acc2[i][j], 0, 0, 0);
        acc2[i][j] = __builtin_amdgcn_mfma_f32_16x16x32_bf16(H.s, Dlo[j], acc2[i][j], 0, 0, 0);
        acc2[i][j] = __builtin_amdgcn_mfma_f32_16x16x32_bf16(L.s, Dhi[j], acc2[i][j], 0, 0, 0);
      }
    }
  }
#pragma unroll
  for (int i = 0; i < 3; ++i) {
    int d0 = 16 * (3 * wn + i) + 4 * lg;
#pragma unroll
    for (int j = 0; j < 4; ++j) {
      int hw = hw0 + 16 * (4 * wm + j) + l15;
#pragma unroll
      for (int r = 0; r < 4; ++r)
        out[((size_t)(b * 96 + d0 + r)) * HW + hw] = acc2[i][j][r];
    }
  }
}

extern "C" void kernel_launch(void* const* d_in, const int* in_sizes, int n_in,
                              void* d_out, int out_size, void* d_ws, size_t ws_size,
                              hipStream_t stream) {
  const float* x      = (const float*)d_in[0];
  const float* fe     = (const float*)d_in[1];
  const float* of     = (const float*)d_in[2];
  const float* dw_w   = (const float*)d_in[3];
  const float* dw_b   = (const float*)d_in[4];
  const float* lin_w  = (const float*)d_in[5];
  const float* lin_b  = (const float*)d_in[6];
  const float* k_w    = (const float*)d_in[7];
  const float* k_b    = (const float*)d_in[8];
  const float* lin2_w = (const float*)d_in[9];
  const float* lin2_b = (const float*)d_in[10];
  const float* k2_w   = (const float*)d_in[11];
  const float* k2_b   = (const float*)d_in[12];
  const float* lin3_w = (const float*)d_in[13];
  const float* lin3_b = (const float*)d_in[14];
  const float* ln_g   = (const float*)d_in[15];
  const float* ln_b   = (const float*)d_in[16];
  const float* out_w  = (const float*)d_in[17];
  const float* out_b  = (const float*)d_in[18];
  float* out = (float*)d_out;

  float* ws    = (float*)d_ws;
  float* x1p   = ws;                      // [B][96][HW]: x1(packed) -> S1(f32) -> Tf(packed) -> y3(f32)
  float* z     = x1p   + 12582912;        // [96][B*HW] plane-major f32
  float* ofp   = z     + 12582912;        // [B][96][HW]: xc(f32) -> outline(packed) -> OhP(packed)
  float* cm    = ofp   + 12582912;        // [192][HW] f32
  float* skf   = cm    + 3145728;         // [192][HW] (first 96 planes reused as cmSf scratch)
  float* P1    = skf   + 3145728;         // [96][HW]
  float* P2    = P1    + 1572864;         // [192][HW]
  float* cc    = P2    + 3145728;         // [128][128] (unused)
  float* ee    = cc    + 16384;           // [128][128]
  float* linT  = ee    + 16384;           // (unused)
  float* kT    = linT  + 18432;           // [96][96]
  float* lin2T = kT    + 9216;            // (unused)
  float* k2T   = lin2T + 36864;           // (unused)
  float* lin3T = k2T   + 36864;           // (unused)
  float* outT  = lin3T + 18432;           // (unused)
  float* fet   = outT  + 9216;            // [96][HW]
  uint32_t* FAh = (uint32_t*)(fet + 1572864);  // 8192 u32 each
  uint32_t* FAl = FAh + 8192;
  uint32_t* FTh = FAl + 8192;
  uint32_t* FTl = FTh + 8192;
  uint32_t* WLh = FTl + 8192;             // lin frags:  12x3x64x4 = 9216 u32
  uint32_t* WLl = WLh + 9216;
  uint32_t* W3h = WLl + 9216;             // lin3 frags: 6x6x64x4 = 9216
  uint32_t* W3l = W3h + 9216;
  uint32_t* WOh = W3l + 9216;             // out frags:  6x3x64x4 = 4608
  uint32_t* WOl = WOh + 4608;
  uint32_t* W2h = WOl + 4608;             // lin2 frags: 12x6x64x4 = 18432
  uint32_t* W2l = W2h + 18432;
  uint32_t* K2h = W2l + 18432;            // k2 frags:   18432
  uint32_t* K2l = K2h + 18432;
  float* xc    = ofp;                     // aliases ofp: dead after klin, before k3
  float* cmSf  = skf;                     // [96][HW] temp: mean_b(S1)
  uint32_t* x1u = (uint32_t*)x1p;
  uint32_t* ofu = (uint32_t*)ofp;
  (void)in_sizes; (void)n_in; (void)out_size; (void)ws_size;

  kprep<<<423, 256, 0, stream>>>(ee, FAh, FAl, FTh, FTl,
                                 lin_w, WLh, WLl, lin3_w, W3h, W3l,
                                 out_w, WOh, WOl, lin2_w, W2h, W2l,
                                 k2_w, K2h, K2l, k_w, kT, fe, fet);

  kconv<<<12288, 256, 0, stream>>>(x, dw_w, dw_b, xc);
  klin_mfma<<<2048, 256, 0, stream>>>(xc, WLh, WLl, lin_b, x1u, z);
  k3_transpose_mean<<<256, 256, 0, stream>>>(of, ofu, cm + (size_t)96 * HW);
  k3b_kgemm<<<256, 256, 0, stream>>>(fet, cm + (size_t)96 * HW, kT, k_b, ee, P1);
  // S1(f32) = P1 .* dct2(x1 packed)   (in-place in x1p)
  heat_half<true, false, true><<<768, 256, 0, stream>>>(x1p, x1p, P1, FAh, FAl, 96);
  // mean_b(y1) = idct2(mean_b(S1))
  k5_mean<<<6144, 256, 0, stream>>>(x1p, cmSf);
  heat_half<false, false, false><<<96, 256, 0, stream>>>(cmSf, cm, nullptr, FTh, FTl, 96);
  // P2 (k6+k7 fused, MFMA)
  k67_mfma<<<256, 256, 0, stream>>>(cm, W2h, W2l, lin2_b, K2h, K2l, k2_b, ee, P2);
  // OhP(packed) = dct2(outline packed) .* P2hi  (in-place in ofp)
  heat_half<true, true, true><<<768, 256, 0, stream>>>(ofp, ofp, P2 + (size_t)96 * HW, FAh, FAl, 96);
  // Tf(packed) = (concat[S1*P2lo, OhP]) @ lin3^T  (in-place into x1p)
  kmix<<<1024, 256, 0, stream>>>(x1p, ofu, P2, W3h, W3l, x1u);
  // y3(f32) = idct2(Tf packed)  (in-place in x1p)
  heat_half<true, false, false><<<768, 256, 0, stream>>>(x1p, x1p, nullptr, FTh, FTl, 96);
  k9r<<<1024, 256, 0, stream>>>(x1p, z, lin3_b, ln_g, ln_b, WOh, WOl, out_b, out);
}

// Round 14
// 353.697 us; speedup vs baseline: 1.3281x; 1.0135x over previous
//
#include <hip/hip_runtime.h>
#include <math.h>
#include <stdint.h>

#ifndef M_PI
#define M_PI 3.14159265358979323846
#endif

#define HW 16384
#define BHW 131072

typedef __attribute__((ext_vector_type(8))) short s8bf;    // 8 bf16 = 4 VGPR
typedef __attribute__((ext_vector_type(4))) float f32x4;   // MFMA C/D

union FragU { uint32_t u[4]; s8bf s; };

// ---------- bf16 split helpers ----------
__device__ __forceinline__ uint32_t bf16h(float x) {
  uint32_t u = __float_as_uint(x);
  return (u + 0x7FFFu + ((u >> 16) & 1u)) >> 16;     // RNE, low 16 bits
}
__device__ __forceinline__ uint32_t packhl(float x) {  // u32 = (hi<<16)|lo
  uint32_t h = bf16h(x);
  float r = x - __uint_as_float(h << 16);
  return (h << 16) | bf16h(r);
}
__device__ __forceinline__ void unpack8(const uint32_t* w, s8bf& hi, s8bf& lo) {
  FragU H, L;
#pragma unroll
  for (int j = 0; j < 4; ++j) {
    H.u[j] = __builtin_amdgcn_perm(w[2 * j + 1], w[2 * j], 0x07060302u);
    L.u[j] = __builtin_amdgcn_perm(w[2 * j + 1], w[2 * j], 0x05040100u);
  }
  hi = H.s; lo = L.s;
}

__device__ __forceinline__ float cval(int a, int b) {
  double v = cos((double)a * ((double)b + 0.5) * (M_PI / 128.0)) * sqrt(2.0 / 128.0);
  if (a == 0) v *= 0.70710678118654752440;
  return (float)v;
}

// ---------- weight A-frag device helper: W[D][K] row-major -> hi/lo frags ----------
__device__ __forceinline__ void wfrag_dev(const float* __restrict__ src,
                                          uint32_t* __restrict__ Fh,
                                          uint32_t* __restrict__ Fl,
                                          int D, int K, int tid) {
  int nksl = K >> 5;
  int total = (D >> 4) * nksl * 64;
  if (tid >= total) return;
  int lane = tid & 63, fid = tid >> 6;
  int nt = fid / nksl, ksl = fid - nt * nksl;
  int d = 16 * nt + (lane & 15);
  int k0 = 32 * ksl + 8 * (lane >> 4);
#pragma unroll
  for (int j = 0; j < 4; ++j) {
    uint32_t p0 = packhl(src[d * K + k0 + 2 * j]);
    uint32_t p1 = packhl(src[d * K + k0 + 2 * j + 1]);
    Fh[tid * 4 + j] = (p0 >> 16) | (p1 & 0xFFFF0000u);
    Fl[tid * 4 + j] = (p0 & 0xFFFFu) | (p1 << 16);
  }
}

// ---------- KPREP: all table/weight prep in one launch (423 blocks) ----------
__global__ __launch_bounds__(256) void kprep(
    float* __restrict__ ee,
    uint32_t* __restrict__ FAh, uint32_t* __restrict__ FAl,
    uint32_t* __restrict__ FTh, uint32_t* __restrict__ FTl,
    const float* __restrict__ lin_w, uint32_t* __restrict__ WLh, uint32_t* __restrict__ WLl,
    const float* __restrict__ lin3_w, uint32_t* __restrict__ W3h, uint32_t* __restrict__ W3l,
    const float* __restrict__ out_w, uint32_t* __restrict__ WOh, uint32_t* __restrict__ WOl,
    const float* __restrict__ lin2_w, uint32_t* __restrict__ W2h, uint32_t* __restrict__ W2l,
    const float* __restrict__ k2_w, uint32_t* __restrict__ K2h, uint32_t* __restrict__ K2l,
    const float* __restrict__ k_w, float* __restrict__ kT,
    const float* __restrict__ fe, float* __restrict__ fet) {
  __shared__ float tile[64 * 97];
  const int bb = blockIdx.x;
  const int tid = threadIdx.x;
  if (bb < 64) {                              // ee table
    int gid = bb * 256 + tid;
    int n = gid >> 7, m = gid & 127;
    double wn = (double)n * (M_PI / 128.0), wm = (double)m * (M_PI / 128.0);
    ee[gid] = (float)(wn * wn + wm * wm);
  } else if (bb < 72) {                       // DCT frags
    int t2 = (bb - 64) * 256 + tid;
    int lane = t2 & 63, fid = t2 >> 6;
    int mt = fid >> 2, ks = fid & 3;
    int n = 16 * mt + (lane & 15);
    int k0 = 32 * ks + 8 * (lane >> 4);
#pragma unroll
    for (int j = 0; j < 4; ++j) {
      uint32_t p0 = packhl(cval(n, k0 + 2 * j)), p1 = packhl(cval(n, k0 + 2 * j + 1));
      FAh[t2 * 4 + j] = (p0 >> 16) | (p1 & 0xFFFF0000u);
      FAl[t2 * 4 + j] = (p0 & 0xFFFFu) | (p1 << 16);
      uint32_t q0 = packhl(cval(k0 + 2 * j, n)), q1 = packhl(cval(k0 + 2 * j + 1, n));
      FTh[t2 * 4 + j] = (q0 >> 16) | (q1 & 0xFFFF0000u);
      FTl[t2 * 4 + j] = (q0 & 0xFFFFu) | (q1 << 16);
    }
  } else if (bb < 81) {
    wfrag_dev(lin_w, WLh, WLl, 192, 96, (bb - 72) * 256 + tid);
  } else if (bb < 90) {
    wfrag_dev(lin3_w, W3h, W3l, 96, 192, (bb - 81) * 256 + tid);
  } else if (bb < 95) {
    wfrag_dev(out_w, WOh, WOl, 96, 96, (bb - 90) * 256 + tid);
  } else if (bb < 113) {
    wfrag_dev(lin2_w, W2h, W2l, 192, 192, (bb - 95) * 256 + tid);
  } else if (bb < 131) {
    wfrag_dev(k2_w, K2h, K2l, 192, 192, (bb - 113) * 256 + tid);
  } else if (bb < 167) {                      // k_w transpose
    int gid = (bb - 131) * 256 + tid;
    if (gid < 96 * 96) {
      int d = gid / 96, c = gid % 96;
      kT[c * 96 + d] = k_w[gid];
    }
  } else {                                    // fe transpose (256 blocks)
    int hw0 = (bb - 167) * 64;
#pragma unroll
    for (int t = 0; t < 24; ++t) {
      int l = tid + t * 256;
      int r = l / 96, c0 = l % 96;
      tile[r * 97 + c0] = fe[((size_t)hw0 + r) * 96 + c0];
    }
    __syncthreads();
#pragma unroll
    for (int t = 0; t < 24; ++t) {
      int l = tid + t * 256;
      int c0 = l >> 6, r = l & 63;
      fet[(size_t)c0 * HW + hw0 + r] = tile[r * 97 + c0];
    }
  }
}

// ---------- KC: depthwise 3x3 conv, float4 per thread, PACKED plane-major out ----------
__global__ __launch_bounds__(256) void kconv(
    const float* __restrict__ x, const float* __restrict__ dw_w,
    const float* __restrict__ dw_b, uint32_t* __restrict__ xcu) {
  int gid = blockIdx.x * 256 + threadIdx.x;   // B*96*4096 = 3145728
  int p = gid >> 12;                          // plane b*96+c
  int q = gid & 4095;
  int h = q >> 5, w4 = (q & 31) << 2;
  int c = p % 96;
  const float* pw = dw_w + c * 9;
  const float* row = x + (size_t)p * HW + h * 128 + w4;
  bool tp = h > 0, bt = h < 127, lf = w4 > 0, rt = w4 < 124;
  float4 t_, m_, b_;
  float tl, tr, ml, mr, bl, br;
  m_ = *(const float4*)row;
  ml = lf ? row[-1] : 0.f;
  mr = rt ? row[4] : 0.f;
  if (tp) {
    t_ = *(const float4*)(row - 128);
    tl = lf ? row[-129] : 0.f;
    tr = rt ? row[-124] : 0.f;
  } else { t_ = make_float4(0.f, 0.f, 0.f, 0.f); tl = tr = 0.f; }
  if (bt) {
    b_ = *(const float4*)(row + 128);
    bl = lf ? row[127] : 0.f;
    br = rt ? row[132] : 0.f;
  } else { b_ = make_float4(0.f, 0.f, 0.f, 0.f); bl = br = 0.f; }
  float w0 = pw[0], w1 = pw[1], w2 = pw[2], w3 = pw[3], w4w = pw[4],
        w5 = pw[5], w6 = pw[6], w7 = pw[7], w8 = pw[8];
  float bias = dw_b[c];
  float o0, o1, o2, o3;
  o0 = tl * w0 + t_.x * w1 + t_.y * w2 + ml * w3 + m_.x * w4w + m_.y * w5 + bl * w6 + b_.x * w7 + b_.y * w8 + bias;
  o1 = t_.x * w0 + t_.y * w1 + t_.z * w2 + m_.x * w3 + m_.y * w4w + m_.z * w5 + b_.x * w6 + b_.y * w7 + b_.z * w8 + bias;
  o2 = t_.y * w0 + t_.z * w1 + t_.w * w2 + m_.y * w3 + m_.z * w4w + m_.w * w5 + b_.y * w6 + b_.z * w7 + b_.w * w8 + bias;
  o3 = t_.z * w0 + t_.w * w1 + tr * w2 + m_.z * w3 + m_.w * w4w + mr * w5 + b_.z * w6 + b_.w * w7 + br * w8 + bias;
  uint4 ou = make_uint4(packhl(o0), packhl(o1), packhl(o2), packhl(o3));
  *(uint4*)(xcu + (size_t)p * HW + h * 128 + w4) = ou;
}

// ---------- KL-MFMA: [B*HW,96] @ lin_w^T -> x1 planes (PACKED u32) + z planes (f32) ----------
__global__ __launch_bounds__(256) void klin_mfma(
    const uint32_t* __restrict__ xcu, const uint32_t* __restrict__ WLh,
    const uint32_t* __restrict__ WLl, const float* __restrict__ lin_b,
    uint32_t* __restrict__ x1u, float* __restrict__ z) {
  __shared__ uint32_t Ds[64 * 102];   // [m][k], 26 KB
  const int tid = threadIdx.x;
  const int lane = tid & 63;
  const int w = tid >> 6;
  const int l15 = lane & 15, lg = lane >> 4;
  const int gp0 = blockIdx.x * 64;
  const int b = gp0 >> 14, hw0 = gp0 & 16383;

#pragma unroll
  for (int i = 0; i < 24; ++i) {      // stage xc (packed) -> Ds[m*102+k]
    int k = w + 4 * i;
    Ds[lane * 102 + k] = xcu[((size_t)(b * 96 + k)) * HW + hw0 + lane];
  }
  __syncthreads();

  f32x4 acc[3][4];
#pragma unroll
  for (int nt = 0; nt < 3; ++nt) {
    float bv[4];
#pragma unroll
    for (int r = 0; r < 4; ++r) bv[r] = lin_b[16 * (3 * w + nt) + 4 * lg + r];
#pragma unroll
    for (int mt = 0; mt < 4; ++mt)
#pragma unroll
      for (int r = 0; r < 4; ++r) acc[nt][mt][r] = bv[r];
  }

#pragma unroll
  for (int ksl = 0; ksl < 3; ++ksl) {
    s8bf Dhi[4], Dlo[4];
#pragma unroll
    for (int mt = 0; mt < 4; ++mt) {
      const uint32_t* p = Ds + (16 * mt + l15) * 102 + 32 * ksl + 8 * lg;
      uint32_t wv[8];
      *(uint2*)&wv[0] = *(const uint2*)(p);
      *(uint2*)&wv[2] = *(const uint2*)(p + 2);
      *(uint2*)&wv[4] = *(const uint2*)(p + 4);
      *(uint2*)&wv[6] = *(const uint2*)(p + 6);
      unpack8(wv, Dhi[mt], Dlo[mt]);
    }
#pragma unroll
    for (int nt = 0; nt < 3; ++nt) {
      int base = (((3 * w + nt) * 3 + ksl) * 64 + lane) * 4;
      FragU H, L;
      *(uint4*)H.u = *(const uint4*)(WLh + base);
      *(uint4*)L.u = *(const uint4*)(WLl + base);
#pragma unroll
      for (int mt = 0; mt < 4; ++mt) {
        acc[nt][mt] = __builtin_amdgcn_mfma_f32_16x16x32_bf16(H.s, Dhi[mt], acc[nt][mt], 0, 0, 0);
        acc[nt][mt] = __builtin_amdgcn_mfma_f32_16x16x32_bf16(H.s, Dlo[mt], acc[nt][mt], 0, 0, 0);
        acc[nt][mt] = __builtin_amdgcn_mfma_f32_16x16x32_bf16(L.s, Dhi[mt], acc[nt][mt], 0, 0, 0);
      }
    }
  }
#pragma unroll
  for (int nt = 0; nt < 3; ++nt) {
    int d0 = 16 * (3 * w + nt) + 4 * lg;
#pragma unroll
    for (int mt = 0; mt < 4; ++mt) {
#pragma unroll
      for (int r = 0; r < 4; ++r) {
        int d = d0 + r;
        if (d < 96)
          x1u[((size_t)(b * 96 + d)) * HW + hw0 + 16 * mt + l15] = packhl(acc[nt][mt][r]);
        else
          z[((size_t)(d - 96)) * BHW + gp0 + 16 * mt + l15] = acc[nt][mt][r];
      }
    }
  }
}

// ---------- K3: outline_feat transpose to plane-major (PACKED) + mean over B (f32) ----------
__global__ __launch_bounds__(256) void k3_transpose_mean(
    const float* __restrict__ of, uint32_t* __restrict__ ofu, float* __restrict__ cmU) {
  __shared__ float tile[64 * 97];
  int hw0 = blockIdx.x * 64;
  int tid = threadIdx.x;
  float sum[24];
#pragma unroll
  for (int t = 0; t < 24; ++t) sum[t] = 0.f;
  for (int b = 0; b < 8; ++b) {
    __syncthreads();
#pragma unroll
    for (int t = 0; t < 24; ++t) {
      int l = tid + t * 256;
      int r = l / 96, c0 = l % 96;
      tile[r * 97 + c0] = of[((size_t)b * 16384 + hw0 + r) * 96 + c0];
    }
    __syncthreads();
#pragma unroll
    for (int t = 0; t < 24; ++t) {
      int l = tid + t * 256;
      int c0 = l >> 6, r = l & 63;
      float v = tile[r * 97 + c0];
      sum[t] += v;
      ofu[(size_t)(b * 96 + c0) * HW + hw0 + r] = packhl(v);
    }
  }
#pragma unroll
  for (int t = 0; t < 24; ++t) {
    int l = tid + t * 256;
    int c0 = l >> 6, r = l & 63;
    cmU[(size_t)c0 * HW + hw0 + r] = sum[t] * 0.125f;
  }
}

// ---------- K3b: k = relu((fet+otm)@k_w^T + k_b); P1 = exp(-e*k) ----------
__global__ __launch_bounds__(256) void k3b_kgemm(
    const float* __restrict__ fet, const float* __restrict__ otm,
    const float* __restrict__ kT, const float* __restrict__ kb,
    const float* __restrict__ ee, float* __restrict__ P1) {
  int tid = threadIdx.x;
  int lane = tid & 63;
  int n0 = __builtin_amdgcn_readfirstlane((tid >> 6) * 24);
  int row = blockIdx.x * 64 + lane;           // 256 blocks
  float acc[24];
#pragma unroll
  for (int j = 0; j < 24; ++j) acc[j] = kb[n0 + j];
#pragma unroll 4
  for (int c = 0; c < 96; ++c) {
    float a = fet[(size_t)c * HW + row] + otm[(size_t)c * HW + row];
    const float* wr = kT + c * 96 + n0;
#pragma unroll
    for (int j = 0; j < 24; ++j) acc[j] = fmaf(a, wr[j], acc[j]);
  }
  float er = ee[row];
#pragma unroll
  for (int j = 0; j < 24; ++j)
    P1[(size_t)(n0 + j) * HW + row] = expf(-er * fmaxf(acc[j], 0.f));
}

// ---------- MFMA transform primitives ----------
template <bool DATA_A>
__device__ __forceinline__ void heat_step(
    const uint32_t* __restrict__ Fh, const uint32_t* __restrict__ Fl,
    const uint32_t* __restrict__ Ds, f32x4 (&acc)[4][4], int wm, int wn, int lane) {
  const int l15 = lane & 15, lg = lane >> 4;
  const int wd = DATA_A ? wm : wn;
  const int wf = DATA_A ? wn : wm;
#pragma unroll
  for (int ksl = 0; ksl < 4; ++ksl) {
    s8bf Dhi[4], Dlo[4], Fhi[4], Flo[4];
#pragma unroll
    for (int t = 0; t < 4; ++t) {
      const uint32_t* p = Ds + (64 * wd + 16 * t + l15) * 130 + 32 * ksl + 8 * lg;
      uint32_t wv[8];
      *(uint2*)&wv[0] = *(const uint2*)(p);
      *(uint2*)&wv[2] = *(const uint2*)(p + 2);
      *(uint2*)&wv[4] = *(const uint2*)(p + 4);
      *(uint2*)&wv[6] = *(const uint2*)(p + 6);
      unpack8(wv, Dhi[t], Dlo[t]);
    }
#pragma unroll
    for (int t = 0; t < 4; ++t) {
      int base = (((4 * wf + t) * 4 + ksl) * 64 + lane) * 4;
      FragU H, L;
      *(uint4*)H.u = *(const uint4*)(Fh + base);
      *(uint4*)L.u = *(const uint4*)(Fl + base);
      Fhi[t] = H.s; Flo[t] = L.s;
    }
    const s8bf* Ah = DATA_A ? Dhi : Fhi;
    const s8bf* Al = DATA_A ? Dlo : Flo;
    const s8bf* Bh = DATA_A ? Fhi : Dhi;
    const s8bf* Bl = DATA_A ? Flo : Dlo;
#pragma unroll
    for (int mi = 0; mi < 4; ++mi)
#pragma unroll
      for (int ni = 0; ni < 4; ++ni)
        acc[mi][ni] = __builtin_amdgcn_mfma_f32_16x16x32_bf16(Ah[mi], Bh[ni], acc[mi][ni], 0, 0, 0);
#pragma unroll
    for (int mi = 0; mi < 4; ++mi)
#pragma unroll
      for (int ni = 0; ni < 4; ++ni)
        acc[mi][ni] = __builtin_amdgcn_mfma_f32_16x16x32_bf16(Ah[mi], Bl[ni], acc[mi][ni], 0, 0, 0);
#pragma unroll
    for (int mi = 0; mi < 4; ++mi)
#pragma unroll
      for (int ni = 0; ni < 4; ++ni)
        acc[mi][ni] = __builtin_amdgcn_mfma_f32_16x16x32_bf16(Al[mi], Bh[ni], acc[mi][ni], 0, 0, 0);
  }
}

// ---------- heat_half: Out = F * In * F^T; PIN: packed-u32 input; POUT: packed output ----------
template <bool PIN, bool POUT, bool USE_P>
__global__ __launch_bounds__(256, 2) void heat_half(
    const float* __restrict__ In, float* __restrict__ Out,
    const float* __restrict__ P, const uint32_t* __restrict__ Fh,
    const uint32_t* __restrict__ Fl, int Cmod) {
  __shared__ uint32_t Ds[128 * 130];
  const int tid = threadIdx.x;
  const int lane = tid & 63;
  const int w = tid >> 6;
  const int wm = w >> 1, wn = w & 1;
  const int l15 = lane & 15, lg = lane >> 4;
  const float* Ip = In + (size_t)blockIdx.x * HW;
  float* Op = Out + (size_t)blockIdx.x * HW;
  const float* Pp = nullptr;
  if constexpr (USE_P) Pp = P + (size_t)(blockIdx.x % Cmod) * HW;

  {
    int col = tid & 127, r0 = tid >> 7;
    if constexpr (PIN) {
      const uint32_t* Iu = (const uint32_t*)Ip;
#pragma unroll
      for (int i = 0; i < 64; ++i) {
        int row = r0 + 2 * i;
        Ds[col * 130 + row] = Iu[row * 128 + col];
      }
    } else {
#pragma unroll
      for (int i = 0; i < 64; ++i) {
        int row = r0 + 2 * i;
        Ds[col * 130 + row] = packhl(Ip[row * 128 + col]);
      }
    }
  }
  __syncthreads();

  f32x4 acc[4][4];
  const f32x4 zero4 = {0.f, 0.f, 0.f, 0.f};
#pragma unroll
  for (int mi = 0; mi < 4; ++mi)
#pragma unroll
    for (int ni = 0; ni < 4; ++ni) acc[mi][ni] = zero4;
  heat_step<false>(Fh, Fl, Ds, acc, wm, wn, lane);     // T = F * In
  __syncthreads();
#pragma unroll
  for (int mi = 0; mi < 4; ++mi)
#pragma unroll
    for (int ni = 0; ni < 4; ++ni)
#pragma unroll
      for (int r = 0; r < 4; ++r)
        Ds[(64 * wm + 16 * mi + 4 * lg + r) * 130 + 64 * wn + 16 * ni + l15] =
            packhl(acc[mi][ni][r]);
  __syncthreads();

#pragma unroll
  for (int mi = 0; mi < 4; ++mi)
#pragma unroll
    for (int ni = 0; ni < 4; ++ni) acc[mi][ni] = zero4;
  heat_step<true>(Fh, Fl, Ds, acc, wm, wn, lane);      // Out = T * F^T
#pragma unroll
  for (int mi = 0; mi < 4; ++mi)
#pragma unroll
    for (int ni = 0; ni < 4; ++ni) {
      int row = 64 * wm + 16 * mi + 4 * lg;
      int col = 64 * wn + 16 * ni + l15;
#pragma unroll
      for (int r = 0; r < 4; ++r) {
        float v = acc[mi][ni][r];
        if constexpr (USE_P) v *= Pp[(row + r) * 128 + col];
        if constexpr (POUT)
          ((uint32_t*)Op)[(row + r) * 128 + col] = packhl(v);
        else
          Op[(row + r) * 128 + col] = v;
      }
    }
}

// ---------- K5: plane-mean over batch: dst[c][s] = mean_b src[b*96+c][s] (f32 src) ----------
__global__ void k5_mean(const float* __restrict__ src, float* __restrict__ dst) {
  int idx = blockIdx.x * 256 + threadIdx.x;
  int c = idx >> 14, s = idx & 16383;
  float sum = 0.f;
#pragma unroll
  for (int b = 0; b < 8; ++b) sum += src[(size_t)(b * 96 + c) * HW + s];
  dst[idx] = sum * 0.125f;
}

// ---------- K67-MFMA: skf = cm@lin2^T+b2; k2 = relu(skf@k2^T+b2k); P2 = exp(-e*k2) ----------
__global__ __launch_bounds__(256) void k67_mfma(
    const float* __restrict__ cm,
    const uint32_t* __restrict__ W2h, const uint32_t* __restrict__ W2l,
    const float* __restrict__ b2,
    const uint32_t* __restrict__ K2h, const uint32_t* __restrict__ K2l,
    const float* __restrict__ b2k, const float* __restrict__ ee,
    float* __restrict__ P2) {
  __shared__ uint32_t Ds[64 * 194];           // 48.5 KB
  const int tid = threadIdx.x;
  const int lane = tid & 63;
  const int w = tid >> 6;
  const int l15 = lane & 15, lg = lane >> 4;
  const int row0 = blockIdx.x * 64;           // 256 blocks

#pragma unroll
  for (int i = 0; i < 48; ++i) {              // stage cm -> Ds[m*194+k]
    int k = w + 4 * i;
    Ds[lane * 194 + k] = packhl(cm[(size_t)k * HW + row0 + lane]);
  }
  __syncthreads();

  f32x4 acc[3][4];
#pragma unroll
  for (int nt = 0; nt < 3; ++nt) {
    float bv[4];
#pragma unroll
    for (int r = 0; r < 4; ++r) bv[r] = b2[16 * (3 * w + nt) + 4 * lg + r];
#pragma unroll
    for (int mt = 0; mt < 4; ++mt)
#pragma unroll
      for (int r = 0; r < 4; ++r) acc[nt][mt][r] = bv[r];
  }
#pragma unroll
  for (int ksl = 0; ksl < 6; ++ksl) {
    s8bf Dhi[4], Dlo[4];
#pragma unroll
    for (int mt = 0; mt < 4; ++mt) {
      const uint32_t* p = Ds + (16 * mt + l15) * 194 + 32 * ksl + 8 * lg;
      uint32_t wv[8];
      *(uint2*)&wv[0] = *(const uint2*)(p);
      *(uint2*)&wv[2] = *(const uint2*)(p + 2);
      *(uint2*)&wv[4] = *(const uint2*)(p + 4);
      *(uint2*)&wv[6] = *(const uint2*)(p + 6);
      unpack8(wv, Dhi[mt], Dlo[mt]);
    }
#pragma unroll
    for (int nt = 0; nt < 3; ++nt) {
      int base = (((3 * w + nt) * 6 + ksl) * 64 + lane) * 4;
      FragU H, L;
      *(uint4*)H.u = *(const uint4*)(W2h + base);
      *(uint4*)L.u = *(const uint4*)(W2l + base);
#pragma unroll
      for (int mt = 0; mt < 4; ++mt) {
        acc[nt][mt] = __builtin_amdgcn_mfma_f32_16x16x32_bf16(H.s, Dhi[mt], acc[nt][mt], 0, 0, 0);
        acc[nt][mt] = __builtin_amdgcn_mfma_f32_16x16x32_bf16(H.s, Dlo[mt], acc[nt][mt], 0, 0, 0);
        acc[nt][mt] = __builtin_amdgcn_mfma_f32_16x16x32_bf16(L.s, Dhi[mt], acc[nt][mt], 0, 0, 0);
      }
    }
  }
  __syncthreads();
#pragma unroll
  for (int nt = 0; nt < 3; ++nt) {
    int d0 = 16 * (3 * w + nt) + 4 * lg;
#pragma unroll
    for (int mt = 0; mt < 4; ++mt) {
      int col = 16 * mt + l15;
#pragma unroll
      for (int r = 0; r < 4; ++r)
        Ds[col * 194 + d0 + r] = packhl(acc[nt][mt][r]);
    }
  }
  __syncthreads();

  f32x4 acc2[3][4];
#pragma unroll
  for (int nt = 0; nt < 3; ++nt) {
    float bv[4];
#pragma unroll
    for (int r = 0; r < 4; ++r) bv[r] = b2k[16 * (3 * w + nt) + 4 * lg + r];
#pragma unroll
    for (int mt = 0; mt < 4; ++mt)
#pragma unroll
      for (int r = 0; r < 4; ++r) acc2[nt][mt][r] = bv[r];
  }
#pragma unroll
  for (int ksl = 0; ksl < 6; ++ksl) {
    s8bf Dhi[4], Dlo[4];
#pragma unroll
    for (int mt = 0; mt < 4; ++mt) {
      const uint32_t* p = Ds + (16 * mt + l15) * 194 + 32 * ksl + 8 * lg;
      uint32_t wv[8];
      *(uint2*)&wv[0] = *(const uint2*)(p);
      *(uint2*)&wv[2] = *(const uint2*)(p + 2);
      *(uint2*)&wv[4] = *(const uint2*)(p + 4);
      *(uint2*)&wv[6] = *(const uint2*)(p + 6);
      unpack8(wv, Dhi[mt], Dlo[mt]);
    }
#pragma unroll
    for (int nt = 0; nt < 3; ++nt) {
      int base = (((3 * w + nt) * 6 + ksl) * 64 + lane) * 4;
      FragU H, L;
      *(uint4*)H.u = *(const uint4*)(K2h + base);
      *(uint4*)L.u = *(const uint4*)(K2l + base);
#pragma unroll
      for (int mt = 0; mt < 4; ++mt) {
        acc2[nt][mt] = __builtin_amdgcn_mfma_f32_16x16x32_bf16(H.s, Dhi[mt], acc2[nt][mt], 0, 0, 0);
        acc2[nt][mt] = __builtin_amdgcn_mfma_f32_16x16x32_bf16(H.s, Dlo[mt], acc2[nt][mt], 0, 0, 0);
        acc2[nt][mt] = __builtin_amdgcn_mfma_f32_16x16x32_bf16(L.s, Dhi[mt], acc2[nt][mt], 0, 0, 0);
      }
    }
  }
  float er[4];
#pragma unroll
  for (int mt = 0; mt < 4; ++mt) er[mt] = ee[row0 + 16 * mt + l15];
#pragma unroll
  for (int nt = 0; nt < 3; ++nt) {
    int d0 = 16 * (3 * w + nt) + 4 * lg;
#pragma unroll
    for (int mt = 0; mt < 4; ++mt) {
      int row = row0 + 16 * mt + l15;
#pragma unroll
      for (int r = 0; r < 4; ++r)
        P2[(size_t)(d0 + r) * HW + row] = expf(-er[mt] * fmaxf(acc2[nt][mt][r], 0.f));
    }
  }
}

// ---------- KMIX: Tf(packed) = (concat[S1*P2lo, OhP(packed)]) @ lin3_w^T ----------
__global__ __launch_bounds__(256) void kmix(
    const float* __restrict__ S1, const uint32_t* __restrict__ OhU,
    const float* __restrict__ P2,
    const uint32_t* __restrict__ W3h, const uint32_t* __restrict__ W3l,
    uint32_t* __restrict__ TfU) {
  __shared__ uint32_t Ds[128 * 98];           // 50 KB -> 3 blocks/CU
  const int tid = threadIdx.x;
  const int lane = tid & 63;
  const int w = tid >> 6;
  const int wn = w >> 1, wm = w & 1;
  const int l15 = lane & 15, lg = lane >> 4;
  const int gp0 = blockIdx.x * 128;           // 1024 blocks
  const int b = gp0 >> 14, hw0 = gp0 & 16383;

  f32x4 acc[3][4];
#pragma unroll
  for (int i = 0; i < 3; ++i)
#pragma unroll
    for (int j = 0; j < 4; ++j)
#pragma unroll
      for (int r = 0; r < 4; ++r) acc[i][j][r] = 0.f;

#pragma unroll
  for (int c = 0; c < 2; ++c) {
    if (c) __syncthreads();                   // protect LDS reuse
#pragma unroll
    for (int i = 0; i < 24; ++i) {
      int k = w + 4 * i;
      if (c == 0) {
        const float* sp = S1 + ((size_t)(b * 96 + k)) * HW + hw0;
        const float* pp = P2 + (size_t)k * HW + hw0;
        Ds[lane * 98 + k] = packhl(sp[lane] * pp[lane]);
        Ds[(lane + 64) * 98 + k] = packhl(sp[lane + 64] * pp[lane + 64]);
      } else {
        const uint32_t* sp = OhU + ((size_t)(b * 96 + k)) * HW + hw0;
        Ds[lane * 98 + k] = sp[lane];
        Ds[(lane + 64) * 98 + k] = sp[lane + 64];
      }
    }
    __syncthreads();
#pragma unroll
    for (int ksl = 0; ksl < 3; ++ksl) {
      s8bf Dhi[4], Dlo[4];
#pragma unroll
      for (int j = 0; j < 4; ++j) {
        const uint32_t* p = Ds + (16 * (4 * wm + j) + l15) * 98 + 32 * ksl + 8 * lg;
        uint32_t wv[8];
        *(uint2*)&wv[0] = *(const uint2*)(p);
        *(uint2*)&wv[2] = *(const uint2*)(p + 2);
        *(uint2*)&wv[4] = *(const uint2*)(p + 4);
        *(uint2*)&wv[6] = *(const uint2*)(p + 6);
        unpack8(wv, Dhi[j], Dlo[j]);
      }
#pragma unroll
      for (int i = 0; i < 3; ++i) {
        int base = (((3 * wn + i) * 6 + 3 * c + ksl) * 64 + lane) * 4;
        FragU H, L;
        *(uint4*)H.u = *(const uint4*)(W3h + base);
        *(uint4*)L.u = *(const uint4*)(W3l + base);
#pragma unroll
        for (int j = 0; j < 4; ++j) {
          acc[i][j] = __builtin_amdgcn_mfma_f32_16x16x32_bf16(H.s, Dhi[j], acc[i][j], 0, 0, 0);
          acc[i][j] = __builtin_amdgcn_mfma_f32_16x16x32_bf16(H.s, Dlo[j], acc[i][j], 0, 0, 0);
          acc[i][j] = __builtin_amdgcn_mfma_f32_16x16x32_bf16(L.s, Dhi[j], acc[i][j], 0, 0, 0);
        }
      }
    }
  }
#pragma unroll
  for (int i = 0; i < 3; ++i) {
    int d0 = 16 * (3 * wn + i) + 4 * lg;
#pragma unroll
    for (int j = 0; j < 4; ++j) {
      int hw = hw0 + 16 * (4 * wm + j) + l15;
#pragma unroll
      for (int r = 0; r < 4; ++r)
        TfU[((size_t)(b * 96 + d0 + r)) * HW + hw] = packhl(acc[i][j][r]);
    }
  }
}

// ---------- K9R: (y3 + b3) -> LN -> *silu(z) -> out GEMM (128 pos/block) ----------
__global__ __launch_bounds__(256) void k9r(
    const float* __restrict__ y3, const float* __restrict__ z,
    const float* __restrict__ lin3b,
    const float* __restrict__ lng, const float* __restrict__ lnb,
    const uint32_t* __restrict__ WOh, const uint32_t* __restrict__ WOl,
    const float* __restrict__ outb, float* __restrict__ out) {
  __shared__ uint32_t Ds2[128 * 97];          // 49.7 KB
  __shared__ float2 red[4][128];              // 4 KB  (total 53.7 KB)
  const int tid = threadIdx.x;
  const int lane = tid & 63;
  const int w = tid >> 6;
  const int wn = w >> 1, wm = w & 1;
  const int l15 = lane & 15, lg = lane >> 4;
  const int gp0 = blockIdx.x * 128;           // 1024 blocks
  const int b = gp0 >> 14, hw0 = gp0 & 16383;

  float vA[24], vB[24];
  float sA = 0.f, qA = 0.f, sB = 0.f, qB = 0.f;
#pragma unroll
  for (int i = 0; i < 24; ++i) {
    int k = w + 4 * i;
    const float* yp = y3 + ((size_t)(b * 96 + k)) * HW + hw0;
    float bk = lin3b[k];
    float tA = yp[lane] + bk;      vA[i] = tA; sA += tA; qA = fmaf(tA, tA, qA);
    float tB = yp[lane + 64] + bk; vB[i] = tB; sB += tB; qB = fmaf(tB, tB, qB);
  }
  red[w][lane] = make_float2(sA, qA);
  red[w][lane + 64] = make_float2(sB, qB);
  __syncthreads();
  float2 a0 = red[0][lane], a1 = red[1][lane], a2 = red[2][lane], a3 = red[3][lane];
  float2 b0 = red[0][lane + 64], b1 = red[1][lane + 64], b2_ = red[2][lane + 64], b3 = red[3][lane + 64];
  float muA = (a0.x + a1.x + a2.x + a3.x) * (1.f / 96.f);
  float vrA = (a0.y + a1.y + a2.y + a3.y) * (1.f / 96.f) - muA * muA;
  float invA = rsqrtf(fmaxf(vrA, 0.f) + 1e-5f);
  float muB = (b0.x + b1.x + b2_.x + b3.x) * (1.f / 96.f);
  float vrB = (b0.y + b1.y + b2_.y + b3.y) * (1.f / 96.f) - muB * muB;
  float invB = rsqrtf(fmaxf(vrB, 0.f) + 1e-5f);
#pragma unroll
  for (int i = 0; i < 24; ++i) {
    int k = w + 4 * i;
    const float* zp = z + (size_t)k * BHW + gp0;
    float g = lng[k], bb = lnb[k];
    float zA = zp[lane];
    float uA = (vA[i] - muA) * invA * g + bb;
    Ds2[lane * 97 + k] = packhl(uA * (zA / (1.f + __expf(-zA))));
    float zB = zp[lane + 64];
    float uB = (vB[i] - muB) * invB * g + bb;
    Ds2[(lane + 64) * 97 + k] = packhl(uB * (zB / (1.f + __expf(-zB))));
  }
  __syncthreads();

  f32x4 acc2[3][4];
#pragma unroll
  for (int i = 0; i < 3; ++i) {
    float bv[4];
#pragma unroll
    for (int r = 0; r < 4; ++r) bv[r] = outb[16 * (3 * wn + i) + 4 * lg + r];
#pragma unroll
    for (int j = 0; j < 4; ++j)
#pragma unroll
      for (int r = 0; r < 4; ++r) acc2[i][j][r] = bv[r];
  }
#pragma unroll
  for (int ksl = 0; ksl < 3; ++ksl) {
    s8bf Dhi[4], Dlo[4];
#pragma unroll
    for (int j = 0; j < 4; ++j) {
      const uint32_t* p = Ds2 + (16 * (4 * wm + j) + l15) * 97 + 32 * ksl + 8 * lg;
      uint32_t wv[8];
      *(uint2*)&wv[0] = *(const uint2*)(p);
      *(uint2*)&wv[2] = *(const uint2*)(p + 2);
      *(uint2*)&wv[4] = *(const uint2*)(p + 4);
      *(uint2*)&wv[6] = *(const uint2*)(p + 6);
      unpack8(wv, Dhi[j], Dlo[j]);
    }
#pragma unroll
    for (int i = 0; i < 3; ++i) {
      int base = (((3 * wn + i) * 3 + ksl) * 64 + lane) * 4;
      FragU H, L;
      *(uint4*)H.u = *(const uint4*)(WOh + base);
      *(uint4*)L.u = *(const uint4*)(WOl + base);
#pragma unroll
      for (int j = 0; j < 4; ++j) {
        acc2[i][j] = __builtin_amdgcn_mfma_f32_16x16x32_bf16(H.s, Dhi[j], acc2[i][j], 0, 0, 0);
        acc2[i][j] = __builtin_amdgcn_mfma_f32_16x16x32_bf16(H.s, Dlo[j], acc2[i][j], 0, 0, 0);
        acc2[i][j] = __builtin_amdgcn_mfma_f32_16x16x32_bf16(L.s, Dhi[j], acc2[i][j], 0, 0, 0);
      }
    }
  }
#pragma unroll
  for (int i = 0; i < 3; ++i) {
    int d0 = 16 * (3 * wn + i) + 4 * lg;
#pragma unroll
    for (int j = 0; j < 4; ++j) {
      int hw = hw0 + 16 * (4 * wm + j) + l15;
#pragma unroll
      for (int r = 0; r < 4; ++r)
        out[((size_t)(b * 96 + d0 + r)) * HW + hw] = acc2[i][j][r];
    }
  }
}

extern "C" void kernel_launch(void* const* d_in, const int* in_sizes, int n_in,
                              void* d_out, int out_size, void* d_ws, size_t ws_size,
                              hipStream_t stream) {
  const float* x      = (const float*)d_in[0];
  const float* fe     = (const float*)d_in[1];
  const float* of     = (const float*)d_in[2];
  const float* dw_w   = (const float*)d_in[3];
  const float* dw_b   = (const float*)d_in[4];
  const float* lin_w  = (const float*)d_in[5];
  const float* lin_b  = (const float*)d_in[6];
  const float* k_w    = (const float*)d_in[7];
  const float* k_b    = (const float*)d_in[8];
  const float* lin2_w = (const float*)d_in[9];
  const float* lin2_b = (const float*)d_in[10];
  const float* k2_w   = (const float*)d_in[11];
  const float* k2_b   = (const float*)d_in[12];
  const float* lin3_w = (const float*)d_in[13];
  const float* lin3_b = (const float*)d_in[14];
  const float* ln_g   = (const float*)d_in[15];
  const float* ln_b   = (const float*)d_in[16];
  const float* out_w  = (const float*)d_in[17];
  const float* out_b  = (const float*)d_in[18];
  float* out = (float*)d_out;

  float* ws    = (float*)d_ws;
  float* x1p   = ws;                      // [B][96][HW]: x1(packed) -> S1(f32) -> Tf(packed) -> y3(f32)
  float* z     = x1p   + 12582912;        // [96][B*HW] plane-major f32
  float* ofp   = z     + 12582912;        // [B][96][HW]: xc(packed) -> outline(packed) -> OhP(packed)
  float* cm    = ofp   + 12582912;        // [192][HW] f32
  float* skf   = cm    + 3145728;         // [192][HW] (first 96 planes reused as cmSf scratch)
  float* P1    = skf   + 3145728;         // [96][HW]
  float* P2    = P1    + 1572864;         // [192][HW]
  float* cc    = P2    + 3145728;         // [128][128] (unused)
  float* ee    = cc    + 16384;           // [128][128]
  float* linT  = ee    + 16384;           // (unused)
  float* kT    = linT  + 18432;           // [96][96]
  float* lin2T = kT    + 9216;            // (unused)
  float* k2T   = lin2T + 36864;           // (unused)
  float* lin3T = k2T   + 36864;           // (unused)
  float* outT  = lin3T + 18432;           // (unused)
  float* fet   = outT  + 9216;            // [96][HW]
  uint32_t* FAh = (uint32_t*)(fet + 1572864);  // 8192 u32 each
  uint32_t* FAl = FAh + 8192;
  uint32_t* FTh = FAl + 8192;
  uint32_t* FTl = FTh + 8192;
  uint32_t* WLh = FTl + 8192;             // lin frags:  12x3x64x4 = 9216 u32
  uint32_t* WLl = WLh + 9216;
  uint32_t* W3h = WLl + 9216;             // lin3 frags: 6x6x64x4 = 9216
  uint32_t* W3l = W3h + 9216;
  uint32_t* WOh = W3l + 9216;             // out frags:  6x3x64x4 = 4608
  uint32_t* WOl = WOh + 4608;
  uint32_t* W2h = WOl + 4608;             // lin2 frags: 12x6x64x4 = 18432
  uint32_t* W2l = W2h + 18432;
  uint32_t* K2h = W2l + 18432;            // k2 frags:   18432
  uint32_t* K2l = K2h + 18432;
  float* cmSf  = skf;                     // [96][HW] temp: mean_b(S1)
  uint32_t* x1u = (uint32_t*)x1p;
  uint32_t* ofu = (uint32_t*)ofp;
  uint32_t* xcu = ofu;                    // aliases ofp: dead after klin, before k3
  (void)in_sizes; (void)n_in; (void)out_size; (void)ws_size;

  kprep<<<423, 256, 0, stream>>>(ee, FAh, FAl, FTh, FTl,
                                 lin_w, WLh, WLl, lin3_w, W3h, W3l,
                                 out_w, WOh, WOl, lin2_w, W2h, W2l,
                                 k2_w, K2h, K2l, k_w, kT, fe, fet);

  kconv<<<12288, 256, 0, stream>>>(x, dw_w, dw_b, xcu);
  klin_mfma<<<2048, 256, 0, stream>>>(xcu, WLh, WLl, lin_b, x1u, z);
  k3_transpose_mean<<<256, 256, 0, stream>>>(of, ofu, cm + (size_t)96 * HW);
  k3b_kgemm<<<256, 256, 0, stream>>>(fet, cm + (size_t)96 * HW, kT, k_b, ee, P1);
  // S1(f32) = P1 .* dct2(x1 packed)   (in-place in x1p)
  heat_half<true, false, true><<<768, 256, 0, stream>>>(x1p, x1p, P1, FAh, FAl, 96);
  // mean_b(y1) = idct2(mean_b(S1))
  k5_mean<<<6144, 256, 0, stream>>>(x1p, cmSf);
  heat_half<false, false, false><<<96, 256, 0, stream>>>(cmSf, cm, nullptr, FTh, FTl, 96);
  // P2 (k6+k7 fused, MFMA)
  k67_mfma<<<256, 256, 0, stream>>>(cm, W2h, W2l, lin2_b, K2h, K2l, k2_b, ee, P2);
  // OhP(packed) = dct2(outline packed) .* P2hi  (in-place in ofp)
  heat_half<true, true, true><<<768, 256, 0, stream>>>(ofp, ofp, P2 + (size_t)96 * HW, FAh, FAl, 96);
  // Tf(packed) = (concat[S1*P2lo, OhP]) @ lin3^T  (in-place into x1p)
  kmix<<<1024, 256, 0, stream>>>(x1p, ofu, P2, W3h, W3l, x1u);
  // y3(f32) = idct2(Tf packed)  (in-place in x1p)
  heat_half<true, false, false><<<768, 256, 0, stream>>>(x1p, x1p, nullptr, FTh, FTl, 96);
  k9r<<<1024, 256, 0, stream>>>(x1p, z, lin3_b, ln_g, ln_b, WOh, WOl, out_b, out);
}

// Round 15
// 335.088 us; speedup vs baseline: 1.4019x; 1.0555x over previous
//
#include <hip/hip_runtime.h>
#include <math.h>
#include <stdint.h>

#ifndef M_PI
#define M_PI 3.14159265358979323846
#endif

#define HW 16384
#define BHW 131072

typedef __attribute__((ext_vector_type(8))) short s8bf;    // 8 bf16 = 4 VGPR
typedef __attribute__((ext_vector_type(4))) float f32x4;   // MFMA C/D

union FragU { uint32_t u[4]; s8bf s; };

// ---------- bf16 split helpers ----------
__device__ __forceinline__ uint32_t bf16h(float x) {
  uint32_t u = __float_as_uint(x);
  return (u + 0x7FFFu + ((u >> 16) & 1u)) >> 16;     // RNE, low 16 bits
}
__device__ __forceinline__ uint32_t packhl(float x) {  // u32 = (hi<<16)|lo
  uint32_t h = bf16h(x);
  float r = x - __uint_as_float(h << 16);
  return (h << 16) | bf16h(r);
}
__device__ __forceinline__ void unpack8(const uint32_t* w, s8bf& hi, s8bf& lo) {
  FragU H, L;
#pragma unroll
  for (int j = 0; j < 4; ++j) {
    H.u[j] = __builtin_amdgcn_perm(w[2 * j + 1], w[2 * j], 0x07060302u);
    L.u[j] = __builtin_amdgcn_perm(w[2 * j + 1], w[2 * j], 0x05040100u);
  }
  hi = H.s; lo = L.s;
}

__device__ __forceinline__ float cval(int a, int b) {
  double v = cos((double)a * ((double)b + 0.5) * (M_PI / 128.0)) * sqrt(2.0 / 128.0);
  if (a == 0) v *= 0.70710678118654752440;
  return (float)v;
}

// ---------- weight A-frag device helper: W[D][K] row-major -> hi/lo frags ----------
__device__ __forceinline__ void wfrag_dev(const float* __restrict__ src,
                                          uint32_t* __restrict__ Fh,
                                          uint32_t* __restrict__ Fl,
                                          int D, int K, int tid) {
  int nksl = K >> 5;
  int total = (D >> 4) * nksl * 64;
  if (tid >= total) return;
  int lane = tid & 63, fid = tid >> 6;
  int nt = fid / nksl, ksl = fid - nt * nksl;
  int d = 16 * nt + (lane & 15);
  int k0 = 32 * ksl + 8 * (lane >> 4);
#pragma unroll
  for (int j = 0; j < 4; ++j) {
    uint32_t p0 = packhl(src[d * K + k0 + 2 * j]);
    uint32_t p1 = packhl(src[d * K + k0 + 2 * j + 1]);
    Fh[tid * 4 + j] = (p0 >> 16) | (p1 & 0xFFFF0000u);
    Fl[tid * 4 + j] = (p0 & 0xFFFFu) | (p1 << 16);
  }
}

// ---------- KPREP: all table/weight prep in one launch (423 blocks) ----------
__global__ __launch_bounds__(256) void kprep(
    float* __restrict__ ee,
    uint32_t* __restrict__ FAh, uint32_t* __restrict__ FAl,
    uint32_t* __restrict__ FTh, uint32_t* __restrict__ FTl,
    const float* __restrict__ lin_w, uint32_t* __restrict__ WLh, uint32_t* __restrict__ WLl,
    const float* __restrict__ lin3_w, uint32_t* __restrict__ W3h, uint32_t* __restrict__ W3l,
    const float* __restrict__ out_w, uint32_t* __restrict__ WOh, uint32_t* __restrict__ WOl,
    const float* __restrict__ lin2_w, uint32_t* __restrict__ W2h, uint32_t* __restrict__ W2l,
    const float* __restrict__ k2_w, uint32_t* __restrict__ K2h, uint32_t* __restrict__ K2l,
    const float* __restrict__ k_w, float* __restrict__ kT,
    const float* __restrict__ fe, float* __restrict__ fet) {
  __shared__ float tile[64 * 97];
  const int bb = blockIdx.x;
  const int tid = threadIdx.x;
  if (bb < 64) {                              // ee table
    int gid = bb * 256 + tid;
    int n = gid >> 7, m = gid & 127;
    double wn = (double)n * (M_PI / 128.0), wm = (double)m * (M_PI / 128.0);
    ee[gid] = (float)(wn * wn + wm * wm);
  } else if (bb < 72) {                       // DCT frags
    int t2 = (bb - 64) * 256 + tid;
    int lane = t2 & 63, fid = t2 >> 6;
    int mt = fid >> 2, ks = fid & 3;
    int n = 16 * mt + (lane & 15);
    int k0 = 32 * ks + 8 * (lane >> 4);
#pragma unroll
    for (int j = 0; j < 4; ++j) {
      uint32_t p0 = packhl(cval(n, k0 + 2 * j)), p1 = packhl(cval(n, k0 + 2 * j + 1));
      FAh[t2 * 4 + j] = (p0 >> 16) | (p1 & 0xFFFF0000u);
      FAl[t2 * 4 + j] = (p0 & 0xFFFFu) | (p1 << 16);
      uint32_t q0 = packhl(cval(k0 + 2 * j, n)), q1 = packhl(cval(k0 + 2 * j + 1, n));
      FTh[t2 * 4 + j] = (q0 >> 16) | (q1 & 0xFFFF0000u);
      FTl[t2 * 4 + j] = (q0 & 0xFFFFu) | (q1 << 16);
    }
  } else if (bb < 81) {
    wfrag_dev(lin_w, WLh, WLl, 192, 96, (bb - 72) * 256 + tid);
  } else if (bb < 90) {
    wfrag_dev(lin3_w, W3h, W3l, 96, 192, (bb - 81) * 256 + tid);
  } else if (bb < 95) {
    wfrag_dev(out_w, WOh, WOl, 96, 96, (bb - 90) * 256 + tid);
  } else if (bb < 113) {
    wfrag_dev(lin2_w, W2h, W2l, 192, 192, (bb - 95) * 256 + tid);
  } else if (bb < 131) {
    wfrag_dev(k2_w, K2h, K2l, 192, 192, (bb - 113) * 256 + tid);
  } else if (bb < 167) {                      // k_w transpose
    int gid = (bb - 131) * 256 + tid;
    if (gid < 96 * 96) {
      int d = gid / 96, c = gid % 96;
      kT[c * 96 + d] = k_w[gid];
    }
  } else {                                    // fe transpose (256 blocks)
    int hw0 = (bb - 167) * 64;
#pragma unroll
    for (int t = 0; t < 24; ++t) {
      int l = tid + t * 256;
      int r = l / 96, c0 = l % 96;
      tile[r * 97 + c0] = fe[((size_t)hw0 + r) * 96 + c0];
    }
    __syncthreads();
#pragma unroll
    for (int t = 0; t < 24; ++t) {
      int l = tid + t * 256;
      int c0 = l >> 6, r = l & 63;
      fet[(size_t)c0 * HW + hw0 + r] = tile[r * 97 + c0];
    }
  }
}

// ---------- KC: depthwise 3x3 conv, float4 per thread, PACKED plane-major out ----------
__global__ __launch_bounds__(256) void kconv(
    const float* __restrict__ x, const float* __restrict__ dw_w,
    const float* __restrict__ dw_b, uint32_t* __restrict__ xcu) {
  int gid = blockIdx.x * 256 + threadIdx.x;   // B*96*4096 = 3145728
  int p = gid >> 12;                          // plane b*96+c
  int q = gid & 4095;
  int h = q >> 5, w4 = (q & 31) << 2;
  int c = p % 96;
  const float* pw = dw_w + c * 9;
  const float* row = x + (size_t)p * HW + h * 128 + w4;
  bool tp = h > 0, bt = h < 127, lf = w4 > 0, rt = w4 < 124;
  float4 t_, m_, b_;
  float tl, tr, ml, mr, bl, br;
  m_ = *(const float4*)row;
  ml = lf ? row[-1] : 0.f;
  mr = rt ? row[4] : 0.f;
  if (tp) {
    t_ = *(const float4*)(row - 128);
    tl = lf ? row[-129] : 0.f;
    tr = rt ? row[-124] : 0.f;
  } else { t_ = make_float4(0.f, 0.f, 0.f, 0.f); tl = tr = 0.f; }
  if (bt) {
    b_ = *(const float4*)(row + 128);
    bl = lf ? row[127] : 0.f;
    br = rt ? row[132] : 0.f;
  } else { b_ = make_float4(0.f, 0.f, 0.f, 0.f); bl = br = 0.f; }
  float w0 = pw[0], w1 = pw[1], w2 = pw[2], w3 = pw[3], w4w = pw[4],
        w5 = pw[5], w6 = pw[6], w7 = pw[7], w8 = pw[8];
  float bias = dw_b[c];
  float o0, o1, o2, o3;
  o0 = tl * w0 + t_.x * w1 + t_.y * w2 + ml * w3 + m_.x * w4w + m_.y * w5 + bl * w6 + b_.x * w7 + b_.y * w8 + bias;
  o1 = t_.x * w0 + t_.y * w1 + t_.z * w2 + m_.x * w3 + m_.y * w4w + m_.z * w5 + b_.x * w6 + b_.y * w7 + b_.z * w8 + bias;
  o2 = t_.y * w0 + t_.z * w1 + t_.w * w2 + m_.y * w3 + m_.z * w4w + m_.w * w5 + b_.y * w6 + b_.z * w7 + b_.w * w8 + bias;
  o3 = t_.z * w0 + t_.w * w1 + tr * w2 + m_.z * w3 + m_.w * w4w + mr * w5 + b_.z * w6 + b_.w * w7 + br * w8 + bias;
  uint4 ou = make_uint4(packhl(o0), packhl(o1), packhl(o2), packhl(o3));
  *(uint4*)(xcu + (size_t)p * HW + h * 128 + w4) = ou;
}

// ---------- KL-MFMA: [B*HW,96] @ lin_w^T -> x1 planes (PACKED u32) + z planes (f32) ----------
__global__ __launch_bounds__(256) void klin_mfma(
    const uint32_t* __restrict__ xcu, const uint32_t* __restrict__ WLh,
    const uint32_t* __restrict__ WLl, const float* __restrict__ lin_b,
    uint32_t* __restrict__ x1u, float* __restrict__ z) {
  __shared__ uint32_t Ds[64 * 102];   // [m][k], 26 KB
  const int tid = threadIdx.x;
  const int lane = tid & 63;
  const int w = tid >> 6;
  const int l15 = lane & 15, lg = lane >> 4;
  const int gp0 = blockIdx.x * 64;
  const int b = gp0 >> 14, hw0 = gp0 & 16383;

#pragma unroll
  for (int i = 0; i < 24; ++i) {      // stage xc (packed) -> Ds[m*102+k]
    int k = w + 4 * i;
    Ds[lane * 102 + k] = xcu[((size_t)(b * 96 + k)) * HW + hw0 + lane];
  }
  __syncthreads();

  f32x4 acc[3][4];
#pragma unroll
  for (int nt = 0; nt < 3; ++nt) {
    float bv[4];
#pragma unroll
    for (int r = 0; r < 4; ++r) bv[r] = lin_b[16 * (3 * w + nt) + 4 * lg + r];
#pragma unroll
    for (int mt = 0; mt < 4; ++mt)
#pragma unroll
      for (int r = 0; r < 4; ++r) acc[nt][mt][r] = bv[r];
  }

#pragma unroll
  for (int ksl = 0; ksl < 3; ++ksl) {
    s8bf Dhi[4], Dlo[4];
#pragma unroll
    for (int mt = 0; mt < 4; ++mt) {
      const uint32_t* p = Ds + (16 * mt + l15) * 102 + 32 * ksl + 8 * lg;
      uint32_t wv[8];
      *(uint2*)&wv[0] = *(const uint2*)(p);
      *(uint2*)&wv[2] = *(const uint2*)(p + 2);
      *(uint2*)&wv[4] = *(const uint2*)(p + 4);
      *(uint2*)&wv[6] = *(const uint2*)(p + 6);
      unpack8(wv, Dhi[mt], Dlo[mt]);
    }
#pragma unroll
    for (int nt = 0; nt < 3; ++nt) {
      int base = (((3 * w + nt) * 3 + ksl) * 64 + lane) * 4;
      FragU H, L;
      *(uint4*)H.u = *(const uint4*)(WLh + base);
      *(uint4*)L.u = *(const uint4*)(WLl + base);
#pragma unroll
      for (int mt = 0; mt < 4; ++mt) {
        acc[nt][mt] = __builtin_amdgcn_mfma_f32_16x16x32_bf16(H.s, Dhi[mt], acc[nt][mt], 0, 0, 0);
        acc[nt][mt] = __builtin_amdgcn_mfma_f32_16x16x32_bf16(H.s, Dlo[mt], acc[nt][mt], 0, 0, 0);
        acc[nt][mt] = __builtin_amdgcn_mfma_f32_16x16x32_bf16(L.s, Dhi[mt], acc[nt][mt], 0, 0, 0);
      }
    }
  }
#pragma unroll
  for (int nt = 0; nt < 3; ++nt) {
    int d0 = 16 * (3 * w + nt) + 4 * lg;
#pragma unroll
    for (int mt = 0; mt < 4; ++mt) {
#pragma unroll
      for (int r = 0; r < 4; ++r) {
        int d = d0 + r;
        if (d < 96)
          x1u[((size_t)(b * 96 + d)) * HW + hw0 + 16 * mt + l15] = packhl(acc[nt][mt][r]);
        else
          z[((size_t)(d - 96)) * BHW + gp0 + 16 * mt + l15] = acc[nt][mt][r];
      }
    }
  }
}

// ---------- K3: outline_feat transpose to plane-major (PACKED) + mean over B (f32) ----------
__global__ __launch_bounds__(256) void k3_transpose_mean(
    const float* __restrict__ of, uint32_t* __restrict__ ofu, float* __restrict__ cmU) {
  __shared__ float tile[64 * 97];
  int hw0 = blockIdx.x * 64;
  int tid = threadIdx.x;
  float sum[24];
#pragma unroll
  for (int t = 0; t < 24; ++t) sum[t] = 0.f;
  for (int b = 0; b < 8; ++b) {
    __syncthreads();
#pragma unroll
    for (int t = 0; t < 24; ++t) {
      int l = tid + t * 256;
      int r = l / 96, c0 = l % 96;
      tile[r * 97 + c0] = of[((size_t)b * 16384 + hw0 + r) * 96 + c0];
    }
    __syncthreads();
#pragma unroll
    for (int t = 0; t < 24; ++t) {
      int l = tid + t * 256;
      int c0 = l >> 6, r = l & 63;
      float v = tile[r * 97 + c0];
      sum[t] += v;
      ofu[(size_t)(b * 96 + c0) * HW + hw0 + r] = packhl(v);
    }
  }
#pragma unroll
  for (int t = 0; t < 24; ++t) {
    int l = tid + t * 256;
    int c0 = l >> 6, r = l & 63;
    cmU[(size_t)c0 * HW + hw0 + r] = sum[t] * 0.125f;
  }
}

// ---------- K3b: k = relu((fet+otm)@k_w^T + k_b); P1 = exp(-e*k) ----------
__global__ __launch_bounds__(256) void k3b_kgemm(
    const float* __restrict__ fet, const float* __restrict__ otm,
    const float* __restrict__ kT, const float* __restrict__ kb,
    const float* __restrict__ ee, float* __restrict__ P1) {
  int tid = threadIdx.x;
  int lane = tid & 63;
  int n0 = __builtin_amdgcn_readfirstlane((tid >> 6) * 24);
  int row = blockIdx.x * 64 + lane;           // 256 blocks
  float acc[24];
#pragma unroll
  for (int j = 0; j < 24; ++j) acc[j] = kb[n0 + j];
#pragma unroll 4
  for (int c = 0; c < 96; ++c) {
    float a = fet[(size_t)c * HW + row] + otm[(size_t)c * HW + row];
    const float* wr = kT + c * 96 + n0;
#pragma unroll
    for (int j = 0; j < 24; ++j) acc[j] = fmaf(a, wr[j], acc[j]);
  }
  float er = ee[row];
#pragma unroll
  for (int j = 0; j < 24; ++j)
    P1[(size_t)(n0 + j) * HW + row] = expf(-er * fmaxf(acc[j], 0.f));
}

// ---------- MFMA transform primitives ----------
template <bool DATA_A>
__device__ __forceinline__ void heat_step(
    const uint32_t* __restrict__ Fh, const uint32_t* __restrict__ Fl,
    const uint32_t* __restrict__ Ds, f32x4 (&acc)[4][4], int wm, int wn, int lane) {
  const int l15 = lane & 15, lg = lane >> 4;
  const int wd = DATA_A ? wm : wn;
  const int wf = DATA_A ? wn : wm;
#pragma unroll
  for (int ksl = 0; ksl < 4; ++ksl) {
    s8bf Dhi[4], Dlo[4], Fhi[4], Flo[4];
#pragma unroll
    for (int t = 0; t < 4; ++t) {
      const uint32_t* p = Ds + (64 * wd + 16 * t + l15) * 130 + 32 * ksl + 8 * lg;
      uint32_t wv[8];
      *(uint2*)&wv[0] = *(const uint2*)(p);
      *(uint2*)&wv[2] = *(const uint2*)(p + 2);
      *(uint2*)&wv[4] = *(const uint2*)(p + 4);
      *(uint2*)&wv[6] = *(const uint2*)(p + 6);
      unpack8(wv, Dhi[t], Dlo[t]);
    }
#pragma unroll
    for (int t = 0; t < 4; ++t) {
      int base = (((4 * wf + t) * 4 + ksl) * 64 + lane) * 4;
      FragU H, L;
      *(uint4*)H.u = *(const uint4*)(Fh + base);
      *(uint4*)L.u = *(const uint4*)(Fl + base);
      Fhi[t] = H.s; Flo[t] = L.s;
    }
    const s8bf* Ah = DATA_A ? Dhi : Fhi;
    const s8bf* Al = DATA_A ? Dlo : Flo;
    const s8bf* Bh = DATA_A ? Fhi : Dhi;
    const s8bf* Bl = DATA_A ? Flo : Dlo;
#pragma unroll
    for (int mi = 0; mi < 4; ++mi)
#pragma unroll
      for (int ni = 0; ni < 4; ++ni)
        acc[mi][ni] = __builtin_amdgcn_mfma_f32_16x16x32_bf16(Ah[mi], Bh[ni], acc[mi][ni], 0, 0, 0);
#pragma unroll
    for (int mi = 0; mi < 4; ++mi)
#pragma unroll
      for (int ni = 0; ni < 4; ++ni)
        acc[mi][ni] = __builtin_amdgcn_mfma_f32_16x16x32_bf16(Ah[mi], Bl[ni], acc[mi][ni], 0, 0, 0);
#pragma unroll
    for (int mi = 0; mi < 4; ++mi)
#pragma unroll
      for (int ni = 0; ni < 4; ++ni)
        acc[mi][ni] = __builtin_amdgcn_mfma_f32_16x16x32_bf16(Al[mi], Bh[ni], acc[mi][ni], 0, 0, 0);
  }
}

// ---------- heat_half: Out = F * In * F^T; PIN: packed-u32 input; POUT: packed output ----------
template <bool PIN, bool POUT, bool USE_P>
__global__ __launch_bounds__(256, 2) void heat_half(
    const float* __restrict__ In, float* __restrict__ Out,
    const float* __restrict__ P, const uint32_t* __restrict__ Fh,
    const uint32_t* __restrict__ Fl, int Cmod) {
  __shared__ uint32_t Ds[128 * 130];
  const int tid = threadIdx.x;
  const int lane = tid & 63;
  const int w = tid >> 6;
  const int wm = w >> 1, wn = w & 1;
  const int l15 = lane & 15, lg = lane >> 4;
  const float* Ip = In + (size_t)blockIdx.x * HW;
  float* Op = Out + (size_t)blockIdx.x * HW;
  const float* Pp = nullptr;
  if constexpr (USE_P) Pp = P + (size_t)(blockIdx.x % Cmod) * HW;

  {
    int col = tid & 127, r0 = tid >> 7;
    if constexpr (PIN) {
      const uint32_t* Iu = (const uint32_t*)Ip;
#pragma unroll
      for (int i = 0; i < 64; ++i) {
        int row = r0 + 2 * i;
        Ds[col * 130 + row] = Iu[row * 128 + col];
      }
    } else {
#pragma unroll
      for (int i = 0; i < 64; ++i) {
        int row = r0 + 2 * i;
        Ds[col * 130 + row] = packhl(Ip[row * 128 + col]);
      }
    }
  }
  __syncthreads();

  f32x4 acc[4][4];
  const f32x4 zero4 = {0.f, 0.f, 0.f, 0.f};
#pragma unroll
  for (int mi = 0; mi < 4; ++mi)
#pragma unroll
    for (int ni = 0; ni < 4; ++ni) acc[mi][ni] = zero4;
  heat_step<false>(Fh, Fl, Ds, acc, wm, wn, lane);     // T = F * In
  __syncthreads();
#pragma unroll
  for (int mi = 0; mi < 4; ++mi)
#pragma unroll
    for (int ni = 0; ni < 4; ++ni)
#pragma unroll
      for (int r = 0; r < 4; ++r)
        Ds[(64 * wm + 16 * mi + 4 * lg + r) * 130 + 64 * wn + 16 * ni + l15] =
            packhl(acc[mi][ni][r]);
  __syncthreads();

#pragma unroll
  for (int mi = 0; mi < 4; ++mi)
#pragma unroll
    for (int ni = 0; ni < 4; ++ni) acc[mi][ni] = zero4;
  heat_step<true>(Fh, Fl, Ds, acc, wm, wn, lane);      // Out = T * F^T
#pragma unroll
  for (int mi = 0; mi < 4; ++mi)
#pragma unroll
    for (int ni = 0; ni < 4; ++ni) {
      int row = 64 * wm + 16 * mi + 4 * lg;
      int col = 64 * wn + 16 * ni + l15;
#pragma unroll
      for (int r = 0; r < 4; ++r) {
        float v = acc[mi][ni][r];
        if constexpr (USE_P) v *= Pp[(row + r) * 128 + col];
        if constexpr (POUT)
          ((uint32_t*)Op)[(row + r) * 128 + col] = packhl(v);
        else
          Op[(row + r) * 128 + col] = v;
      }
    }
}

// ---------- K5: plane-mean over batch: dst[c][s] = mean_b src[b*96+c][s] (f32 src) ----------
__global__ void k5_mean(const float* __restrict__ src, float* __restrict__ dst) {
  int idx = blockIdx.x * 256 + threadIdx.x;
  int c = idx >> 14, s = idx & 16383;
  float sum = 0.f;
#pragma unroll
  for (int b = 0; b < 8; ++b) sum += src[(size_t)(b * 96 + c) * HW + s];
  dst[idx] = sum * 0.125f;
}

// ---------- K67-MFMA: skf = cm@lin2^T+b2; k2 = relu(skf@k2^T+b2k); P2 = exp(-e*k2) ----------
__global__ __launch_bounds__(256) void k67_mfma(
    const float* __restrict__ cm,
    const uint32_t* __restrict__ W2h, const uint32_t* __restrict__ W2l,
    const float* __restrict__ b2,
    const uint32_t* __restrict__ K2h, const uint32_t* __restrict__ K2l,
    const float* __restrict__ b2k, const float* __restrict__ ee,
    float* __restrict__ P2) {
  __shared__ uint32_t Ds[64 * 194];           // 48.5 KB
  const int tid = threadIdx.x;
  const int lane = tid & 63;
  const int w = tid >> 6;
  const int l15 = lane & 15, lg = lane >> 4;
  const int row0 = blockIdx.x * 64;           // 256 blocks

#pragma unroll
  for (int i = 0; i < 48; ++i) {              // stage cm -> Ds[m*194+k]
    int k = w + 4 * i;
    Ds[lane * 194 + k] = packhl(cm[(size_t)k * HW + row0 + lane]);
  }
  __syncthreads();

  f32x4 acc[3][4];
#pragma unroll
  for (int nt = 0; nt < 3; ++nt) {
    float bv[4];
#pragma unroll
    for (int r = 0; r < 4; ++r) bv[r] = b2[16 * (3 * w + nt) + 4 * lg + r];
#pragma unroll
    for (int mt = 0; mt < 4; ++mt)
#pragma unroll
      for (int r = 0; r < 4; ++r) acc[nt][mt][r] = bv[r];
  }
#pragma unroll
  for (int ksl = 0; ksl < 6; ++ksl) {
    s8bf Dhi[4], Dlo[4];
#pragma unroll
    for (int mt = 0; mt < 4; ++mt) {
      const uint32_t* p = Ds + (16 * mt + l15) * 194 + 32 * ksl + 8 * lg;
      uint32_t wv[8];
      *(uint2*)&wv[0] = *(const uint2*)(p);
      *(uint2*)&wv[2] = *(const uint2*)(p + 2);
      *(uint2*)&wv[4] = *(const uint2*)(p + 4);
      *(uint2*)&wv[6] = *(const uint2*)(p + 6);
      unpack8(wv, Dhi[mt], Dlo[mt]);
    }
#pragma unroll
    for (int nt = 0; nt < 3; ++nt) {
      int base = (((3 * w + nt) * 6 + ksl) * 64 + lane) * 4;
      FragU H, L;
      *(uint4*)H.u = *(const uint4*)(W2h + base);
      *(uint4*)L.u = *(const uint4*)(W2l + base);
#pragma unroll
      for (int mt = 0; mt < 4; ++mt) {
        acc[nt][mt] = __builtin_amdgcn_mfma_f32_16x16x32_bf16(H.s, Dhi[mt], acc[nt][mt], 0, 0, 0);
        acc[nt][mt] = __builtin_amdgcn_mfma_f32_16x16x32_bf16(H.s, Dlo[mt], acc[nt][mt], 0, 0, 0);
        acc[nt][mt] = __builtin_amdgcn_mfma_f32_16x16x32_bf16(L.s, Dhi[mt], acc[nt][mt], 0, 0, 0);
      }
    }
  }
  __syncthreads();
#pragma unroll
  for (int nt = 0; nt < 3; ++nt) {
    int d0 = 16 * (3 * w + nt) + 4 * lg;
#pragma unroll
    for (int mt = 0; mt < 4; ++mt) {
      int col = 16 * mt + l15;
#pragma unroll
      for (int r = 0; r < 4; ++r)
        Ds[col * 194 + d0 + r] = packhl(acc[nt][mt][r]);
    }
  }
  __syncthreads();

  f32x4 acc2[3][4];
#pragma unroll
  for (int nt = 0; nt < 3; ++nt) {
    float bv[4];
#pragma unroll
    for (int r = 0; r < 4; ++r) bv[r] = b2k[16 * (3 * w + nt) + 4 * lg + r];
#pragma unroll
    for (int mt = 0; mt < 4; ++mt)
#pragma unroll
      for (int r = 0; r < 4; ++r) acc2[nt][mt][r] = bv[r];
  }
#pragma unroll
  for (int ksl = 0; ksl < 6; ++ksl) {
    s8bf Dhi[4], Dlo[4];
#pragma unroll
    for (int mt = 0; mt < 4; ++mt) {
      const uint32_t* p = Ds + (16 * mt + l15) * 194 + 32 * ksl + 8 * lg;
      uint32_t wv[8];
      *(uint2*)&wv[0] = *(const uint2*)(p);
      *(uint2*)&wv[2] = *(const uint2*)(p + 2);
      *(uint2*)&wv[4] = *(const uint2*)(p + 4);
      *(uint2*)&wv[6] = *(const uint2*)(p + 6);
      unpack8(wv, Dhi[mt], Dlo[mt]);
    }
#pragma unroll
    for (int nt = 0; nt < 3; ++nt) {
      int base = (((3 * w + nt) * 6 + ksl) * 64 + lane) * 4;
      FragU H, L;
      *(uint4*)H.u = *(const uint4*)(K2h + base);
      *(uint4*)L.u = *(const uint4*)(K2l + base);
#pragma unroll
      for (int mt = 0; mt < 4; ++mt) {
        acc2[nt][mt] = __builtin_amdgcn_mfma_f32_16x16x32_bf16(H.s, Dhi[mt], acc2[nt][mt], 0, 0, 0);
        acc2[nt][mt] = __builtin_amdgcn_mfma_f32_16x16x32_bf16(H.s, Dlo[mt], acc2[nt][mt], 0, 0, 0);
        acc2[nt][mt] = __builtin_amdgcn_mfma_f32_16x16x32_bf16(L.s, Dhi[mt], acc2[nt][mt], 0, 0, 0);
      }
    }
  }
  float er[4];
#pragma unroll
  for (int mt = 0; mt < 4; ++mt) er[mt] = ee[row0 + 16 * mt + l15];
#pragma unroll
  for (int nt = 0; nt < 3; ++nt) {
    int d0 = 16 * (3 * w + nt) + 4 * lg;
#pragma unroll
    for (int mt = 0; mt < 4; ++mt) {
      int row = row0 + 16 * mt + l15;
#pragma unroll
      for (int r = 0; r < 4; ++r)
        P2[(size_t)(d0 + r) * HW + row] = expf(-er[mt] * fmaxf(acc2[nt][mt][r], 0.f));
    }
  }
}

// ---------- KMIX: Tf(packed) = (concat[S1*P2lo, OhP(packed)]) @ lin3_w^T ----------
__global__ __launch_bounds__(256) void kmix(
    const float* __restrict__ S1, const uint32_t* __restrict__ OhU,
    const float* __restrict__ P2,
    const uint32_t* __restrict__ W3h, const uint32_t* __restrict__ W3l,
    uint32_t* __restrict__ TfU) {
  __shared__ uint32_t Ds[128 * 98];           // 50 KB
  const int tid = threadIdx.x;
  const int lane = tid & 63;
  const int w = tid >> 6;
  const int wn = w >> 1, wm = w & 1;
  const int l15 = lane & 15, lg = lane >> 4;
  const int gp0 = blockIdx.x * 128;           // 1024 blocks
  const int b = gp0 >> 14, hw0 = gp0 & 16383;

  f32x4 acc[3][4];
#pragma unroll
  for (int i = 0; i < 3; ++i)
#pragma unroll
    for (int j = 0; j < 4; ++j)
#pragma unroll
      for (int r = 0; r < 4; ++r) acc[i][j][r] = 0.f;

#pragma unroll
  for (int c = 0; c < 2; ++c) {
    if (c) __syncthreads();                   // protect LDS reuse
#pragma unroll
    for (int i = 0; i < 24; ++i) {
      int k = w + 4 * i;
      if (c == 0) {
        const float* sp = S1 + ((size_t)(b * 96 + k)) * HW + hw0;
        const float* pp = P2 + (size_t)k * HW + hw0;
        Ds[lane * 98 + k] = packhl(sp[lane] * pp[lane]);
        Ds[(lane + 64) * 98 + k] = packhl(sp[lane + 64] * pp[lane + 64]);
      } else {
        const uint32_t* sp = OhU + ((size_t)(b * 96 + k)) * HW + hw0;
        Ds[lane * 98 + k] = sp[lane];
        Ds[(lane + 64) * 98 + k] = sp[lane + 64];
      }
    }
    __syncthreads();
#pragma unroll
    for (int ksl = 0; ksl < 3; ++ksl) {
      s8bf Dhi[4], Dlo[4];
#pragma unroll
      for (int j = 0; j < 4; ++j) {
        const uint32_t* p = Ds + (16 * (4 * wm + j) + l15) * 98 + 32 * ksl + 8 * lg;
        uint32_t wv[8];
        *(uint2*)&wv[0] = *(const uint2*)(p);
        *(uint2*)&wv[2] = *(const uint2*)(p + 2);
        *(uint2*)&wv[4] = *(const uint2*)(p + 4);
        *(uint2*)&wv[6] = *(const uint2*)(p + 6);
        unpack8(wv, Dhi[j], Dlo[j]);
      }
#pragma unroll
      for (int i = 0; i < 3; ++i) {
        int base = (((3 * wn + i) * 6 + 3 * c + ksl) * 64 + lane) * 4;
        FragU H, L;
        *(uint4*)H.u = *(const uint4*)(W3h + base);
        *(uint4*)L.u = *(const uint4*)(W3l + base);
#pragma unroll
        for (int j = 0; j < 4; ++j) {
          acc[i][j] = __builtin_amdgcn_mfma_f32_16x16x32_bf16(H.s, Dhi[j], acc[i][j], 0, 0, 0);
          acc[i][j] = __builtin_amdgcn_mfma_f32_16x16x32_bf16(H.s, Dlo[j], acc[i][j], 0, 0, 0);
          acc[i][j] = __builtin_amdgcn_mfma_f32_16x16x32_bf16(L.s, Dhi[j], acc[i][j], 0, 0, 0);
        }
      }
    }
  }
#pragma unroll
  for (int i = 0; i < 3; ++i) {
    int d0 = 16 * (3 * wn + i) + 4 * lg;
#pragma unroll
    for (int j = 0; j < 4; ++j) {
      int hw = hw0 + 16 * (4 * wm + j) + l15;
#pragma unroll
      for (int r = 0; r < 4; ++r)
        TfU[((size_t)(b * 96 + d0 + r)) * HW + hw] = packhl(acc[i][j][r]);
    }
  }
}

// ---------- K9R: (y3 + b3) -> LN -> *silu(z) -> out GEMM (128 pos/block) ----------
// Ds2 stride 98 (EVEN): keeps all uint2 LDS reads 8-byte aligned (ds_read_b64).
// Stride 97 (R13/R14) broke alignment -> split b32 reads -> 25% slower kernel.
__global__ __launch_bounds__(256) void k9r(
    const float* __restrict__ y3, const float* __restrict__ z,
    const float* __restrict__ lin3b,
    const float* __restrict__ lng, const float* __restrict__ lnb,
    const uint32_t* __restrict__ WOh, const uint32_t* __restrict__ WOl,
    const float* __restrict__ outb, float* __restrict__ out) {
  __shared__ uint32_t Ds2[128 * 98];          // 50.2 KB
  __shared__ float2 red[4][128];              // 4 KB  (total 54.25 KB)
  const int tid = threadIdx.x;
  const int lane = tid & 63;
  const int w = tid >> 6;
  const int wn = w >> 1, wm = w & 1;
  const int l15 = lane & 15, lg = lane >> 4;
  const int gp0 = blockIdx.x * 128;           // 1024 blocks
  const int b = gp0 >> 14, hw0 = gp0 & 16383;

  float vA[24], vB[24];
  float sA = 0.f, qA = 0.f, sB = 0.f, qB = 0.f;
#pragma unroll
  for (int i = 0; i < 24; ++i) {
    int k = w + 4 * i;
    const float* yp = y3 + ((size_t)(b * 96 + k)) * HW + hw0;
    float bk = lin3b[k];
    float tA = yp[lane] + bk;      vA[i] = tA; sA += tA; qA = fmaf(tA, tA, qA);
    float tB = yp[lane + 64] + bk; vB[i] = tB; sB += tB; qB = fmaf(tB, tB, qB);
  }
  red[w][lane] = make_float2(sA, qA);
  red[w][lane + 64] = make_float2(sB, qB);
  __syncthreads();
  float2 a0 = red[0][lane], a1 = red[1][lane], a2 = red[2][lane], a3 = red[3][lane];
  float2 b0 = red[0][lane + 64], b1 = red[1][lane + 64], b2_ = red[2][lane + 64], b3 = red[3][lane + 64];
  float muA = (a0.x + a1.x + a2.x + a3.x) * (1.f / 96.f);
  float vrA = (a0.y + a1.y + a2.y + a3.y) * (1.f / 96.f) - muA * muA;
  float invA = rsqrtf(fmaxf(vrA, 0.f) + 1e-5f);
  float muB = (b0.x + b1.x + b2_.x + b3.x) * (1.f / 96.f);
  float vrB = (b0.y + b1.y + b2_.y + b3.y) * (1.f / 96.f) - muB * muB;
  float invB = rsqrtf(fmaxf(vrB, 0.f) + 1e-5f);
#pragma unroll
  for (int i = 0; i < 24; ++i) {
    int k = w + 4 * i;
    const float* zp = z + (size_t)k * BHW + gp0;
    float g = lng[k], bb = lnb[k];
    float zA = zp[lane];
    float uA = (vA[i] - muA) * invA * g + bb;
    Ds2[lane * 98 + k] = packhl(uA * (zA / (1.f + __expf(-zA))));
    float zB = zp[lane + 64];
    float uB = (vB[i] - muB) * invB * g + bb;
    Ds2[(lane + 64) * 98 + k] = packhl(uB * (zB / (1.f + __expf(-zB))));
  }
  __syncthreads();

  f32x4 acc2[3][4];
#pragma unroll
  for (int i = 0; i < 3; ++i) {
    float bv[4];
#pragma unroll
    for (int r = 0; r < 4; ++r) bv[r] = outb[16 * (3 * wn + i) + 4 * lg + r];
#pragma unroll
    for (int j = 0; j < 4; ++j)
#pragma unroll
      for (int r = 0; r < 4; ++r) acc2[i][j][r] = bv[r];
  }
#pragma unroll
  for (int ksl = 0; ksl < 3; ++ksl) {
    s8bf Dhi[4], Dlo[4];
#pragma unroll
    for (int j = 0; j < 4; ++j) {
      const uint32_t* p = Ds2 + (16 * (4 * wm + j) + l15) * 98 + 32 * ksl + 8 * lg;
      uint32_t wv[8];
      *(uint2*)&wv[0] = *(const uint2*)(p);
      *(uint2*)&wv[2] = *(const uint2*)(p + 2);
      *(uint2*)&wv[4] = *(const uint2*)(p + 4);
      *(uint2*)&wv[6] = *(const uint2*)(p + 6);
      unpack8(wv, Dhi[j], Dlo[j]);
    }
#pragma unroll
    for (int i = 0; i < 3; ++i) {
      int base = (((3 * wn + i) * 3 + ksl) * 64 + lane) * 4;
      FragU H, L;
      *(uint4*)H.u = *(const uint4*)(WOh + base);
      *(uint4*)L.u = *(const uint4*)(WOl + base);
#pragma unroll
      for (int j = 0; j < 4; ++j) {
        acc2[i][j] = __builtin_amdgcn_mfma_f32_16x16x32_bf16(H.s, Dhi[j], acc2[i][j], 0, 0, 0);
        acc2[i][j] = __builtin_amdgcn_mfma_f32_16x16x32_bf16(H.s, Dlo[j], acc2[i][j], 0, 0, 0);
        acc2[i][j] = __builtin_amdgcn_mfma_f32_16x16x32_bf16(L.s, Dhi[j], acc2[i][j], 0, 0, 0);
      }
    }
  }
#pragma unroll
  for (int i = 0; i < 3; ++i) {
    int d0 = 16 * (3 * wn + i) + 4 * lg;
#pragma unroll
    for (int j = 0; j < 4; ++j) {
      int hw = hw0 + 16 * (4 * wm + j) + l15;
#pragma unroll
      for (int r = 0; r < 4; ++r)
        out[((size_t)(b * 96 + d0 + r)) * HW + hw] = acc2[i][j][r];
    }
  }
}

extern "C" void kernel_launch(void* const* d_in, const int* in_sizes, int n_in,
                              void* d_out, int out_size, void* d_ws, size_t ws_size,
                              hipStream_t stream) {
  const float* x      = (const float*)d_in[0];
  const float* fe     = (const float*)d_in[1];
  const float* of     = (const float*)d_in[2];
  const float* dw_w   = (const float*)d_in[3];
  const float* dw_b   = (const float*)d_in[4];
  const float* lin_w  = (const float*)d_in[5];
  const float* lin_b  = (const float*)d_in[6];
  const float* k_w    = (const float*)d_in[7];
  const float* k_b    = (const float*)d_in[8];
  const float* lin2_w = (const float*)d_in[9];
  const float* lin2_b = (const float*)d_in[10];
  const float* k2_w   = (const float*)d_in[11];
  const float* k2_b   = (const float*)d_in[12];
  const float* lin3_w = (const float*)d_in[13];
  const float* lin3_b = (const float*)d_in[14];
  const float* ln_g   = (const float*)d_in[15];
  const float* ln_b   = (const float*)d_in[16];
  const float* out_w  = (const float*)d_in[17];
  const float* out_b  = (const float*)d_in[18];
  float* out = (float*)d_out;

  float* ws    = (float*)d_ws;
  float* x1p   = ws;                      // [B][96][HW]: x1(packed) -> S1(f32) -> Tf(packed) -> y3(f32)
  float* z     = x1p   + 12582912;        // [96][B*HW] plane-major f32
  float* ofp   = z     + 12582912;        // [B][96][HW]: xc(packed) -> outline(packed) -> OhP(packed)
  float* cm    = ofp   + 12582912;        // [192][HW] f32
  float* skf   = cm    + 3145728;         // [192][HW] (first 96 planes reused as cmSf scratch)
  float* P1    = skf   + 3145728;         // [96][HW]
  float* P2    = P1    + 1572864;         // [192][HW]
  float* cc    = P2    + 3145728;         // [128][128] (unused)
  float* ee    = cc    + 16384;           // [128][128]
  float* linT  = ee    + 16384;           // (unused)
  float* kT    = linT  + 18432;           // [96][96]
  float* lin2T = kT    + 9216;            // (unused)
  float* k2T   = lin2T + 36864;           // (unused)
  float* lin3T = k2T   + 36864;           // (unused)
  float* outT  = lin3T + 18432;           // (unused)
  float* fet   = outT  + 9216;            // [96][HW]
  uint32_t* FAh = (uint32_t*)(fet + 1572864);  // 8192 u32 each
  uint32_t* FAl = FAh + 8192;
  uint32_t* FTh = FAl + 8192;
  uint32_t* FTl = FTh + 8192;
  uint32_t* WLh = FTl + 8192;             // lin frags:  12x3x64x4 = 9216 u32
  uint32_t* WLl = WLh + 9216;
  uint32_t* W3h = WLl + 9216;             // lin3 frags: 6x6x64x4 = 9216
  uint32_t* W3l = W3h + 9216;
  uint32_t* WOh = W3l + 9216;             // out frags:  6x3x64x4 = 4608
  uint32_t* WOl = WOh + 4608;
  uint32_t* W2h = WOl + 4608;             // lin2 frags: 12x6x64x4 = 18432
  uint32_t* W2l = W2h + 18432;
  uint32_t* K2h = W2l + 18432;            // k2 frags:   18432
  uint32_t* K2l = K2h + 18432;
  float* cmSf  = skf;                     // [96][HW] temp: mean_b(S1)
  uint32_t* x1u = (uint32_t*)x1p;
  uint32_t* ofu = (uint32_t*)ofp;
  uint32_t* xcu = ofu;                    // aliases ofp: dead after klin, before k3
  (void)in_sizes; (void)n_in; (void)out_size; (void)ws_size;

  kprep<<<423, 256, 0, stream>>>(ee, FAh, FAl, FTh, FTl,
                                 lin_w, WLh, WLl, lin3_w, W3h, W3l,
                                 out_w, WOh, WOl, lin2_w, W2h, W2l,
                                 k2_w, K2h, K2l, k_w, kT, fe, fet);

  kconv<<<12288, 256, 0, stream>>>(x, dw_w, dw_b, xcu);
  klin_mfma<<<2048, 256, 0, stream>>>(xcu, WLh, WLl, lin_b, x1u, z);
  k3_transpose_mean<<<256, 256, 0, stream>>>(of, ofu, cm + (size_t)96 * HW);
  k3b_kgemm<<<256, 256, 0, stream>>>(fet, cm + (size_t)96 * HW, kT, k_b, ee, P1);
  // S1(f32) = P1 .* dct2(x1 packed)   (in-place in x1p)
  heat_half<true, false, true><<<768, 256, 0, stream>>>(x1p, x1p, P1, FAh, FAl, 96);
  // mean_b(y1) = idct2(mean_b(S1))
  k5_mean<<<6144, 256, 0, stream>>>(x1p, cmSf);
  heat_half<false, false, false><<<96, 256, 0, stream>>>(cmSf, cm, nullptr, FTh, FTl, 96);
  // P2 (k6+k7 fused, MFMA)
  k67_mfma<<<256, 256, 0, stream>>>(cm, W2h, W2l, lin2_b, K2h, K2l, k2_b, ee, P2);
  // OhP(packed) = dct2(outline packed) .* P2hi  (in-place in ofp)
  heat_half<true, true, true><<<768, 256, 0, stream>>>(ofp, ofp, P2 + (size_t)96 * HW, FAh, FAl, 96);
  // Tf(packed) = (concat[S1*P2lo, OhP]) @ lin3^T  (in-place into x1p)
  kmix<<<1024, 256, 0, stream>>>(x1p, ofu, P2, W3h, W3l, x1u);
  // y3(f32) = idct2(Tf packed)  (in-place in x1p)
  heat_half<true, false, false><<<768, 256, 0, stream>>>(x1p, x1p, nullptr, FTh, FTl, 96);
  k9r<<<1024, 256, 0, stream>>>(x1p, z, lin3_b, ln_g, ln_b, WOh, WOl, out_b, out);
}